// Round 1
// baseline (1101.595 us; speedup 1.0000x reference)
//
#include <hip/hip_runtime.h>
#include <cstdint>
#include <cstddef>

#define NB 16
#define NP 4096
#define KNN 16
#define CIN 64
#define H 32
#define OCC 64

__device__ __forceinline__ float lrelu(float v){ return v > 0.f ? v : 0.2f*v; }
__device__ __forceinline__ float reluf(float v){ return v > 0.f ? v : 0.f; }

// ---------------- K1: pointwise f1 = lrelu(cbn(ft,mlp1)); q1/k1/v1 = relu(cbn(f1,p1_*))
__global__ __launch_bounds__(256) void k_pointwise(
    const float* __restrict__ feat,
    const float* __restrict__ w1, const float* __restrict__ s1, const float* __restrict__ b1,
    const float* __restrict__ wq, const float* __restrict__ sq, const float* __restrict__ bq,
    const float* __restrict__ wk, const float* __restrict__ sk, const float* __restrict__ bk,
    const float* __restrict__ wv, const float* __restrict__ sv, const float* __restrict__ bv,
    float* __restrict__ q1, float* __restrict__ k1, float* __restrict__ v1)
{
    int p = blockIdx.x*256 + threadIdx.x;
    int b = p >> 12, n = p & (NP-1);
    const float* fb = feat + ((size_t)b*CIN)*NP + n;
    float ft[CIN];
    #pragma unroll
    for (int c=0;c<CIN;c++) ft[c] = fb[(size_t)c*NP];   // coalesced over lanes
    float f1[H];
    #pragma unroll 4
    for (int h=0;h<H;h++){
        float a0=0.f, a1=0.f;
        #pragma unroll
        for (int c=0;c<CIN;c+=2){ a0 += w1[h*CIN+c]*ft[c]; a1 += w1[h*CIN+c+1]*ft[c+1]; }
        f1[h] = lrelu((a0+a1)*s1[h] + b1[h]);
    }
    size_t base = (size_t)p*H;
    #pragma unroll 4
    for (int h=0;h<H;h++){
        float aq=0.f, ak=0.f, av=0.f;
        #pragma unroll
        for (int j=0;j<H;j++){
            float fj = f1[j];
            aq += wq[h*H+j]*fj; ak += wk[h*H+j]*fj; av += wv[h*H+j]*fj;
        }
        q1[base+h] = reluf(aq*sq[h]+bq[h]);
        k1[base+h] = reluf(ak*sk[h]+bk[h]);
        v1[base+h] = reluf(av*sv[h]+bv[h]);
    }
}

// ---------------- K2: pool1 (x_info from lse1 recomputed) + fused q2/k2/v2
__global__ __launch_bounds__(256) void k_pool1(
    const float* __restrict__ xpos, const int* __restrict__ nidx,
    const float* __restrict__ q1, const float* __restrict__ k1, const float* __restrict__ v1,
    const float* __restrict__ l1w, const float* __restrict__ l1s, const float* __restrict__ l1b,
    const float* __restrict__ w2, const float* __restrict__ s2, const float* __restrict__ b2,
    const float* __restrict__ wq, const float* __restrict__ sq, const float* __restrict__ bq,
    const float* __restrict__ wk, const float* __restrict__ sk, const float* __restrict__ bk,
    const float* __restrict__ wv, const float* __restrict__ sv, const float* __restrict__ bv,
    float* __restrict__ q2, float* __restrict__ k2, float* __restrict__ v2)
{
    int t = threadIdx.x;
    int c = t & 31;            // channel lane
    int half = t & 32;        // wave-half base for shuffles
    int p = blockIdx.x*8 + (t>>5);
    int b = p >> 12, n = p & (NP-1);

    float wl1[10];
    #pragma unroll
    for (int j=0;j<10;j++) wl1[j] = l1w[c*10+j];
    float sl1 = l1s[c], bl1 = l1b[c];

    const float* xb = xpos + (size_t)b*3*NP;
    float cx = xb[n], cy = xb[NP+n], cz = xb[2*NP+n];
    float qc = q1[(size_t)p*H + c];
    const int* irow = nidx + (size_t)p*KNN;

    float m = -1e30f, den = 0.f, acc = 0.f;
    #pragma unroll
    for (int k=0;k<KNN;k++){
        int id = irow[k];
        float kx = xb[id], ky = xb[NP+id], kz = xb[2*NP+id];
        float dx = kx-cx, dy = ky-cy, dz = kz-cz;
        float dist = sqrtf(dx*dx+dy*dy+dz*dz + 1e-12f);
        float gd = wl1[0]*cx + wl1[1]*cy + wl1[2]*cz
                 + wl1[3]*kx + wl1[4]*ky + wl1[5]*kz
                 + wl1[6]*dx + wl1[7]*dy + wl1[8]*dz + wl1[9]*dist;
        float xi = lrelu(gd*sl1 + bl1);
        size_t nb = ((size_t)b*NP + id)*H + c;      // 128B coalesced gather
        float Kn = k1[nb], Vn = v1[nb];
        float W = xi*(Kn - qc);
        float nm = fmaxf(m, W);
        float scl = __expf(m - nm);
        float e   = __expf(W - nm);
        den = den*scl + e;
        acc = acc*scl + e*Vn;
        m = nm;
    }
    float outc = acc/den;

    // feat2 = lrelu(cbn(out, p1_w2)) via shuffle-broadcast matvec
    float w2r[32];
    #pragma unroll
    for (int j=0;j<32;j++) w2r[j] = w2[c*32+j];
    float f2a = 0.f;
    #pragma unroll
    for (int j=0;j<32;j++) f2a += w2r[j]*__shfl(outc, half+j, 64);
    float f2 = lrelu(f2a*s2[c] + b2[c]);

    // q2/k2/v2 = relu(cbn(feat2, p2_*))
    float wqr[32], wkr[32], wvr[32];
    #pragma unroll
    for (int j=0;j<32;j++){ wqr[j]=wq[c*32+j]; wkr[j]=wk[c*32+j]; wvr[j]=wv[c*32+j]; }
    float aq=0.f, ak=0.f, av=0.f;
    #pragma unroll
    for (int j=0;j<32;j++){
        float fj = __shfl(f2, half+j, 64);
        aq += wqr[j]*fj; ak += wkr[j]*fj; av += wvr[j]*fj;
    }
    size_t base = (size_t)p*H + c;
    q2[base] = reluf(aq*sq[c]+bq[c]);
    k2[base] = reluf(ak*sk[c]+bk[c]);
    v2[base] = reluf(av*sv[c]+bv[c]);
}

// ---------------- K3: pool2 (x_info2 = lrelu(cbn(x_info,lse2)) per neighbor) -> feat3 [B*N,64]
__global__ __launch_bounds__(256) void k_pool2(
    const float* __restrict__ xpos, const int* __restrict__ nidx,
    const float* __restrict__ q2, const float* __restrict__ k2, const float* __restrict__ v2,
    const float* __restrict__ l1w, const float* __restrict__ l1s, const float* __restrict__ l1b,
    const float* __restrict__ l2w, const float* __restrict__ l2s, const float* __restrict__ l2b,
    const float* __restrict__ w2, const float* __restrict__ s2, const float* __restrict__ b2,
    float* __restrict__ feat3)
{
    int t = threadIdx.x;
    int c = t & 31;
    int half = t & 32;
    int p = blockIdx.x*8 + (t>>5);
    int b = p >> 12, n = p & (NP-1);

    float wl1[10];
    #pragma unroll
    for (int j=0;j<10;j++) wl1[j] = l1w[c*10+j];
    float sl1 = l1s[c], bl1 = l1b[c];
    float wl2[32];
    #pragma unroll
    for (int j=0;j<32;j++) wl2[j] = l2w[c*32+j];
    float sl2 = l2s[c], bl2 = l2b[c];

    const float* xb = xpos + (size_t)b*3*NP;
    float cx = xb[n], cy = xb[NP+n], cz = xb[2*NP+n];
    float qc = q2[(size_t)p*H + c];
    const int* irow = nidx + (size_t)p*KNN;

    float m = -1e30f, den = 0.f, acc = 0.f;
    #pragma unroll
    for (int k=0;k<KNN;k++){
        int id = irow[k];
        float kx = xb[id], ky = xb[NP+id], kz = xb[2*NP+id];
        float dx = kx-cx, dy = ky-cy, dz = kz-cz;
        float dist = sqrtf(dx*dx+dy*dy+dz*dz + 1e-12f);
        float gd = wl1[0]*cx + wl1[1]*cy + wl1[2]*cz
                 + wl1[3]*kx + wl1[4]*ky + wl1[5]*kz
                 + wl1[6]*dx + wl1[7]*dy + wl1[8]*dz + wl1[9]*dist;
        float xi = lrelu(gd*sl1 + bl1);
        // x_info2 = lrelu(cbn(x_info, lse2)) : cross-lane matvec via shuffles
        float a2 = 0.f;
        #pragma unroll
        for (int j=0;j<32;j++) a2 += wl2[j]*__shfl(xi, half+j, 64);
        float xi2 = lrelu(a2*sl2 + bl2);
        size_t nb = ((size_t)b*NP + id)*H + c;
        float Kn = k2[nb], Vn = v2[nb];
        float W = xi2*(Kn - qc);
        float nm = fmaxf(m, W);
        float scl = __expf(m - nm);
        float e   = __expf(W - nm);
        den = den*scl + e;
        acc = acc*scl + e*Vn;
        m = nm;
    }
    float outc = acc/den;

    // feat3 = lrelu(cbn(out, p2_w2 [64,32])): each lane computes rows c and c+32
    float w2a[32], w2b[32];
    #pragma unroll
    for (int j=0;j<32;j++){ w2a[j] = w2[c*32+j]; w2b[j] = w2[(c+32)*32+j]; }
    float fa=0.f, fb2=0.f;
    #pragma unroll
    for (int j=0;j<32;j++){
        float oj = __shfl(outc, half+j, 64);
        fa += w2a[j]*oj; fb2 += w2b[j]*oj;
    }
    feat3[(size_t)p*OCC + c]      = lrelu(fa *s2[c]   + b2[c]);
    feat3[(size_t)p*OCC + 32 + c] = lrelu(fb2*s2[c+32]+ b2[c+32]);
}

// ---------------- K4: out = lrelu(cbn(feat3,mlp2) + cbn(ft,res)) -> [B,128,N]
__global__ __launch_bounds__(256) void k_final(
    const float* __restrict__ feat, const float* __restrict__ feat3,
    const float* __restrict__ m2w, const float* __restrict__ m2s, const float* __restrict__ m2b,
    const float* __restrict__ rw, const float* __restrict__ rs, const float* __restrict__ rb,
    float* __restrict__ out)
{
    int p = blockIdx.x*256 + threadIdx.x;
    int b = p >> 12, n = p & (NP-1);
    float f3[OCC], ft[CIN];
    const float* fp = feat3 + (size_t)p*OCC;
    #pragma unroll
    for (int c=0;c<OCC;c++) f3[c] = fp[c];
    const float* fb = feat + ((size_t)b*CIN)*NP + n;
    #pragma unroll
    for (int c=0;c<CIN;c++) ft[c] = fb[(size_t)c*NP];
    float* ob = out + ((size_t)b*128)*NP + n;
    #pragma unroll 1
    for (int o=0;o<128;o++){
        float a0=0.f,a1=0.f,r0=0.f,r1=0.f;
        #pragma unroll
        for (int cc=0; cc<OCC; cc+=2){
            a0 += m2w[o*OCC+cc]  *f3[cc];
            a1 += m2w[o*OCC+cc+1]*f3[cc+1];
            r0 += rw[o*CIN+cc]   *ft[cc];
            r1 += rw[o*CIN+cc+1] *ft[cc+1];
        }
        float v = (a0+a1)*m2s[o]+m2b[o] + (r0+r1)*rs[o]+rb[o];
        ob[(size_t)o*NP] = lrelu(v);
    }
}

extern "C" void kernel_launch(void* const* d_in, const int* in_sizes, int n_in,
                              void* d_out, int out_size, void* d_ws, size_t ws_size,
                              hipStream_t stream)
{
    (void)in_sizes; (void)n_in; (void)out_size; (void)ws_size;
    const float* x     = (const float*)d_in[0];
    const float* feat  = (const float*)d_in[1];
    const int*   nidx  = (const int*)  d_in[2];
    const float* m1w=(const float*)d_in[3],  *m1s=(const float*)d_in[4],  *m1b=(const float*)d_in[5];
    const float* l1w=(const float*)d_in[6],  *l1s=(const float*)d_in[7],  *l1b=(const float*)d_in[8];
    const float* p1wq=(const float*)d_in[9],  *p1sq=(const float*)d_in[10], *p1bq=(const float*)d_in[11];
    const float* p1wk=(const float*)d_in[12], *p1sk=(const float*)d_in[13], *p1bk=(const float*)d_in[14];
    const float* p1wv=(const float*)d_in[15], *p1sv=(const float*)d_in[16], *p1bv=(const float*)d_in[17];
    const float* p1w2=(const float*)d_in[18], *p1s2=(const float*)d_in[19], *p1b2=(const float*)d_in[20];
    const float* p2wq=(const float*)d_in[21], *p2sq=(const float*)d_in[22], *p2bq=(const float*)d_in[23];
    const float* p2wk=(const float*)d_in[24], *p2sk=(const float*)d_in[25], *p2bk=(const float*)d_in[26];
    const float* p2wv=(const float*)d_in[27], *p2sv=(const float*)d_in[28], *p2bv=(const float*)d_in[29];
    const float* p2w2=(const float*)d_in[30], *p2s2=(const float*)d_in[31], *p2b2=(const float*)d_in[32];
    const float* l2w=(const float*)d_in[33], *l2s=(const float*)d_in[34], *l2b=(const float*)d_in[35];
    const float* m2w=(const float*)d_in[36], *m2s=(const float*)d_in[37], *m2b=(const float*)d_in[38];
    const float* rw =(const float*)d_in[39], *rs =(const float*)d_in[40], *rb =(const float*)d_in[41];

    float* ws = (float*)d_ws;
    const size_t PN = (size_t)NB*NP;      // 65536 points
    float* q1 = ws;
    float* k1 = q1 + PN*H;
    float* v1 = k1 + PN*H;
    float* q2 = v1 + PN*H;
    float* k2 = q2 + PN*H;
    float* v2 = k2 + PN*H;
    float* f3 = v2 + PN*H;                // PN*64 floats

    float* outp = (float*)d_out;

    k_pointwise<<<dim3(PN/256),dim3(256),0,stream>>>(feat, m1w,m1s,m1b,
        p1wq,p1sq,p1bq, p1wk,p1sk,p1bk, p1wv,p1sv,p1bv, q1,k1,v1);
    k_pool1<<<dim3(PN/8),dim3(256),0,stream>>>(x,nidx, q1,k1,v1,
        l1w,l1s,l1b, p1w2,p1s2,p1b2,
        p2wq,p2sq,p2bq, p2wk,p2sk,p2bk, p2wv,p2sv,p2bv, q2,k2,v2);
    k_pool2<<<dim3(PN/8),dim3(256),0,stream>>>(x,nidx, q2,k2,v2,
        l1w,l1s,l1b, l2w,l2s,l2b, p2w2,p2s2,p2b2, f3);
    k_final<<<dim3(PN/256),dim3(256),0,stream>>>(feat, f3, m2w,m2s,m2b, rw,rs,rb, outp);
}

// Round 2
// 625.913 us; speedup vs baseline: 1.7600x; 1.7600x over previous
//
#include <hip/hip_runtime.h>
#include <cstdint>
#include <cstddef>

#define NB 16
#define NP 4096
#define KNN 16
#define CIN 64
#define H 32
#define OCC 64
#define PN ((size_t)NB*NP)

__device__ __forceinline__ float lrelu(float v){ return v > 0.f ? v : 0.2f*v; }
__device__ __forceinline__ float reluf(float v){ return v > 0.f ? v : 0.f; }

// ---------------- K1: pointwise f1 = lrelu(cbn(ft,mlp1)); q1/k1/v1 = relu(cbn(f1,p1_*))
__global__ __launch_bounds__(256) void k_pointwise(
    const float* __restrict__ feat,
    const float* __restrict__ w1, const float* __restrict__ s1, const float* __restrict__ b1,
    const float* __restrict__ wq, const float* __restrict__ sq, const float* __restrict__ bq,
    const float* __restrict__ wk, const float* __restrict__ sk, const float* __restrict__ bk,
    const float* __restrict__ wv, const float* __restrict__ sv, const float* __restrict__ bv,
    float* __restrict__ q1, float* __restrict__ k1, float* __restrict__ v1)
{
    int p = blockIdx.x*256 + threadIdx.x;
    int b = p >> 12, n = p & (NP-1);
    const float* fb = feat + ((size_t)b*CIN)*NP + n;
    float ft[CIN];
    #pragma unroll
    for (int c=0;c<CIN;c++) ft[c] = fb[(size_t)c*NP];   // coalesced over lanes
    float f1[H];
    #pragma unroll 4
    for (int h=0;h<H;h++){
        float a0=0.f, a1=0.f;
        #pragma unroll
        for (int c=0;c<CIN;c+=2){ a0 = fmaf(w1[h*CIN+c],ft[c],a0); a1 = fmaf(w1[h*CIN+c+1],ft[c+1],a1); }
        f1[h] = lrelu((a0+a1)*s1[h] + b1[h]);
    }
    size_t base = (size_t)p*H;
    #pragma unroll
    for (int hg=0;hg<8;hg++){
        float qr[4], kr[4], vr[4];
        #pragma unroll
        for (int u=0;u<4;u++){
            int h = hg*4+u;
            float aq=0.f, ak=0.f, av=0.f;
            #pragma unroll
            for (int j=0;j<H;j++){
                float fj = f1[j];
                aq = fmaf(wq[h*H+j],fj,aq); ak = fmaf(wk[h*H+j],fj,ak); av = fmaf(wv[h*H+j],fj,av);
            }
            qr[u] = reluf(aq*sq[h]+bq[h]);
            kr[u] = reluf(ak*sk[h]+bk[h]);
            vr[u] = reluf(av*sv[h]+bv[h]);
        }
        *(float4*)(q1+base+hg*4) = make_float4(qr[0],qr[1],qr[2],qr[3]);
        *(float4*)(k1+base+hg*4) = make_float4(kr[0],kr[1],kr[2],kr[3]);
        *(float4*)(v1+base+hg*4) = make_float4(vr[0],vr[1],vr[2],vr[3]);
    }
}

// ---------------- K2: pool1 + fused q2/k2/v2.  Half-wave = one point, lane = channel.
__global__ __launch_bounds__(256) void k_pool1(
    const float* __restrict__ xpos, const int* __restrict__ nidx,
    const float* __restrict__ q1, const float* __restrict__ k1, const float* __restrict__ v1,
    const float* __restrict__ l1w, const float* __restrict__ l1s, const float* __restrict__ l1b,
    const float* __restrict__ w2, const float* __restrict__ s2, const float* __restrict__ b2,
    const float* __restrict__ wq, const float* __restrict__ sq, const float* __restrict__ bq,
    const float* __restrict__ wk, const float* __restrict__ sk, const float* __restrict__ bk,
    const float* __restrict__ wv, const float* __restrict__ sv, const float* __restrict__ bv,
    float* __restrict__ q2, float* __restrict__ k2, float* __restrict__ v2)
{
    __shared__ float wl[4][32*36];   // w2, wq, wk, wv  (rows padded to 36)
    __shared__ float bc[8][32];      // per-half-wave broadcast slot
    int t = threadIdx.x;
    {
        const float* wsrc[4] = {w2, wq, wk, wv};
        #pragma unroll
        for (int m=0;m<4;m++)
            for (int i=t;i<1024;i+=256)
                wl[m][(i>>5)*36 + (i&31)] = wsrc[m][i];
    }
    __syncthreads();

    int c = t & 31;
    int hw = t >> 5;
    int p = blockIdx.x*8 + hw;
    int b = p >> 12, n = p & (NP-1);

    float wl1r[10];
    #pragma unroll
    for (int j=0;j<10;j++) wl1r[j] = l1w[c*10+j];
    float sl1 = l1s[c], bl1 = l1b[c];

    const float* xb = xpos + (size_t)b*3*NP;
    float cx = xb[n], cy = xb[NP+n], cz = xb[2*NP+n];
    float qc = q1[(size_t)p*H + c];
    const int* irow = nidx + (size_t)p*KNN;
    int idxs[KNN];
    #pragma unroll
    for (int k=0;k<KNN;k++) idxs[k] = irow[k];

    float W[KNN], V[KNN];
    #pragma unroll
    for (int k=0;k<KNN;k++){
        int id = idxs[k];
        float kx = xb[id], ky = xb[NP+id], kz = xb[2*NP+id];
        float dx = kx-cx, dy = ky-cy, dz = kz-cz;
        float dist = sqrtf(dx*dx+dy*dy+dz*dz + 1e-12f);
        float gd = wl1r[0]*cx + wl1r[1]*cy + wl1r[2]*cz
                 + wl1r[3]*kx + wl1r[4]*ky + wl1r[5]*kz
                 + wl1r[6]*dx + wl1r[7]*dy + wl1r[8]*dz + wl1r[9]*dist;
        float xi = lrelu(gd*sl1 + bl1);
        size_t nb = ((size_t)b*NP + id)*H + c;
        W[k] = xi*(k1[nb] - qc);
        V[k] = v1[nb];
    }
    float m = W[0];
    #pragma unroll
    for (int k=1;k<KNN;k++) m = fmaxf(m, W[k]);
    float den = 0.f, acc = 0.f;
    #pragma unroll
    for (int k=0;k<KNN;k++){
        float e = __expf(W[k]-m);
        den += e; acc = fmaf(e, V[k], acc);
    }
    float outc = acc/den;

    // feat2 = lrelu(cbn(out, p1_w2)) via LDS broadcast matvec
    bc[hw][c] = outc;
    float f2a = 0.f;
    #pragma unroll
    for (int jj=0;jj<8;jj++){
        float4 xv = *(const float4*)&bc[hw][jj*4];
        float4 wv4 = *(const float4*)&wl[0][c*36 + jj*4];
        f2a += wv4.x*xv.x + wv4.y*xv.y + wv4.z*xv.z + wv4.w*xv.w;
    }
    float f2 = lrelu(f2a*s2[c] + b2[c]);

    bc[hw][c] = f2;
    float aq=0.f, ak=0.f, av=0.f;
    #pragma unroll
    for (int jj=0;jj<8;jj++){
        float4 xv = *(const float4*)&bc[hw][jj*4];
        float4 wq4 = *(const float4*)&wl[1][c*36 + jj*4];
        float4 wk4 = *(const float4*)&wl[2][c*36 + jj*4];
        float4 wv4 = *(const float4*)&wl[3][c*36 + jj*4];
        aq += wq4.x*xv.x + wq4.y*xv.y + wq4.z*xv.z + wq4.w*xv.w;
        ak += wk4.x*xv.x + wk4.y*xv.y + wk4.z*xv.z + wk4.w*xv.w;
        av += wv4.x*xv.x + wv4.y*xv.y + wv4.z*xv.z + wv4.w*xv.w;
    }
    size_t base = (size_t)p*H + c;
    q2[base] = reluf(aq*sq[c]+bq[c]);
    k2[base] = reluf(ak*sk[c]+bk[c]);
    v2[base] = reluf(av*sv[c]+bv[c]);
}

// ---------------- K3: pool2 -> feat3 channel-major [64][PN]
__global__ __launch_bounds__(256) void k_pool2(
    const float* __restrict__ xpos, const int* __restrict__ nidx,
    const float* __restrict__ q2, const float* __restrict__ k2, const float* __restrict__ v2,
    const float* __restrict__ l1w, const float* __restrict__ l1s, const float* __restrict__ l1b,
    const float* __restrict__ l2w, const float* __restrict__ l2s, const float* __restrict__ l2b,
    const float* __restrict__ w2, const float* __restrict__ s2, const float* __restrict__ b2,
    float* __restrict__ f3T)
{
    __shared__ float we[64*36];      // p2_w2 rows padded to 36
    __shared__ float bc[2][8][32];
    int t = threadIdx.x;
    for (int i=t;i<2048;i+=256) we[(i>>5)*36 + (i&31)] = w2[i];
    __syncthreads();

    int c = t & 31;
    int hw = t >> 5;
    int p = blockIdx.x*8 + hw;
    int b = p >> 12, n = p & (NP-1);

    float wl1r[10];
    #pragma unroll
    for (int j=0;j<10;j++) wl1r[j] = l1w[c*10+j];
    float sl1 = l1s[c], bl1 = l1b[c];
    float wl2r[32];
    #pragma unroll
    for (int j=0;j<32;j++) wl2r[j] = l2w[c*32+j];
    float sl2 = l2s[c], bl2 = l2b[c];

    const float* xb = xpos + (size_t)b*3*NP;
    float cx = xb[n], cy = xb[NP+n], cz = xb[2*NP+n];
    float qc = q2[(size_t)p*H + c];
    const int* irow = nidx + (size_t)p*KNN;
    int idxs[KNN];
    #pragma unroll
    for (int k=0;k<KNN;k++) idxs[k] = irow[k];

    float W[KNN], V[KNN];
    #pragma unroll
    for (int k=0;k<KNN;k++){
        int id = idxs[k];
        float kx = xb[id], ky = xb[NP+id], kz = xb[2*NP+id];
        float dx = kx-cx, dy = ky-cy, dz = kz-cz;
        float dist = sqrtf(dx*dx+dy*dy+dz*dz + 1e-12f);
        float gd = wl1r[0]*cx + wl1r[1]*cy + wl1r[2]*cz
                 + wl1r[3]*kx + wl1r[4]*ky + wl1r[5]*kz
                 + wl1r[6]*dx + wl1r[7]*dy + wl1r[8]*dz + wl1r[9]*dist;
        float xi = lrelu(gd*sl1 + bl1);
        bc[k&1][hw][c] = xi;
        float a0=0.f, a1=0.f;
        #pragma unroll
        for (int jj=0;jj<8;jj++){
            float4 xv = *(const float4*)&bc[k&1][hw][jj*4];
            a0 = fmaf(wl2r[jj*4+0],xv.x,a0); a1 = fmaf(wl2r[jj*4+1],xv.y,a1);
            a0 = fmaf(wl2r[jj*4+2],xv.z,a0); a1 = fmaf(wl2r[jj*4+3],xv.w,a1);
        }
        float xi2 = lrelu((a0+a1)*sl2 + bl2);
        size_t nb = ((size_t)b*NP + id)*H + c;
        W[k] = xi2*(k2[nb] - qc);
        V[k] = v2[nb];
    }
    float m = W[0];
    #pragma unroll
    for (int k=1;k<KNN;k++) m = fmaxf(m, W[k]);
    float den = 0.f, acc = 0.f;
    #pragma unroll
    for (int k=0;k<KNN;k++){
        float e = __expf(W[k]-m);
        den += e; acc = fmaf(e, V[k], acc);
    }
    float outc = acc/den;

    // feat3 = lrelu(cbn(out, p2_w2)) rows c and c+32; write channel-major
    bc[0][hw][c] = outc;
    float fa=0.f, fb2=0.f;
    #pragma unroll
    for (int jj=0;jj<8;jj++){
        float4 xv  = *(const float4*)&bc[0][hw][jj*4];
        float4 wa4 = *(const float4*)&we[c*36 + jj*4];
        float4 wb4 = *(const float4*)&we[(c+32)*36 + jj*4];
        fa  += wa4.x*xv.x + wa4.y*xv.y + wa4.z*xv.z + wa4.w*xv.w;
        fb2 += wb4.x*xv.x + wb4.y*xv.y + wb4.z*xv.z + wb4.w*xv.w;
    }
    f3T[(size_t)c*PN + p]      = lrelu(fa *s2[c]    + b2[c]);
    f3T[(size_t)(c+32)*PN + p] = lrelu(fb2*s2[c+32] + b2[c+32]);
}

// ---------------- K4: out = lrelu(cbn(feat3,mlp2) + cbn(ft,res)) -> [B,128,N]
// 4 output-groups per point; lane = point (coalesced); weights via s_load rows.
__global__ __launch_bounds__(256) void k_final(
    const float* __restrict__ feat, const float* __restrict__ f3T,
    const float* __restrict__ m2w, const float* __restrict__ m2s, const float* __restrict__ m2b,
    const float* __restrict__ rw, const float* __restrict__ rs, const float* __restrict__ rb,
    float* __restrict__ out)
{
    int t = threadIdx.x;
    int lane = t & 63;
    int og = __builtin_amdgcn_readfirstlane(t >> 6);
    size_t p = (size_t)blockIdx.x*64 + lane;
    int b = (int)(p >> 12), n = (int)(p & (NP-1));

    float xf[64];
    #pragma unroll
    for (int c=0;c<64;c++) xf[c] = f3T[(size_t)c*PN + p];   // coalesced (channel-major)
    float pm[32];
    #pragma unroll
    for (int j=0;j<32;j++){
        const float* wr = m2w + (size_t)(og*32+j)*OCC;      // wave-uniform -> s_load
        float a0=0.f, a1=0.f;
        #pragma unroll
        for (int c=0;c<64;c+=2){ a0 = fmaf(wr[c],xf[c],a0); a1 = fmaf(wr[c+1],xf[c+1],a1); }
        pm[j] = a0+a1;
    }
    const float* fb = feat + ((size_t)b*CIN)*NP + n;
    #pragma unroll
    for (int c=0;c<64;c++) xf[c] = fb[(size_t)c*NP];        // coalesced
    float* ob = out + ((size_t)b*128)*NP + n;
    #pragma unroll
    for (int j=0;j<32;j++){
        int o = og*32+j;
        const float* wr = rw + (size_t)o*CIN;
        float a0=0.f, a1=0.f;
        #pragma unroll
        for (int c=0;c<64;c+=2){ a0 = fmaf(wr[c],xf[c],a0); a1 = fmaf(wr[c+1],xf[c+1],a1); }
        float v = pm[j]*m2s[o]+m2b[o] + (a0+a1)*rs[o]+rb[o];
        ob[(size_t)o*NP] = lrelu(v);
    }
}

extern "C" void kernel_launch(void* const* d_in, const int* in_sizes, int n_in,
                              void* d_out, int out_size, void* d_ws, size_t ws_size,
                              hipStream_t stream)
{
    (void)in_sizes; (void)n_in; (void)out_size; (void)ws_size;
    const float* x     = (const float*)d_in[0];
    const float* feat  = (const float*)d_in[1];
    const int*   nidx  = (const int*)  d_in[2];
    const float* m1w=(const float*)d_in[3],  *m1s=(const float*)d_in[4],  *m1b=(const float*)d_in[5];
    const float* l1w=(const float*)d_in[6],  *l1s=(const float*)d_in[7],  *l1b=(const float*)d_in[8];
    const float* p1wq=(const float*)d_in[9],  *p1sq=(const float*)d_in[10], *p1bq=(const float*)d_in[11];
    const float* p1wk=(const float*)d_in[12], *p1sk=(const float*)d_in[13], *p1bk=(const float*)d_in[14];
    const float* p1wv=(const float*)d_in[15], *p1sv=(const float*)d_in[16], *p1bv=(const float*)d_in[17];
    const float* p1w2=(const float*)d_in[18], *p1s2=(const float*)d_in[19], *p1b2=(const float*)d_in[20];
    const float* p2wq=(const float*)d_in[21], *p2sq=(const float*)d_in[22], *p2bq=(const float*)d_in[23];
    const float* p2wk=(const float*)d_in[24], *p2sk=(const float*)d_in[25], *p2bk=(const float*)d_in[26];
    const float* p2wv=(const float*)d_in[27], *p2sv=(const float*)d_in[28], *p2bv=(const float*)d_in[29];
    const float* p2w2=(const float*)d_in[30], *p2s2=(const float*)d_in[31], *p2b2=(const float*)d_in[32];
    const float* l2w=(const float*)d_in[33], *l2s=(const float*)d_in[34], *l2b=(const float*)d_in[35];
    const float* m2w=(const float*)d_in[36], *m2s=(const float*)d_in[37], *m2b=(const float*)d_in[38];
    const float* rw =(const float*)d_in[39], *rs =(const float*)d_in[40], *rb =(const float*)d_in[41];

    float* ws = (float*)d_ws;
    float* q1 = ws;
    float* k1 = q1 + PN*H;
    float* v1 = k1 + PN*H;
    float* q2 = v1 + PN*H;
    float* k2 = q2 + PN*H;
    float* v2 = k2 + PN*H;
    float* f3T = v2 + PN*H;               // PN*64 floats, channel-major

    float* outp = (float*)d_out;

    k_pointwise<<<dim3(PN/256),dim3(256),0,stream>>>(feat, m1w,m1s,m1b,
        p1wq,p1sq,p1bq, p1wk,p1sk,p1bk, p1wv,p1sv,p1bv, q1,k1,v1);
    k_pool1<<<dim3(PN/8),dim3(256),0,stream>>>(x,nidx, q1,k1,v1,
        l1w,l1s,l1b, p1w2,p1s2,p1b2,
        p2wq,p2sq,p2bq, p2wk,p2sk,p2bk, p2wv,p2sv,p2bv, q2,k2,v2);
    k_pool2<<<dim3(PN/8),dim3(256),0,stream>>>(x,nidx, q2,k2,v2,
        l1w,l1s,l1b, l2w,l2s,l2b, p2w2,p2s2,p2b2, f3T);
    k_final<<<dim3(PN/64),dim3(256),0,stream>>>(feat, f3T, m2w,m2s,m2b, rw,rs,rb, outp);
}

// Round 3
// 572.295 us; speedup vs baseline: 1.9249x; 1.0937x over previous
//
#include <hip/hip_runtime.h>
#include <cstdint>
#include <cstddef>

#define NB 16
#define NP 4096
#define KNN 16
#define CIN 64
#define H 32
#define OCC 64
#define PN ((size_t)NB*NP)

__device__ __forceinline__ float lrelu(float v){ return v > 0.f ? v : 0.2f*v; }
__device__ __forceinline__ float reluf(float v){ return v > 0.f ? v : 0.f; }

// ---------------- K1: f1 = lrelu(cbn(ft,mlp1)); q1/k1/v1 = relu(cbn(f1,p1_*))
// Block = 64 points x 4 channel-groups. LDS-staged tiles, grid 1024 blocks.
__global__ __launch_bounds__(256) void k_pointwise(
    const float* __restrict__ feat,
    const float* __restrict__ w1, const float* __restrict__ s1, const float* __restrict__ b1,
    const float* __restrict__ wq, const float* __restrict__ sq, const float* __restrict__ bq,
    const float* __restrict__ wk, const float* __restrict__ sk, const float* __restrict__ bk,
    const float* __restrict__ wv, const float* __restrict__ sv, const float* __restrict__ bv,
    float* __restrict__ q1, float* __restrict__ k1, float* __restrict__ v1)
{
    __shared__ float ftile[CIN][65];   // [channel][point]
    __shared__ float f1t[H][65];       // [h][point]
    int t = threadIdx.x;
    int l = t & 63;                    // point within tile
    int g = __builtin_amdgcn_readfirstlane(t >> 6);   // channel group 0..3
    int bid = blockIdx.x;
    int b  = bid >> 6;
    int n0 = (bid & 63) * 64;
    size_t p = (size_t)b*NP + n0 + l;

    const float* fb = feat + ((size_t)b*CIN)*NP + n0 + l;
    #pragma unroll
    for (int k=0;k<16;k++){
        int c = g*16 + k;
        ftile[c][l] = fb[(size_t)c*NP];      // coalesced 256B rows
    }
    __syncthreads();

    float acc[8];
    #pragma unroll
    for (int u=0;u<8;u++) acc[u] = 0.f;
    #pragma unroll
    for (int c=0;c<CIN;c++){
        float x = ftile[c][l];
        #pragma unroll
        for (int u=0;u<8;u++) acc[u] = fmaf(w1[(g*8+u)*CIN+c], x, acc[u]);
    }
    #pragma unroll
    for (int u=0;u<8;u++){
        int h = g*8+u;
        f1t[h][l] = lrelu(acc[u]*s1[h] + b1[h]);
    }
    __syncthreads();

    float aq[8], ak[8], av[8];
    #pragma unroll
    for (int u=0;u<8;u++){ aq[u]=0.f; ak[u]=0.f; av[u]=0.f; }
    #pragma unroll
    for (int j=0;j<H;j++){
        float x = f1t[j][l];
        #pragma unroll
        for (int u=0;u<8;u++){
            int h = g*8+u;
            aq[u] = fmaf(wq[h*H+j], x, aq[u]);
            ak[u] = fmaf(wk[h*H+j], x, ak[u]);
            av[u] = fmaf(wv[h*H+j], x, av[u]);
        }
    }
    size_t base = p*H + g*8;
    float qr[8], kr[8], vr[8];
    #pragma unroll
    for (int u=0;u<8;u++){
        int h = g*8+u;
        qr[u] = reluf(aq[u]*sq[h]+bq[h]);
        kr[u] = reluf(ak[u]*sk[h]+bk[h]);
        vr[u] = reluf(av[u]*sv[h]+bv[h]);
    }
    *(float4*)(q1+base)   = make_float4(qr[0],qr[1],qr[2],qr[3]);
    *(float4*)(q1+base+4) = make_float4(qr[4],qr[5],qr[6],qr[7]);
    *(float4*)(k1+base)   = make_float4(kr[0],kr[1],kr[2],kr[3]);
    *(float4*)(k1+base+4) = make_float4(kr[4],kr[5],kr[6],kr[7]);
    *(float4*)(v1+base)   = make_float4(vr[0],vr[1],vr[2],vr[3]);
    *(float4*)(v1+base+4) = make_float4(vr[4],vr[5],vr[6],vr[7]);
}

// ---------------- K2: pool1 + fused q2/k2/v2.  Half-wave = one point, lane = channel.
__global__ __launch_bounds__(256) void k_pool1(
    const float* __restrict__ xpos, const int* __restrict__ nidx,
    const float* __restrict__ q1, const float* __restrict__ k1, const float* __restrict__ v1,
    const float* __restrict__ l1w, const float* __restrict__ l1s, const float* __restrict__ l1b,
    const float* __restrict__ w2, const float* __restrict__ s2, const float* __restrict__ b2,
    const float* __restrict__ wq, const float* __restrict__ sq, const float* __restrict__ bq,
    const float* __restrict__ wk, const float* __restrict__ sk, const float* __restrict__ bk,
    const float* __restrict__ wv, const float* __restrict__ sv, const float* __restrict__ bv,
    float* __restrict__ q2, float* __restrict__ k2, float* __restrict__ v2)
{
    __shared__ float wl[4][32*36];   // w2, wq, wk, wv  (rows padded to 36)
    __shared__ float bc[8][32];      // per-half-wave broadcast slot
    int t = threadIdx.x;
    {
        const float* wsrc[4] = {w2, wq, wk, wv};
        #pragma unroll
        for (int m=0;m<4;m++)
            for (int i=t;i<1024;i+=256)
                wl[m][(i>>5)*36 + (i&31)] = wsrc[m][i];
    }
    __syncthreads();

    int c = t & 31;
    int hw = t >> 5;
    int p = blockIdx.x*8 + hw;
    int b = p >> 12, n = p & (NP-1);

    float wl1r[10];
    #pragma unroll
    for (int j=0;j<10;j++) wl1r[j] = l1w[c*10+j];
    float sl1 = l1s[c], bl1 = l1b[c];

    const float* xb = xpos + (size_t)b*3*NP;
    float cx = xb[n], cy = xb[NP+n], cz = xb[2*NP+n];
    float qc = q1[(size_t)p*H + c];
    const int* irow = nidx + (size_t)p*KNN;
    int idxs[KNN];
    #pragma unroll
    for (int k=0;k<KNN;k++) idxs[k] = irow[k];

    float W[KNN], V[KNN];
    #pragma unroll
    for (int k=0;k<KNN;k++){
        int id = idxs[k];
        float kx = xb[id], ky = xb[NP+id], kz = xb[2*NP+id];
        float dx = kx-cx, dy = ky-cy, dz = kz-cz;
        float dist = sqrtf(dx*dx+dy*dy+dz*dz + 1e-12f);
        float gd = wl1r[0]*cx + wl1r[1]*cy + wl1r[2]*cz
                 + wl1r[3]*kx + wl1r[4]*ky + wl1r[5]*kz
                 + wl1r[6]*dx + wl1r[7]*dy + wl1r[8]*dz + wl1r[9]*dist;
        float xi = lrelu(gd*sl1 + bl1);
        size_t nb = ((size_t)b*NP + id)*H + c;
        W[k] = xi*(k1[nb] - qc);
        V[k] = v1[nb];
    }
    float m = W[0];
    #pragma unroll
    for (int k=1;k<KNN;k++) m = fmaxf(m, W[k]);
    float den = 0.f, acc = 0.f;
    #pragma unroll
    for (int k=0;k<KNN;k++){
        float e = __expf(W[k]-m);
        den += e; acc = fmaf(e, V[k], acc);
    }
    float outc = acc/den;

    // feat2 = lrelu(cbn(out, p1_w2)) via LDS broadcast matvec
    bc[hw][c] = outc;
    float f2a = 0.f;
    #pragma unroll
    for (int jj=0;jj<8;jj++){
        float4 xv = *(const float4*)&bc[hw][jj*4];
        float4 wv4 = *(const float4*)&wl[0][c*36 + jj*4];
        f2a += wv4.x*xv.x + wv4.y*xv.y + wv4.z*xv.z + wv4.w*xv.w;
    }
    float f2 = lrelu(f2a*s2[c] + b2[c]);

    bc[hw][c] = f2;
    float aq=0.f, ak=0.f, av=0.f;
    #pragma unroll
    for (int jj=0;jj<8;jj++){
        float4 xv = *(const float4*)&bc[hw][jj*4];
        float4 wq4 = *(const float4*)&wl[1][c*36 + jj*4];
        float4 wk4 = *(const float4*)&wl[2][c*36 + jj*4];
        float4 wv4 = *(const float4*)&wl[3][c*36 + jj*4];
        aq += wq4.x*xv.x + wq4.y*xv.y + wq4.z*xv.z + wq4.w*xv.w;
        ak += wk4.x*xv.x + wk4.y*xv.y + wk4.z*xv.z + wk4.w*xv.w;
        av += wv4.x*xv.x + wv4.y*xv.y + wv4.z*xv.z + wv4.w*xv.w;
    }
    size_t base = (size_t)p*H + c;
    q2[base] = reluf(aq*sq[c]+bq[c]);
    k2[base] = reluf(ak*sk[c]+bk[c]);
    v2[base] = reluf(av*sv[c]+bv[c]);
}

// ---------------- K3: pool2 -> feat3 channel-major [64][PN]
__global__ __launch_bounds__(256) void k_pool2(
    const float* __restrict__ xpos, const int* __restrict__ nidx,
    const float* __restrict__ q2, const float* __restrict__ k2, const float* __restrict__ v2,
    const float* __restrict__ l1w, const float* __restrict__ l1s, const float* __restrict__ l1b,
    const float* __restrict__ l2w, const float* __restrict__ l2s, const float* __restrict__ l2b,
    const float* __restrict__ w2, const float* __restrict__ s2, const float* __restrict__ b2,
    float* __restrict__ f3T)
{
    __shared__ float we[64*36];      // p2_w2 rows padded to 36
    __shared__ float bc[2][8][32];
    int t = threadIdx.x;
    for (int i=t;i<2048;i+=256) we[(i>>5)*36 + (i&31)] = w2[i];
    __syncthreads();

    int c = t & 31;
    int hw = t >> 5;
    int p = blockIdx.x*8 + hw;
    int b = p >> 12, n = p & (NP-1);

    float wl1r[10];
    #pragma unroll
    for (int j=0;j<10;j++) wl1r[j] = l1w[c*10+j];
    float sl1 = l1s[c], bl1 = l1b[c];
    float wl2r[32];
    #pragma unroll
    for (int j=0;j<32;j++) wl2r[j] = l2w[c*32+j];
    float sl2 = l2s[c], bl2 = l2b[c];

    const float* xb = xpos + (size_t)b*3*NP;
    float cx = xb[n], cy = xb[NP+n], cz = xb[2*NP+n];
    float qc = q2[(size_t)p*H + c];
    const int* irow = nidx + (size_t)p*KNN;
    int idxs[KNN];
    #pragma unroll
    for (int k=0;k<KNN;k++) idxs[k] = irow[k];

    float W[KNN], V[KNN];
    #pragma unroll
    for (int k=0;k<KNN;k++){
        int id = idxs[k];
        float kx = xb[id], ky = xb[NP+id], kz = xb[2*NP+id];
        float dx = kx-cx, dy = ky-cy, dz = kz-cz;
        float dist = sqrtf(dx*dx+dy*dy+dz*dz + 1e-12f);
        float gd = wl1r[0]*cx + wl1r[1]*cy + wl1r[2]*cz
                 + wl1r[3]*kx + wl1r[4]*ky + wl1r[5]*kz
                 + wl1r[6]*dx + wl1r[7]*dy + wl1r[8]*dz + wl1r[9]*dist;
        float xi = lrelu(gd*sl1 + bl1);
        bc[k&1][hw][c] = xi;
        float a0=0.f, a1=0.f;
        #pragma unroll
        for (int jj=0;jj<8;jj++){
            float4 xv = *(const float4*)&bc[k&1][hw][jj*4];
            a0 = fmaf(wl2r[jj*4+0],xv.x,a0); a1 = fmaf(wl2r[jj*4+1],xv.y,a1);
            a0 = fmaf(wl2r[jj*4+2],xv.z,a0); a1 = fmaf(wl2r[jj*4+3],xv.w,a1);
        }
        float xi2 = lrelu((a0+a1)*sl2 + bl2);
        size_t nb = ((size_t)b*NP + id)*H + c;
        W[k] = xi2*(k2[nb] - qc);
        V[k] = v2[nb];
    }
    float m = W[0];
    #pragma unroll
    for (int k=1;k<KNN;k++) m = fmaxf(m, W[k]);
    float den = 0.f, acc = 0.f;
    #pragma unroll
    for (int k=0;k<KNN;k++){
        float e = __expf(W[k]-m);
        den += e; acc = fmaf(e, V[k], acc);
    }
    float outc = acc/den;

    // feat3 = lrelu(cbn(out, p2_w2)) rows c and c+32; write channel-major
    bc[0][hw][c] = outc;
    float fa=0.f, fb2=0.f;
    #pragma unroll
    for (int jj=0;jj<8;jj++){
        float4 xv  = *(const float4*)&bc[0][hw][jj*4];
        float4 wa4 = *(const float4*)&we[c*36 + jj*4];
        float4 wb4 = *(const float4*)&we[(c+32)*36 + jj*4];
        fa  += wa4.x*xv.x + wa4.y*xv.y + wa4.z*xv.z + wa4.w*xv.w;
        fb2 += wb4.x*xv.x + wb4.y*xv.y + wb4.z*xv.z + wb4.w*xv.w;
    }
    f3T[(size_t)c*PN + p]      = lrelu(fa *s2[c]    + b2[c]);
    f3T[(size_t)(c+32)*PN + p] = lrelu(fb2*s2[c+32] + b2[c+32]);
}

// ---------------- K4: out = lrelu(cbn(feat3,mlp2) + cbn(ft,res)) -> [B,128,N]
// Thread = (point, 16-output group); 8 groups/point; grid 2048 blocks.
__global__ __launch_bounds__(256) void k_final(
    const float* __restrict__ feat, const float* __restrict__ f3T,
    const float* __restrict__ m2w, const float* __restrict__ m2s, const float* __restrict__ m2b,
    const float* __restrict__ rw, const float* __restrict__ rs, const float* __restrict__ rb,
    float* __restrict__ out)
{
    int t = threadIdx.x;
    int lane = t & 63;
    int bid = blockIdx.x;
    int tile = bid >> 1;
    int og = __builtin_amdgcn_readfirstlane(((bid & 1) << 2) + (t >> 6));  // 0..7
    size_t p = (size_t)tile*64 + lane;
    int b = (int)(p >> 12), n = (int)(p & (NP-1));
    int o0 = og*16;

    float xf[64];
    #pragma unroll
    for (int c=0;c<64;c++) xf[c] = f3T[(size_t)c*PN + p];   // coalesced (channel-major)
    float pm[16];
    #pragma unroll
    for (int j=0;j<16;j++){
        const float* wr = m2w + (size_t)(o0+j)*OCC;          // wave-uniform -> s_load
        float a0=0.f, a1=0.f;
        #pragma unroll
        for (int c=0;c<64;c+=2){ a0 = fmaf(wr[c],xf[c],a0); a1 = fmaf(wr[c+1],xf[c+1],a1); }
        pm[j] = a0+a1;
    }
    const float* fb = feat + ((size_t)b*CIN)*NP + n;
    #pragma unroll
    for (int c=0;c<64;c++) xf[c] = fb[(size_t)c*NP];        // coalesced
    float* ob = out + ((size_t)b*128)*NP + n;
    #pragma unroll
    for (int j=0;j<16;j++){
        int o = o0+j;
        const float* wr = rw + (size_t)o*CIN;
        float a0=0.f, a1=0.f;
        #pragma unroll
        for (int c=0;c<64;c+=2){ a0 = fmaf(wr[c],xf[c],a0); a1 = fmaf(wr[c+1],xf[c+1],a1); }
        float v = pm[j]*m2s[o]+m2b[o] + (a0+a1)*rs[o]+rb[o];
        ob[(size_t)o*NP] = lrelu(v);
    }
}

extern "C" void kernel_launch(void* const* d_in, const int* in_sizes, int n_in,
                              void* d_out, int out_size, void* d_ws, size_t ws_size,
                              hipStream_t stream)
{
    (void)in_sizes; (void)n_in; (void)out_size; (void)ws_size;
    const float* x     = (const float*)d_in[0];
    const float* feat  = (const float*)d_in[1];
    const int*   nidx  = (const int*)  d_in[2];
    const float* m1w=(const float*)d_in[3],  *m1s=(const float*)d_in[4],  *m1b=(const float*)d_in[5];
    const float* l1w=(const float*)d_in[6],  *l1s=(const float*)d_in[7],  *l1b=(const float*)d_in[8];
    const float* p1wq=(const float*)d_in[9],  *p1sq=(const float*)d_in[10], *p1bq=(const float*)d_in[11];
    const float* p1wk=(const float*)d_in[12], *p1sk=(const float*)d_in[13], *p1bk=(const float*)d_in[14];
    const float* p1wv=(const float*)d_in[15], *p1sv=(const float*)d_in[16], *p1bv=(const float*)d_in[17];
    const float* p1w2=(const float*)d_in[18], *p1s2=(const float*)d_in[19], *p1b2=(const float*)d_in[20];
    const float* p2wq=(const float*)d_in[21], *p2sq=(const float*)d_in[22], *p2bq=(const float*)d_in[23];
    const float* p2wk=(const float*)d_in[24], *p2sk=(const float*)d_in[25], *p2bk=(const float*)d_in[26];
    const float* p2wv=(const float*)d_in[27], *p2sv=(const float*)d_in[28], *p2bv=(const float*)d_in[29];
    const float* p2w2=(const float*)d_in[30], *p2s2=(const float*)d_in[31], *p2b2=(const float*)d_in[32];
    const float* l2w=(const float*)d_in[33], *l2s=(const float*)d_in[34], *l2b=(const float*)d_in[35];
    const float* m2w=(const float*)d_in[36], *m2s=(const float*)d_in[37], *m2b=(const float*)d_in[38];
    const float* rw =(const float*)d_in[39], *rs =(const float*)d_in[40], *rb =(const float*)d_in[41];

    float* ws = (float*)d_ws;
    float* q1 = ws;
    float* k1 = q1 + PN*H;
    float* v1 = k1 + PN*H;
    float* q2 = v1 + PN*H;
    float* k2 = q2 + PN*H;
    float* v2 = k2 + PN*H;
    float* f3T = v2 + PN*H;               // PN*64 floats, channel-major

    float* outp = (float*)d_out;

    k_pointwise<<<dim3(PN/64),dim3(256),0,stream>>>(feat, m1w,m1s,m1b,
        p1wq,p1sq,p1bq, p1wk,p1sk,p1bk, p1wv,p1sv,p1bv, q1,k1,v1);
    k_pool1<<<dim3(PN/8),dim3(256),0,stream>>>(x,nidx, q1,k1,v1,
        l1w,l1s,l1b, p1w2,p1s2,p1b2,
        p2wq,p2sq,p2bq, p2wk,p2sk,p2bk, p2wv,p2sv,p2bv, q2,k2,v2);
    k_pool2<<<dim3(PN/8),dim3(256),0,stream>>>(x,nidx, q2,k2,v2,
        l1w,l1s,l1b, l2w,l2s,l2b, p2w2,p2s2,p2b2, f3T);
    k_final<<<dim3(PN/32),dim3(256),0,stream>>>(feat, f3T, m2w,m2s,m2b, rw,rs,rb, outp);
}

// Round 4
// 525.637 us; speedup vs baseline: 2.0957x; 1.0888x over previous
//
#include <hip/hip_runtime.h>
#include <cstdint>
#include <cstddef>

#define NB 16
#define NP 4096
#define KNN 16
#define CIN 64
#define H 32
#define OCC 64
#define PN ((size_t)NB*NP)

__device__ __forceinline__ float lrelu(float v){ return v > 0.f ? v : 0.2f*v; }
__device__ __forceinline__ float reluf(float v){ return v > 0.f ? v : 0.f; }

// ---------------- K1: f1 = lrelu(cbn(ft,mlp1)); q1/kv1 = relu(cbn(f1,p1_*))
// Also emits xp[p] = packed float4 xyz and ftp[p][64] = transposed feature copy.
__global__ __launch_bounds__(256) void k_pointwise(
    const float* __restrict__ feat, const float* __restrict__ xpos,
    const float* __restrict__ w1, const float* __restrict__ s1, const float* __restrict__ b1,
    const float* __restrict__ wq, const float* __restrict__ sq, const float* __restrict__ bq,
    const float* __restrict__ wk, const float* __restrict__ sk, const float* __restrict__ bk,
    const float* __restrict__ wv, const float* __restrict__ sv, const float* __restrict__ bv,
    float* __restrict__ q1, float* __restrict__ kv1,
    float* __restrict__ xp, float* __restrict__ ftp)
{
    __shared__ float ftile[CIN][65];   // [channel][point]
    __shared__ float f1t[H][65];       // [h][point]
    int t = threadIdx.x;
    int l = t & 63;                    // point within tile
    int g = __builtin_amdgcn_readfirstlane(t >> 6);   // channel group 0..3
    int bid = blockIdx.x;
    int b  = bid >> 6;
    int n0 = (bid & 63) * 64;
    int n  = n0 + l;
    size_t p = (size_t)b*NP + n;

    const float* fb = feat + ((size_t)b*CIN)*NP + n;
    float fv[16];
    #pragma unroll
    for (int k=0;k<16;k++){
        int c = g*16 + k;
        fv[k] = fb[(size_t)c*NP];      // coalesced 256B rows
        ftile[c][l] = fv[k];
    }
    // transposed feature copy for k_final (point-major)
    #pragma unroll
    for (int k4=0;k4<4;k4++)
        *(float4*)(ftp + p*64 + g*16 + k4*4) =
            make_float4(fv[k4*4],fv[k4*4+1],fv[k4*4+2],fv[k4*4+3]);
    // packed xyz
    if (g == 0){
        const float* xb = xpos + (size_t)b*3*NP;
        *(float4*)(xp + 4*p) = make_float4(xb[n], xb[NP+n], xb[2*NP+n], 0.f);
    }
    __syncthreads();

    float acc[8];
    #pragma unroll
    for (int u=0;u<8;u++) acc[u] = 0.f;
    #pragma unroll
    for (int c=0;c<CIN;c++){
        float x = ftile[c][l];
        #pragma unroll
        for (int u=0;u<8;u++) acc[u] = fmaf(w1[(g*8+u)*CIN+c], x, acc[u]);
    }
    #pragma unroll
    for (int u=0;u<8;u++){
        int h = g*8+u;
        f1t[h][l] = lrelu(acc[u]*s1[h] + b1[h]);
    }
    __syncthreads();

    float aq[8], ak[8], av[8];
    #pragma unroll
    for (int u=0;u<8;u++){ aq[u]=0.f; ak[u]=0.f; av[u]=0.f; }
    #pragma unroll
    for (int j=0;j<H;j++){
        float x = f1t[j][l];
        #pragma unroll
        for (int u=0;u<8;u++){
            int h = g*8+u;
            aq[u] = fmaf(wq[h*H+j], x, aq[u]);
            ak[u] = fmaf(wk[h*H+j], x, ak[u]);
            av[u] = fmaf(wv[h*H+j], x, av[u]);
        }
    }
    float qr[8], kr[8], vr[8];
    #pragma unroll
    for (int u=0;u<8;u++){
        int h = g*8+u;
        qr[u] = reluf(aq[u]*sq[h]+bq[h]);
        kr[u] = reluf(ak[u]*sk[h]+bk[h]);
        vr[u] = reluf(av[u]*sv[h]+bv[h]);
    }
    size_t qb = p*H + g*8;
    *(float4*)(q1+qb)   = make_float4(qr[0],qr[1],qr[2],qr[3]);
    *(float4*)(q1+qb+4) = make_float4(qr[4],qr[5],qr[6],qr[7]);
    size_t kb = (p*H + g*8)*2;
    #pragma unroll
    for (int u2=0;u2<4;u2++)
        *(float4*)(kv1+kb+u2*4) = make_float4(kr[u2*2],vr[u2*2],kr[u2*2+1],vr[u2*2+1]);
}

// ---------------- K2: pool1 + fused q2/kv2.  Half-wave = one point, lane = channel.
__global__ __launch_bounds__(256) void k_pool1(
    const float* __restrict__ xp, const int* __restrict__ nidx,
    const float* __restrict__ q1, const float* __restrict__ kv1,
    const float* __restrict__ l1w, const float* __restrict__ l1s, const float* __restrict__ l1b,
    const float* __restrict__ w2, const float* __restrict__ s2, const float* __restrict__ b2,
    const float* __restrict__ wq, const float* __restrict__ sq, const float* __restrict__ bq,
    const float* __restrict__ wk, const float* __restrict__ sk, const float* __restrict__ bk,
    const float* __restrict__ wv, const float* __restrict__ sv, const float* __restrict__ bv,
    float* __restrict__ q2, float* __restrict__ kv2)
{
    __shared__ float wl[4][32*36];   // w2, wq, wk, wv  (rows padded to 36)
    __shared__ float bc[8][32];      // per-half-wave broadcast slot
    int t = threadIdx.x;
    {
        const float* wsrc[4] = {w2, wq, wk, wv};
        #pragma unroll
        for (int m=0;m<4;m++)
            for (int i=t;i<1024;i+=256)
                wl[m][(i>>5)*36 + (i&31)] = wsrc[m][i];
    }
    __syncthreads();

    int c = t & 31;
    int hw = t >> 5;
    int p = blockIdx.x*8 + hw;
    int b = p >> 12;

    float wl1r[10];
    #pragma unroll
    for (int j=0;j<10;j++) wl1r[j] = l1w[c*10+j];
    float sl1 = l1s[c], bl1 = l1b[c];

    float4 cp = *(const float4*)(xp + 4*(size_t)p);
    float qc = q1[(size_t)p*H + c];
    const int* irow = nidx + (size_t)p*KNN;
    int idxs[KNN];
    #pragma unroll
    for (int k=0;k<KNN;k++) idxs[k] = irow[k];

    float W[KNN], V[KNN];
    #pragma unroll
    for (int k=0;k<KNN;k++){
        int id = idxs[k];
        float4 nv = *(const float4*)(xp + 4*((size_t)(b<<12) + id));
        float dx = nv.x-cp.x, dy = nv.y-cp.y, dz = nv.z-cp.z;
        float dist = sqrtf(dx*dx+dy*dy+dz*dz + 1e-12f);
        float gd = wl1r[0]*cp.x + wl1r[1]*cp.y + wl1r[2]*cp.z
                 + wl1r[3]*nv.x + wl1r[4]*nv.y + wl1r[5]*nv.z
                 + wl1r[6]*dx + wl1r[7]*dy + wl1r[8]*dz + wl1r[9]*dist;
        float xi = lrelu(gd*sl1 + bl1);
        float2 kv = *(const float2*)(kv1 + 2*(((size_t)b*NP + id)*H + c));
        W[k] = xi*(kv.x - qc);
        V[k] = kv.y;
    }
    float m = W[0];
    #pragma unroll
    for (int k=1;k<KNN;k++) m = fmaxf(m, W[k]);
    float den = 0.f, acc = 0.f;
    #pragma unroll
    for (int k=0;k<KNN;k++){
        float e = __expf(W[k]-m);
        den += e; acc = fmaf(e, V[k], acc);
    }
    float outc = acc/den;

    // feat2 = lrelu(cbn(out, p1_w2)) via LDS broadcast matvec
    bc[hw][c] = outc;
    float f2a = 0.f;
    #pragma unroll
    for (int jj=0;jj<8;jj++){
        float4 xv = *(const float4*)&bc[hw][jj*4];
        float4 wv4 = *(const float4*)&wl[0][c*36 + jj*4];
        f2a += wv4.x*xv.x + wv4.y*xv.y + wv4.z*xv.z + wv4.w*xv.w;
    }
    float f2 = lrelu(f2a*s2[c] + b2[c]);

    bc[hw][c] = f2;
    float aq=0.f, ak=0.f, av=0.f;
    #pragma unroll
    for (int jj=0;jj<8;jj++){
        float4 xv = *(const float4*)&bc[hw][jj*4];
        float4 wq4 = *(const float4*)&wl[1][c*36 + jj*4];
        float4 wk4 = *(const float4*)&wl[2][c*36 + jj*4];
        float4 wv4 = *(const float4*)&wl[3][c*36 + jj*4];
        aq += wq4.x*xv.x + wq4.y*xv.y + wq4.z*xv.z + wq4.w*xv.w;
        ak += wk4.x*xv.x + wk4.y*xv.y + wk4.z*xv.z + wk4.w*xv.w;
        av += wv4.x*xv.x + wv4.y*xv.y + wv4.z*xv.z + wv4.w*xv.w;
    }
    size_t base = (size_t)p*H + c;
    q2[base] = reluf(aq*sq[c]+bq[c]);
    float ko = reluf(ak*sk[c]+bk[c]);
    float vo = reluf(av*sv[c]+bv[c]);
    *(float2*)(kv2 + 2*base) = make_float2(ko, vo);
}

// ---------------- K3: pool2 -> feat3 point-major [PN][64]
__global__ __launch_bounds__(256) void k_pool2(
    const float* __restrict__ xp, const int* __restrict__ nidx,
    const float* __restrict__ q2, const float* __restrict__ kv2,
    const float* __restrict__ l1w, const float* __restrict__ l1s, const float* __restrict__ l1b,
    const float* __restrict__ l2w, const float* __restrict__ l2s, const float* __restrict__ l2b,
    const float* __restrict__ w2, const float* __restrict__ s2, const float* __restrict__ b2,
    float* __restrict__ f3)
{
    __shared__ float we[64*36];      // p2_w2 rows padded to 36
    __shared__ float bc[2][8][32];
    int t = threadIdx.x;
    for (int i=t;i<2048;i+=256) we[(i>>5)*36 + (i&31)] = w2[i];
    __syncthreads();

    int c = t & 31;
    int hw = t >> 5;
    int p = blockIdx.x*8 + hw;
    int b = p >> 12;

    float wl1r[10];
    #pragma unroll
    for (int j=0;j<10;j++) wl1r[j] = l1w[c*10+j];
    float sl1 = l1s[c], bl1 = l1b[c];
    float wl2r[32];
    #pragma unroll
    for (int j=0;j<32;j++) wl2r[j] = l2w[c*32+j];
    float sl2 = l2s[c], bl2 = l2b[c];

    float4 cp = *(const float4*)(xp + 4*(size_t)p);
    float qc = q2[(size_t)p*H + c];
    const int* irow = nidx + (size_t)p*KNN;
    int idxs[KNN];
    #pragma unroll
    for (int k=0;k<KNN;k++) idxs[k] = irow[k];

    float W[KNN], V[KNN];
    #pragma unroll
    for (int k=0;k<KNN;k++){
        int id = idxs[k];
        float4 nv = *(const float4*)(xp + 4*((size_t)(b<<12) + id));
        float dx = nv.x-cp.x, dy = nv.y-cp.y, dz = nv.z-cp.z;
        float dist = sqrtf(dx*dx+dy*dy+dz*dz + 1e-12f);
        float gd = wl1r[0]*cp.x + wl1r[1]*cp.y + wl1r[2]*cp.z
                 + wl1r[3]*nv.x + wl1r[4]*nv.y + wl1r[5]*nv.z
                 + wl1r[6]*dx + wl1r[7]*dy + wl1r[8]*dz + wl1r[9]*dist;
        float xi = lrelu(gd*sl1 + bl1);
        bc[k&1][hw][c] = xi;
        float a0=0.f, a1=0.f;
        #pragma unroll
        for (int jj=0;jj<8;jj++){
            float4 xv = *(const float4*)&bc[k&1][hw][jj*4];
            a0 = fmaf(wl2r[jj*4+0],xv.x,a0); a1 = fmaf(wl2r[jj*4+1],xv.y,a1);
            a0 = fmaf(wl2r[jj*4+2],xv.z,a0); a1 = fmaf(wl2r[jj*4+3],xv.w,a1);
        }
        float xi2 = lrelu((a0+a1)*sl2 + bl2);
        float2 kv = *(const float2*)(kv2 + 2*(((size_t)b*NP + id)*H + c));
        W[k] = xi2*(kv.x - qc);
        V[k] = kv.y;
    }
    float m = W[0];
    #pragma unroll
    for (int k=1;k<KNN;k++) m = fmaxf(m, W[k]);
    float den = 0.f, acc = 0.f;
    #pragma unroll
    for (int k=0;k<KNN;k++){
        float e = __expf(W[k]-m);
        den += e; acc = fmaf(e, V[k], acc);
    }
    float outc = acc/den;

    // feat3 = lrelu(cbn(out, p2_w2)) rows c and c+32; write point-major
    bc[0][hw][c] = outc;
    float fa=0.f, fb2=0.f;
    #pragma unroll
    for (int jj=0;jj<8;jj++){
        float4 xv  = *(const float4*)&bc[0][hw][jj*4];
        float4 wa4 = *(const float4*)&we[c*36 + jj*4];
        float4 wb4 = *(const float4*)&we[(c+32)*36 + jj*4];
        fa  += wa4.x*xv.x + wa4.y*xv.y + wa4.z*xv.z + wa4.w*xv.w;
        fb2 += wb4.x*xv.x + wb4.y*xv.y + wb4.z*xv.z + wb4.w*xv.w;
    }
    f3[(size_t)p*64 + c]      = lrelu(fa *s2[c]    + b2[c]);
    f3[(size_t)p*64 + 32 + c] = lrelu(fb2*s2[c+32] + b2[c+32]);
}

// ---------------- K4: out = lrelu(cbn(f3,mlp2) + cbn(ftp,res)) -> [B,128,N]
// Thread = (point, 16-output group); b128 operand loads; weights s_load rows.
__global__ __launch_bounds__(256) void k_final(
    const float* __restrict__ ftp, const float* __restrict__ f3,
    const float* __restrict__ m2w, const float* __restrict__ m2s, const float* __restrict__ m2b,
    const float* __restrict__ rw, const float* __restrict__ rs, const float* __restrict__ rb,
    float* __restrict__ out)
{
    int t = threadIdx.x;
    int lane = t & 63;
    int bid = blockIdx.x;
    int tile = bid >> 1;
    int og = __builtin_amdgcn_readfirstlane(((bid & 1) << 2) + (t >> 6));  // 0..7
    size_t p = (size_t)tile*64 + lane;
    int b = (int)(p >> 12), n = (int)(p & (NP-1));
    int o0 = og*16;

    float xf[64];
    {
        const float4* fp = (const float4*)(f3 + p*64);
        #pragma unroll
        for (int i=0;i<16;i++){
            float4 v = fp[i];
            xf[i*4]=v.x; xf[i*4+1]=v.y; xf[i*4+2]=v.z; xf[i*4+3]=v.w;
        }
    }
    float pm[16];
    #pragma unroll
    for (int j=0;j<16;j++){
        const float* wr = m2w + (size_t)(o0+j)*OCC;          // wave-uniform -> s_load
        float a0=0.f, a1=0.f;
        #pragma unroll
        for (int c=0;c<64;c+=2){ a0 = fmaf(wr[c],xf[c],a0); a1 = fmaf(wr[c+1],xf[c+1],a1); }
        pm[j] = a0+a1;
    }
    {
        const float4* gp = (const float4*)(ftp + p*64);
        #pragma unroll
        for (int i=0;i<16;i++){
            float4 v = gp[i];
            xf[i*4]=v.x; xf[i*4+1]=v.y; xf[i*4+2]=v.z; xf[i*4+3]=v.w;
        }
    }
    float* ob = out + ((size_t)b*128)*NP + n;
    #pragma unroll
    for (int j=0;j<16;j++){
        int o = o0+j;
        const float* wr = rw + (size_t)o*CIN;
        float a0=0.f, a1=0.f;
        #pragma unroll
        for (int c=0;c<64;c+=2){ a0 = fmaf(wr[c],xf[c],a0); a1 = fmaf(wr[c+1],xf[c+1],a1); }
        float v = pm[j]*m2s[o]+m2b[o] + (a0+a1)*rs[o]+rb[o];
        ob[(size_t)o*NP] = lrelu(v);
    }
}

extern "C" void kernel_launch(void* const* d_in, const int* in_sizes, int n_in,
                              void* d_out, int out_size, void* d_ws, size_t ws_size,
                              hipStream_t stream)
{
    (void)in_sizes; (void)n_in; (void)out_size; (void)ws_size;
    const float* x     = (const float*)d_in[0];
    const float* feat  = (const float*)d_in[1];
    const int*   nidx  = (const int*)  d_in[2];
    const float* m1w=(const float*)d_in[3],  *m1s=(const float*)d_in[4],  *m1b=(const float*)d_in[5];
    const float* l1w=(const float*)d_in[6],  *l1s=(const float*)d_in[7],  *l1b=(const float*)d_in[8];
    const float* p1wq=(const float*)d_in[9],  *p1sq=(const float*)d_in[10], *p1bq=(const float*)d_in[11];
    const float* p1wk=(const float*)d_in[12], *p1sk=(const float*)d_in[13], *p1bk=(const float*)d_in[14];
    const float* p1wv=(const float*)d_in[15], *p1sv=(const float*)d_in[16], *p1bv=(const float*)d_in[17];
    const float* p1w2=(const float*)d_in[18], *p1s2=(const float*)d_in[19], *p1b2=(const float*)d_in[20];
    const float* p2wq=(const float*)d_in[21], *p2sq=(const float*)d_in[22], *p2bq=(const float*)d_in[23];
    const float* p2wk=(const float*)d_in[24], *p2sk=(const float*)d_in[25], *p2bk=(const float*)d_in[26];
    const float* p2wv=(const float*)d_in[27], *p2sv=(const float*)d_in[28], *p2bv=(const float*)d_in[29];
    const float* p2w2=(const float*)d_in[30], *p2s2=(const float*)d_in[31], *p2b2=(const float*)d_in[32];
    const float* l2w=(const float*)d_in[33], *l2s=(const float*)d_in[34], *l2b=(const float*)d_in[35];
    const float* m2w=(const float*)d_in[36], *m2s=(const float*)d_in[37], *m2b=(const float*)d_in[38];
    const float* rw =(const float*)d_in[39], *rs =(const float*)d_in[40], *rb =(const float*)d_in[41];

    float* ws = (float*)d_ws;
    // layout (in floats, per-point widths): q1:32, kv1:64, q2:32, kv2:64, xp:4, ftp:64
    // f3 (64) aliases [q1,kv1) which are dead after k_pool1.
    float* q1  = ws;                    // PN*32
    float* kv1 = ws + PN*32;            // PN*64
    float* q2  = ws + PN*96;            // PN*32
    float* kv2 = ws + PN*128;           // PN*64
    float* xp  = ws + PN*192;           // PN*4
    float* ftp = ws + PN*196;           // PN*64
    float* f3  = ws;                    // PN*64 (aliases q1+kv1 region)

    float* outp = (float*)d_out;

    k_pointwise<<<dim3(PN/64),dim3(256),0,stream>>>(feat, x, m1w,m1s,m1b,
        p1wq,p1sq,p1bq, p1wk,p1sk,p1bk, p1wv,p1sv,p1bv, q1,kv1, xp, ftp);
    k_pool1<<<dim3(PN/8),dim3(256),0,stream>>>(xp,nidx, q1,kv1,
        l1w,l1s,l1b, p1w2,p1s2,p1b2,
        p2wq,p2sq,p2bq, p2wk,p2sk,p2bk, p2wv,p2sv,p2bv, q2,kv2);
    k_pool2<<<dim3(PN/8),dim3(256),0,stream>>>(xp,nidx, q2,kv2,
        l1w,l1s,l1b, l2w,l2s,l2b, p2w2,p2s2,p2b2, f3);
    k_final<<<dim3(PN/32),dim3(256),0,stream>>>(ftp, f3, m2w,m2s,m2b, rw,rs,rb, outp);
}

// Round 5
// 487.529 us; speedup vs baseline: 2.2595x; 1.0782x over previous
//
#include <hip/hip_runtime.h>
#include <cstdint>
#include <cstddef>

#define NB 16
#define NP 4096
#define KNN 16
#define CIN 64
#define H 32
#define OCC 64
#define PN ((size_t)NB*NP)

__device__ __forceinline__ float lrelu(float v){ return v > 0.f ? v : 0.2f*v; }
__device__ __forceinline__ float reluf(float v){ return v > 0.f ? v : 0.f; }

typedef __attribute__((ext_vector_type(8))) short bf16x8s;
typedef __attribute__((ext_vector_type(4))) float f32x4;

__device__ __forceinline__ short f2bf(float f){
    union { float f; unsigned u; } v; v.f = f;
    unsigned r = v.u + 0x7fffu + ((v.u >> 16) & 1u);   // RNE
    return (short)(r >> 16);
}

// ---------------- K1: f1 = lrelu(cbn(ft,mlp1)); q1/kv1 = relu(cbn(f1,p1_*))
__global__ __launch_bounds__(256) void k_pointwise(
    const float* __restrict__ feat, const float* __restrict__ xpos,
    const float* __restrict__ w1, const float* __restrict__ s1, const float* __restrict__ b1,
    const float* __restrict__ wq, const float* __restrict__ sq, const float* __restrict__ bq,
    const float* __restrict__ wk, const float* __restrict__ sk, const float* __restrict__ bk,
    const float* __restrict__ wv, const float* __restrict__ sv, const float* __restrict__ bv,
    float* __restrict__ q1, float* __restrict__ kv1,
    float* __restrict__ xp, float* __restrict__ ftp)
{
    __shared__ float ftile[CIN][65];
    __shared__ float f1t[H][65];
    int t = threadIdx.x;
    int l = t & 63;
    int g = __builtin_amdgcn_readfirstlane(t >> 6);
    int bid = blockIdx.x;
    int b  = bid >> 6;
    int n0 = (bid & 63) * 64;
    int n  = n0 + l;
    size_t p = (size_t)b*NP + n;

    const float* fb = feat + ((size_t)b*CIN)*NP + n;
    float fv[16];
    #pragma unroll
    for (int k=0;k<16;k++){
        int c = g*16 + k;
        fv[k] = fb[(size_t)c*NP];
        ftile[c][l] = fv[k];
    }
    #pragma unroll
    for (int k4=0;k4<4;k4++)
        *(float4*)(ftp + p*64 + g*16 + k4*4) =
            make_float4(fv[k4*4],fv[k4*4+1],fv[k4*4+2],fv[k4*4+3]);
    if (g == 0){
        const float* xb = xpos + (size_t)b*3*NP;
        *(float4*)(xp + 4*p) = make_float4(xb[n], xb[NP+n], xb[2*NP+n], 0.f);
    }
    __syncthreads();

    float acc[8];
    #pragma unroll
    for (int u=0;u<8;u++) acc[u] = 0.f;
    #pragma unroll
    for (int c=0;c<CIN;c++){
        float x = ftile[c][l];
        #pragma unroll
        for (int u=0;u<8;u++) acc[u] = fmaf(w1[(g*8+u)*CIN+c], x, acc[u]);
    }
    #pragma unroll
    for (int u=0;u<8;u++){
        int h = g*8+u;
        f1t[h][l] = lrelu(acc[u]*s1[h] + b1[h]);
    }
    __syncthreads();

    float aq[8], ak[8], av[8];
    #pragma unroll
    for (int u=0;u<8;u++){ aq[u]=0.f; ak[u]=0.f; av[u]=0.f; }
    #pragma unroll
    for (int j=0;j<H;j++){
        float x = f1t[j][l];
        #pragma unroll
        for (int u=0;u<8;u++){
            int h = g*8+u;
            aq[u] = fmaf(wq[h*H+j], x, aq[u]);
            ak[u] = fmaf(wk[h*H+j], x, ak[u]);
            av[u] = fmaf(wv[h*H+j], x, av[u]);
        }
    }
    float qr[8], kr[8], vr[8];
    #pragma unroll
    for (int u=0;u<8;u++){
        int h = g*8+u;
        qr[u] = reluf(aq[u]*sq[h]+bq[h]);
        kr[u] = reluf(ak[u]*sk[h]+bk[h]);
        vr[u] = reluf(av[u]*sv[h]+bv[h]);
    }
    size_t qb = p*H + g*8;
    *(float4*)(q1+qb)   = make_float4(qr[0],qr[1],qr[2],qr[3]);
    *(float4*)(q1+qb+4) = make_float4(qr[4],qr[5],qr[6],qr[7]);
    size_t kb = (p*H + g*8)*2;
    #pragma unroll
    for (int u2=0;u2<4;u2++)
        *(float4*)(kv1+kb+u2*4) = make_float4(kr[u2*2],vr[u2*2],kr[u2*2+1],vr[u2*2+1]);
}

// ---------------- K2: pool1 + fused q2/kv2.  Half-wave = one point, lane = channel.
__global__ __launch_bounds__(256) void k_pool1(
    const float* __restrict__ xp, const int* __restrict__ nidx,
    const float* __restrict__ q1, const float* __restrict__ kv1,
    const float* __restrict__ l1w, const float* __restrict__ l1s, const float* __restrict__ l1b,
    const float* __restrict__ w2, const float* __restrict__ s2, const float* __restrict__ b2,
    const float* __restrict__ wq, const float* __restrict__ sq, const float* __restrict__ bq,
    const float* __restrict__ wk, const float* __restrict__ sk, const float* __restrict__ bk,
    const float* __restrict__ wv, const float* __restrict__ sv, const float* __restrict__ bv,
    float* __restrict__ q2, float* __restrict__ kv2)
{
    __shared__ float wl[4][32*36];
    __shared__ float bc[8][32];
    int t = threadIdx.x;
    {
        const float* wsrc[4] = {w2, wq, wk, wv};
        #pragma unroll
        for (int m=0;m<4;m++)
            for (int i=t;i<1024;i+=256)
                wl[m][(i>>5)*36 + (i&31)] = wsrc[m][i];
    }
    __syncthreads();

    int c = t & 31;
    int hw = t >> 5;
    int p = blockIdx.x*8 + hw;
    int b = p >> 12;

    float wl1r[10];
    #pragma unroll
    for (int j=0;j<10;j++) wl1r[j] = l1w[c*10+j];
    float sl1 = l1s[c], bl1 = l1b[c];

    float4 cp = *(const float4*)(xp + 4*(size_t)p);
    float qc = q1[(size_t)p*H + c];
    const int* irow = nidx + (size_t)p*KNN;
    int idxs[KNN];
    #pragma unroll
    for (int k=0;k<KNN;k++) idxs[k] = irow[k];

    float W[KNN], V[KNN];
    #pragma unroll
    for (int k=0;k<KNN;k++){
        int id = idxs[k];
        float4 nv = *(const float4*)(xp + 4*((size_t)(b<<12) + id));
        float dx = nv.x-cp.x, dy = nv.y-cp.y, dz = nv.z-cp.z;
        float dist = sqrtf(dx*dx+dy*dy+dz*dz + 1e-12f);
        float gd = wl1r[0]*cp.x + wl1r[1]*cp.y + wl1r[2]*cp.z
                 + wl1r[3]*nv.x + wl1r[4]*nv.y + wl1r[5]*nv.z
                 + wl1r[6]*dx + wl1r[7]*dy + wl1r[8]*dz + wl1r[9]*dist;
        float xi = lrelu(gd*sl1 + bl1);
        float2 kv = *(const float2*)(kv1 + 2*(((size_t)b*NP + id)*H + c));
        W[k] = xi*(kv.x - qc);
        V[k] = kv.y;
    }
    float m = W[0];
    #pragma unroll
    for (int k=1;k<KNN;k++) m = fmaxf(m, W[k]);
    float den = 0.f, acc = 0.f;
    #pragma unroll
    for (int k=0;k<KNN;k++){
        float e = __expf(W[k]-m);
        den += e; acc = fmaf(e, V[k], acc);
    }
    float outc = acc/den;

    bc[hw][c] = outc;
    float f2a = 0.f;
    #pragma unroll
    for (int jj=0;jj<8;jj++){
        float4 xv = *(const float4*)&bc[hw][jj*4];
        float4 wv4 = *(const float4*)&wl[0][c*36 + jj*4];
        f2a += wv4.x*xv.x + wv4.y*xv.y + wv4.z*xv.z + wv4.w*xv.w;
    }
    float f2 = lrelu(f2a*s2[c] + b2[c]);

    bc[hw][c] = f2;
    float aq=0.f, ak=0.f, av=0.f;
    #pragma unroll
    for (int jj=0;jj<8;jj++){
        float4 xv = *(const float4*)&bc[hw][jj*4];
        float4 wq4 = *(const float4*)&wl[1][c*36 + jj*4];
        float4 wk4 = *(const float4*)&wl[2][c*36 + jj*4];
        float4 wv4 = *(const float4*)&wl[3][c*36 + jj*4];
        aq += wq4.x*xv.x + wq4.y*xv.y + wq4.z*xv.z + wq4.w*xv.w;
        ak += wk4.x*xv.x + wk4.y*xv.y + wk4.z*xv.z + wk4.w*xv.w;
        av += wv4.x*xv.x + wv4.y*xv.y + wv4.z*xv.z + wv4.w*xv.w;
    }
    size_t base = (size_t)p*H + c;
    q2[base] = reluf(aq*sq[c]+bq[c]);
    float ko = reluf(ak*sk[c]+bk[c]);
    float vo = reluf(av*sv[c]+bv[c]);
    *(float2*)(kv2 + 2*base) = make_float2(ko, vo);
}

// ---------------- K3: pool2, MFMA edition. One wave per point.
// Lane l: A-fragment row m = l&15 (neighbor), k-chunk ch0 = (l>>4)*8 (lse1 channels).
// x_info2 = lrelu(cbn(x_info @ lse2^T)) via 2x v_mfma_f32_16x16x32_bf16.
__global__ __launch_bounds__(256) void k_pool2(
    const float* __restrict__ xp, const int* __restrict__ nidx,
    const float* __restrict__ q2, const float* __restrict__ kv2,
    const float* __restrict__ l1w, const float* __restrict__ l1s, const float* __restrict__ l1b,
    const float* __restrict__ l2w, const float* __restrict__ l2s, const float* __restrict__ l2b,
    const float* __restrict__ w2, const float* __restrict__ s2, const float* __restrict__ b2,
    float* __restrict__ f3)
{
    __shared__ float wt1[10][32];     // lse1^T : wt1[j][c] = l1w[c*10+j]
    __shared__ float we[64*36];       // p2_w2 rows padded to 36
    __shared__ float bc[4][32];       // per-wave pooled-output broadcast
    int t = threadIdx.x;
    if (t < 320) wt1[t>>5][t&31] = l1w[(t&31)*10 + (t>>5)];
    for (int i=t;i<2048;i+=256) we[(i>>5)*36 + (i&31)] = w2[i];
    __syncthreads();

    int wv = t >> 6;                  // wave = point within block
    int l  = t & 63;
    int mA  = l & 15;                 // neighbor index (A row / B col)
    int g4  = l >> 4;                 // lane group
    int ch0 = g4 * 8;                 // lse1-channel chunk (MFMA k)
    size_t p = (size_t)blockIdx.x*4 + wv;
    int b = (int)(p >> 12);

    // B fragments: B[k][n] = lse2[n][k]; lane holds lse2 row n=mA (and mA+16), cols ch0..ch0+7
    bf16x8s B0, B1;
    {
        const float* r0 = l2w + mA*32 + ch0;
        const float* r1 = l2w + (mA+16)*32 + ch0;
        #pragma unroll
        for (int i=0;i<8;i++){ B0[i] = f2bf(r0[i]); B1[i] = f2bf(r1[i]); }
    }
    float sl2a = l2s[mA],    bl2a = l2b[mA];
    float sl2b = l2s[mA+16], bl2b = l2b[mA+16];

    const int* irow = nidx + p*KNN;
    int idA = irow[mA];                          // neighbor for geometry (A row)
    int4 idD = *(const int4*)(irow + g4*4);      // neighbors for D rows m=g4*4+r

    float4 cp = *(const float4*)(xp + 4*p);
    float4 nv = *(const float4*)(xp + 4*((size_t)(b<<12) + idA));
    float dx = nv.x-cp.x, dy = nv.y-cp.y, dz = nv.z-cp.z;
    float dist = sqrtf(dx*dx+dy*dy+dz*dz + 1e-12f);
    float gv[10] = {cp.x,cp.y,cp.z,nv.x,nv.y,nv.z,dx,dy,dz,dist};

    // x_info (lse1) for 8 channels of neighbor mA -> A fragment
    float xi[8] = {0.f,0.f,0.f,0.f,0.f,0.f,0.f,0.f};
    #pragma unroll
    for (int j=0;j<10;j++){
        float4 wA = *(const float4*)&wt1[j][ch0];
        float4 wB = *(const float4*)&wt1[j][ch0+4];
        float g = gv[j];
        xi[0]=fmaf(wA.x,g,xi[0]); xi[1]=fmaf(wA.y,g,xi[1]);
        xi[2]=fmaf(wA.z,g,xi[2]); xi[3]=fmaf(wA.w,g,xi[3]);
        xi[4]=fmaf(wB.x,g,xi[4]); xi[5]=fmaf(wB.y,g,xi[5]);
        xi[6]=fmaf(wB.z,g,xi[6]); xi[7]=fmaf(wB.w,g,xi[7]);
    }
    float4 s1lo = *(const float4*)(l1s + ch0), s1hi = *(const float4*)(l1s + ch0 + 4);
    float4 b1lo = *(const float4*)(l1b + ch0), b1hi = *(const float4*)(l1b + ch0 + 4);
    bf16x8s A;
    A[0] = f2bf(lrelu(xi[0]*s1lo.x + b1lo.x));
    A[1] = f2bf(lrelu(xi[1]*s1lo.y + b1lo.y));
    A[2] = f2bf(lrelu(xi[2]*s1lo.z + b1lo.z));
    A[3] = f2bf(lrelu(xi[3]*s1lo.w + b1lo.w));
    A[4] = f2bf(lrelu(xi[4]*s1hi.x + b1hi.x));
    A[5] = f2bf(lrelu(xi[5]*s1hi.y + b1hi.y));
    A[6] = f2bf(lrelu(xi[6]*s1hi.z + b1hi.z));
    A[7] = f2bf(lrelu(xi[7]*s1hi.w + b1hi.w));

    f32x4 cz = {0.f,0.f,0.f,0.f};
    f32x4 D0 = __builtin_amdgcn_mfma_f32_16x16x32_bf16(A, B0, cz, 0, 0, 0);
    f32x4 D1 = __builtin_amdgcn_mfma_f32_16x16x32_bf16(A, B1, cz, 0, 0, 0);
    // D?[r] = x_info2 pre-act for (neighbor m = g4*4+r, channel n = mA / mA+16)

    float qc0 = q2[p*H + mA];
    float qc1 = q2[p*H + mA + 16];
    float W0[4],V0[4],W1[4],V1[4];
    int ids[4] = {idD.x, idD.y, idD.z, idD.w};
    #pragma unroll
    for (int r=0;r<4;r++){
        const float* kvp = kv2 + 2*(((size_t)b*NP + ids[r])*H);
        float2 kva = *(const float2*)(kvp + 2*mA);
        float2 kvb = *(const float2*)(kvp + 2*(mA+16));
        float x0 = lrelu(D0[r]*sl2a + bl2a);
        float x1 = lrelu(D1[r]*sl2b + bl2b);
        W0[r] = x0*(kva.x - qc0); V0[r] = kva.y;
        W1[r] = x1*(kvb.x - qc1); V1[r] = kvb.y;
    }
    // softmax over 16 neighbors: 4 in-reg + butterfly over lanes ^16, ^32
    float mx0 = fmaxf(fmaxf(W0[0],W0[1]),fmaxf(W0[2],W0[3]));
    float mx1 = fmaxf(fmaxf(W1[0],W1[1]),fmaxf(W1[2],W1[3]));
    mx0 = fmaxf(mx0, __shfl_xor(mx0,16,64)); mx0 = fmaxf(mx0, __shfl_xor(mx0,32,64));
    mx1 = fmaxf(mx1, __shfl_xor(mx1,16,64)); mx1 = fmaxf(mx1, __shfl_xor(mx1,32,64));
    float den0=0.f, ac0=0.f, den1=0.f, ac1=0.f;
    #pragma unroll
    for (int r=0;r<4;r++){
        float e0 = __expf(W0[r]-mx0); den0 += e0; ac0 = fmaf(e0, V0[r], ac0);
        float e1 = __expf(W1[r]-mx1); den1 += e1; ac1 = fmaf(e1, V1[r], ac1);
    }
    den0 += __shfl_xor(den0,16,64); den0 += __shfl_xor(den0,32,64);
    ac0  += __shfl_xor(ac0, 16,64); ac0  += __shfl_xor(ac0, 32,64);
    den1 += __shfl_xor(den1,16,64); den1 += __shfl_xor(den1,32,64);
    ac1  += __shfl_xor(ac1, 16,64); ac1  += __shfl_xor(ac1, 32,64);
    float out0 = ac0/den0;     // pooled value, channel mA
    float out1 = ac1/den1;     // pooled value, channel mA+16

    if (l < 16){ bc[wv][l] = out0; bc[wv][l+16] = out1; }
    // same-wave LDS write->read: in-order, compiler inserts lgkmcnt

    // feat3 = lrelu(cbn(out, p2_w2)): lane l computes output channel l (of 64)
    float a2 = 0.f;
    #pragma unroll
    for (int jj=0;jj<8;jj++){
        float4 xv = *(const float4*)&bc[wv][jj*4];
        float4 w4 = *(const float4*)&we[l*36 + jj*4];
        a2 += w4.x*xv.x + w4.y*xv.y + w4.z*xv.z + w4.w*xv.w;
    }
    f3[p*64 + l] = lrelu(a2*s2[l] + b2[l]);
}

// ---------------- K4: out = lrelu(cbn(f3,mlp2) + cbn(ftp,res)) -> [B,128,N]
__global__ __launch_bounds__(256) void k_final(
    const float* __restrict__ ftp, const float* __restrict__ f3,
    const float* __restrict__ m2w, const float* __restrict__ m2s, const float* __restrict__ m2b,
    const float* __restrict__ rw, const float* __restrict__ rs, const float* __restrict__ rb,
    float* __restrict__ out)
{
    int t = threadIdx.x;
    int lane = t & 63;
    int bid = blockIdx.x;
    int tile = bid >> 1;
    int og = __builtin_amdgcn_readfirstlane(((bid & 1) << 2) + (t >> 6));
    size_t p = (size_t)tile*64 + lane;
    int b = (int)(p >> 12), n = (int)(p & (NP-1));
    int o0 = og*16;

    float xf[64];
    {
        const float4* fp = (const float4*)(f3 + p*64);
        #pragma unroll
        for (int i=0;i<16;i++){
            float4 v = fp[i];
            xf[i*4]=v.x; xf[i*4+1]=v.y; xf[i*4+2]=v.z; xf[i*4+3]=v.w;
        }
    }
    float pm[16];
    #pragma unroll
    for (int j=0;j<16;j++){
        const float* wr = m2w + (size_t)(o0+j)*OCC;
        float a0=0.f, a1=0.f;
        #pragma unroll
        for (int c=0;c<64;c+=2){ a0 = fmaf(wr[c],xf[c],a0); a1 = fmaf(wr[c+1],xf[c+1],a1); }
        pm[j] = a0+a1;
    }
    {
        const float4* gp = (const float4*)(ftp + p*64);
        #pragma unroll
        for (int i=0;i<16;i++){
            float4 v = gp[i];
            xf[i*4]=v.x; xf[i*4+1]=v.y; xf[i*4+2]=v.z; xf[i*4+3]=v.w;
        }
    }
    float* ob = out + ((size_t)b*128)*NP + n;
    #pragma unroll
    for (int j=0;j<16;j++){
        int o = o0+j;
        const float* wr = rw + (size_t)o*CIN;
        float a0=0.f, a1=0.f;
        #pragma unroll
        for (int c=0;c<64;c+=2){ a0 = fmaf(wr[c],xf[c],a0); a1 = fmaf(wr[c+1],xf[c+1],a1); }
        float v = pm[j]*m2s[o]+m2b[o] + (a0+a1)*rs[o]+rb[o];
        ob[(size_t)o*NP] = lrelu(v);
    }
}

extern "C" void kernel_launch(void* const* d_in, const int* in_sizes, int n_in,
                              void* d_out, int out_size, void* d_ws, size_t ws_size,
                              hipStream_t stream)
{
    (void)in_sizes; (void)n_in; (void)out_size; (void)ws_size;
    const float* x     = (const float*)d_in[0];
    const float* feat  = (const float*)d_in[1];
    const int*   nidx  = (const int*)  d_in[2];
    const float* m1w=(const float*)d_in[3],  *m1s=(const float*)d_in[4],  *m1b=(const float*)d_in[5];
    const float* l1w=(const float*)d_in[6],  *l1s=(const float*)d_in[7],  *l1b=(const float*)d_in[8];
    const float* p1wq=(const float*)d_in[9],  *p1sq=(const float*)d_in[10], *p1bq=(const float*)d_in[11];
    const float* p1wk=(const float*)d_in[12], *p1sk=(const float*)d_in[13], *p1bk=(const float*)d_in[14];
    const float* p1wv=(const float*)d_in[15], *p1sv=(const float*)d_in[16], *p1bv=(const float*)d_in[17];
    const float* p1w2=(const float*)d_in[18], *p1s2=(const float*)d_in[19], *p1b2=(const float*)d_in[20];
    const float* p2wq=(const float*)d_in[21], *p2sq=(const float*)d_in[22], *p2bq=(const float*)d_in[23];
    const float* p2wk=(const float*)d_in[24], *p2sk=(const float*)d_in[25], *p2bk=(const float*)d_in[26];
    const float* p2wv=(const float*)d_in[27], *p2sv=(const float*)d_in[28], *p2bv=(const float*)d_in[29];
    const float* p2w2=(const float*)d_in[30], *p2s2=(const float*)d_in[31], *p2b2=(const float*)d_in[32];
    const float* l2w=(const float*)d_in[33], *l2s=(const float*)d_in[34], *l2b=(const float*)d_in[35];
    const float* m2w=(const float*)d_in[36], *m2s=(const float*)d_in[37], *m2b=(const float*)d_in[38];
    const float* rw =(const float*)d_in[39], *rs =(const float*)d_in[40], *rb =(const float*)d_in[41];

    float* ws = (float*)d_ws;
    float* q1  = ws;                    // PN*32
    float* kv1 = ws + PN*32;            // PN*64
    float* q2  = ws + PN*96;            // PN*32
    float* kv2 = ws + PN*128;           // PN*64
    float* xp  = ws + PN*192;           // PN*4
    float* ftp = ws + PN*196;           // PN*64
    float* f3  = ws;                    // PN*64 (aliases q1+kv1, dead after pool1... pool2 reads kv2/q2 only)

    float* outp = (float*)d_out;

    k_pointwise<<<dim3(PN/64),dim3(256),0,stream>>>(feat, x, m1w,m1s,m1b,
        p1wq,p1sq,p1bq, p1wk,p1sk,p1bk, p1wv,p1sv,p1bv, q1,kv1, xp, ftp);
    k_pool1<<<dim3(PN/8),dim3(256),0,stream>>>(xp,nidx, q1,kv1,
        l1w,l1s,l1b, p1w2,p1s2,p1b2,
        p2wq,p2sq,p2bq, p2wk,p2sk,p2bk, p2wv,p2sv,p2bv, q2,kv2);
    k_pool2<<<dim3(PN/4),dim3(256),0,stream>>>(xp,nidx, q2,kv2,
        l1w,l1s,l1b, l2w,l2s,l2b, p2w2,p2s2,p2b2, f3);
    k_final<<<dim3(PN/32),dim3(256),0,stream>>>(ftp, f3, m2w,m2s,m2b, rw,rs,rb, outp);
}

// Round 6
// 386.962 us; speedup vs baseline: 2.8468x; 1.2599x over previous
//
#include <hip/hip_runtime.h>
#include <cstdint>
#include <cstddef>

#define NB 16
#define NP 4096
#define KNN 16
#define CIN 64
#define H 32
#define OCC 64
#define PN ((size_t)NB*NP)

__device__ __forceinline__ float lrelu(float v){ return v > 0.f ? v : 0.2f*v; }
__device__ __forceinline__ float reluf(float v){ return v > 0.f ? v : 0.f; }

typedef __attribute__((ext_vector_type(8))) short bf16x8s;
typedef __attribute__((ext_vector_type(4))) float f32x4;

__device__ __forceinline__ short f2bf(float f){
    union { float f; unsigned u; } v; v.f = f;
    unsigned r = v.u + 0x7fffu + ((v.u >> 16) & 1u);   // RNE
    return (short)(r >> 16);
}

__device__ __forceinline__ bf16x8s pack8(float4 a, float4 b, float sc){
    bf16x8s r;
    r[0]=f2bf(a.x*sc); r[1]=f2bf(a.y*sc); r[2]=f2bf(a.z*sc); r[3]=f2bf(a.w*sc);
    r[4]=f2bf(b.x*sc); r[5]=f2bf(b.y*sc); r[6]=f2bf(b.z*sc); r[7]=f2bf(b.w*sc);
    return r;
}

// ---------------- K1: f1 = lrelu(cbn(ft,mlp1)); q1/kv1 = relu(cbn(f1,p1_*))
__global__ __launch_bounds__(256) void k_pointwise(
    const float* __restrict__ feat, const float* __restrict__ xpos,
    const float* __restrict__ w1, const float* __restrict__ s1, const float* __restrict__ b1,
    const float* __restrict__ wq, const float* __restrict__ sq, const float* __restrict__ bq,
    const float* __restrict__ wk, const float* __restrict__ sk, const float* __restrict__ bk,
    const float* __restrict__ wv, const float* __restrict__ sv, const float* __restrict__ bv,
    float* __restrict__ q1, float* __restrict__ kv1,
    float* __restrict__ xp, float* __restrict__ ftp)
{
    __shared__ float ftile[CIN][65];
    __shared__ float f1t[H][65];
    int t = threadIdx.x;
    int l = t & 63;
    int g = __builtin_amdgcn_readfirstlane(t >> 6);
    int bid = blockIdx.x;
    int b  = bid >> 6;
    int n0 = (bid & 63) * 64;
    int n  = n0 + l;
    size_t p = (size_t)b*NP + n;

    const float* fb = feat + ((size_t)b*CIN)*NP + n;
    float fv[16];
    #pragma unroll
    for (int k=0;k<16;k++){
        int c = g*16 + k;
        fv[k] = fb[(size_t)c*NP];
        ftile[c][l] = fv[k];
    }
    #pragma unroll
    for (int k4=0;k4<4;k4++)
        *(float4*)(ftp + p*64 + g*16 + k4*4) =
            make_float4(fv[k4*4],fv[k4*4+1],fv[k4*4+2],fv[k4*4+3]);
    if (g == 0){
        const float* xb = xpos + (size_t)b*3*NP;
        *(float4*)(xp + 4*p) = make_float4(xb[n], xb[NP+n], xb[2*NP+n], 0.f);
    }
    __syncthreads();

    float acc[8];
    #pragma unroll
    for (int u=0;u<8;u++) acc[u] = 0.f;
    #pragma unroll
    for (int c=0;c<CIN;c++){
        float x = ftile[c][l];
        #pragma unroll
        for (int u=0;u<8;u++) acc[u] = fmaf(w1[(g*8+u)*CIN+c], x, acc[u]);
    }
    #pragma unroll
    for (int u=0;u<8;u++){
        int h = g*8+u;
        f1t[h][l] = lrelu(acc[u]*s1[h] + b1[h]);
    }
    __syncthreads();

    float aq[8], ak[8], av[8];
    #pragma unroll
    for (int u=0;u<8;u++){ aq[u]=0.f; ak[u]=0.f; av[u]=0.f; }
    #pragma unroll
    for (int j=0;j<H;j++){
        float x = f1t[j][l];
        #pragma unroll
        for (int u=0;u<8;u++){
            int h = g*8+u;
            aq[u] = fmaf(wq[h*H+j], x, aq[u]);
            ak[u] = fmaf(wk[h*H+j], x, ak[u]);
            av[u] = fmaf(wv[h*H+j], x, av[u]);
        }
    }
    float qr[8], kr[8], vr[8];
    #pragma unroll
    for (int u=0;u<8;u++){
        int h = g*8+u;
        qr[u] = reluf(aq[u]*sq[h]+bq[h]);
        kr[u] = reluf(ak[u]*sk[h]+bk[h]);
        vr[u] = reluf(av[u]*sv[h]+bv[h]);
    }
    size_t qb = p*H + g*8;
    *(float4*)(q1+qb)   = make_float4(qr[0],qr[1],qr[2],qr[3]);
    *(float4*)(q1+qb+4) = make_float4(qr[4],qr[5],qr[6],qr[7]);
    size_t kb = (p*H + g*8)*2;
    #pragma unroll
    for (int u2=0;u2<4;u2++)
        *(float4*)(kv1+kb+u2*4) = make_float4(kr[u2*2],vr[u2*2],kr[u2*2+1],vr[u2*2+1]);
}

// ---------------- K2: pool1 + fused q2/kv2.  Half-wave = one point, lane = channel.
__global__ __launch_bounds__(256) void k_pool1(
    const float* __restrict__ xp, const int* __restrict__ nidx,
    const float* __restrict__ q1, const float* __restrict__ kv1,
    const float* __restrict__ l1w, const float* __restrict__ l1s, const float* __restrict__ l1b,
    const float* __restrict__ w2, const float* __restrict__ s2, const float* __restrict__ b2,
    const float* __restrict__ wq, const float* __restrict__ sq, const float* __restrict__ bq,
    const float* __restrict__ wk, const float* __restrict__ sk, const float* __restrict__ bk,
    const float* __restrict__ wv, const float* __restrict__ sv, const float* __restrict__ bv,
    float* __restrict__ q2, float* __restrict__ kv2)
{
    __shared__ float wl[4][32*36];
    __shared__ float bc[8][32];
    int t = threadIdx.x;
    {
        const float* wsrc[4] = {w2, wq, wk, wv};
        #pragma unroll
        for (int m=0;m<4;m++)
            for (int i=t;i<1024;i+=256)
                wl[m][(i>>5)*36 + (i&31)] = wsrc[m][i];
    }
    __syncthreads();

    int c = t & 31;
    int hw = t >> 5;
    int p = blockIdx.x*8 + hw;
    int b = p >> 12;

    float wl1r[10];
    #pragma unroll
    for (int j=0;j<10;j++) wl1r[j] = l1w[c*10+j];
    float sl1 = l1s[c], bl1 = l1b[c];

    float4 cp = *(const float4*)(xp + 4*(size_t)p);
    float qc = q1[(size_t)p*H + c];
    const int* irow = nidx + (size_t)p*KNN;
    int idxs[KNN];
    #pragma unroll
    for (int k=0;k<KNN;k++) idxs[k] = irow[k];

    float W[KNN], V[KNN];
    #pragma unroll
    for (int k=0;k<KNN;k++){
        int id = idxs[k];
        float4 nv = *(const float4*)(xp + 4*((size_t)(b<<12) + id));
        float dx = nv.x-cp.x, dy = nv.y-cp.y, dz = nv.z-cp.z;
        float dist = sqrtf(dx*dx+dy*dy+dz*dz + 1e-12f);
        float gd = wl1r[0]*cp.x + wl1r[1]*cp.y + wl1r[2]*cp.z
                 + wl1r[3]*nv.x + wl1r[4]*nv.y + wl1r[5]*nv.z
                 + wl1r[6]*dx + wl1r[7]*dy + wl1r[8]*dz + wl1r[9]*dist;
        float xi = lrelu(gd*sl1 + bl1);
        float2 kv = *(const float2*)(kv1 + 2*(((size_t)b*NP + id)*H + c));
        W[k] = xi*(kv.x - qc);
        V[k] = kv.y;
    }
    float m = W[0];
    #pragma unroll
    for (int k=1;k<KNN;k++) m = fmaxf(m, W[k]);
    float den = 0.f, acc = 0.f;
    #pragma unroll
    for (int k=0;k<KNN;k++){
        float e = __expf(W[k]-m);
        den += e; acc = fmaf(e, V[k], acc);
    }
    float outc = acc/den;

    bc[hw][c] = outc;
    float f2a = 0.f;
    #pragma unroll
    for (int jj=0;jj<8;jj++){
        float4 xv = *(const float4*)&bc[hw][jj*4];
        float4 wv4 = *(const float4*)&wl[0][c*36 + jj*4];
        f2a += wv4.x*xv.x + wv4.y*xv.y + wv4.z*xv.z + wv4.w*xv.w;
    }
    float f2 = lrelu(f2a*s2[c] + b2[c]);

    bc[hw][c] = f2;
    float aq=0.f, ak=0.f, av=0.f;
    #pragma unroll
    for (int jj=0;jj<8;jj++){
        float4 xv = *(const float4*)&bc[hw][jj*4];
        float4 wq4 = *(const float4*)&wl[1][c*36 + jj*4];
        float4 wk4 = *(const float4*)&wl[2][c*36 + jj*4];
        float4 wv4 = *(const float4*)&wl[3][c*36 + jj*4];
        aq += wq4.x*xv.x + wq4.y*xv.y + wq4.z*xv.z + wq4.w*xv.w;
        ak += wk4.x*xv.x + wk4.y*xv.y + wk4.z*xv.z + wk4.w*xv.w;
        av += wv4.x*xv.x + wv4.y*xv.y + wv4.z*xv.z + wv4.w*xv.w;
    }
    size_t base = (size_t)p*H + c;
    q2[base] = reluf(aq*sq[c]+bq[c]);
    float ko = reluf(ak*sk[c]+bk[c]);
    float vo = reluf(av*sv[c]+bv[c]);
    *(float2*)(kv2 + 2*base) = make_float2(ko, vo);
}

// ---------------- K3: pool2, MFMA edition. One wave per point.
__global__ __launch_bounds__(256) void k_pool2(
    const float* __restrict__ xp, const int* __restrict__ nidx,
    const float* __restrict__ q2, const float* __restrict__ kv2,
    const float* __restrict__ l1w, const float* __restrict__ l1s, const float* __restrict__ l1b,
    const float* __restrict__ l2w, const float* __restrict__ l2s, const float* __restrict__ l2b,
    const float* __restrict__ w2, const float* __restrict__ s2, const float* __restrict__ b2,
    float* __restrict__ f3)
{
    __shared__ float wt1[10][32];     // lse1^T : wt1[j][c] = l1w[c*10+j]
    __shared__ float we[64*36];       // p2_w2 rows padded to 36
    __shared__ float bc[4][32];       // per-wave pooled-output broadcast
    int t = threadIdx.x;
    if (t < 320) wt1[t>>5][t&31] = l1w[(t&31)*10 + (t>>5)];
    for (int i=t;i<2048;i+=256) we[(i>>5)*36 + (i&31)] = w2[i];
    __syncthreads();

    int wv = t >> 6;
    int l  = t & 63;
    int mA  = l & 15;
    int g4  = l >> 4;
    int ch0 = g4 * 8;
    size_t p = (size_t)blockIdx.x*4 + wv;
    int b = (int)(p >> 12);

    bf16x8s B0, B1;
    {
        const float* r0 = l2w + mA*32 + ch0;
        const float* r1 = l2w + (mA+16)*32 + ch0;
        #pragma unroll
        for (int i=0;i<8;i++){ B0[i] = f2bf(r0[i]); B1[i] = f2bf(r1[i]); }
    }
    float sl2a = l2s[mA],    bl2a = l2b[mA];
    float sl2b = l2s[mA+16], bl2b = l2b[mA+16];

    const int* irow = nidx + p*KNN;
    int idA = irow[mA];
    int4 idD = *(const int4*)(irow + g4*4);

    float4 cp = *(const float4*)(xp + 4*p);
    float4 nv = *(const float4*)(xp + 4*((size_t)(b<<12) + idA));
    float dx = nv.x-cp.x, dy = nv.y-cp.y, dz = nv.z-cp.z;
    float dist = sqrtf(dx*dx+dy*dy+dz*dz + 1e-12f);
    float gv[10] = {cp.x,cp.y,cp.z,nv.x,nv.y,nv.z,dx,dy,dz,dist};

    float xi[8] = {0.f,0.f,0.f,0.f,0.f,0.f,0.f,0.f};
    #pragma unroll
    for (int j=0;j<10;j++){
        float4 wA = *(const float4*)&wt1[j][ch0];
        float4 wB = *(const float4*)&wt1[j][ch0+4];
        float g = gv[j];
        xi[0]=fmaf(wA.x,g,xi[0]); xi[1]=fmaf(wA.y,g,xi[1]);
        xi[2]=fmaf(wA.z,g,xi[2]); xi[3]=fmaf(wA.w,g,xi[3]);
        xi[4]=fmaf(wB.x,g,xi[4]); xi[5]=fmaf(wB.y,g,xi[5]);
        xi[6]=fmaf(wB.z,g,xi[6]); xi[7]=fmaf(wB.w,g,xi[7]);
    }
    float4 s1lo = *(const float4*)(l1s + ch0), s1hi = *(const float4*)(l1s + ch0 + 4);
    float4 b1lo = *(const float4*)(l1b + ch0), b1hi = *(const float4*)(l1b + ch0 + 4);
    bf16x8s A;
    A[0] = f2bf(lrelu(xi[0]*s1lo.x + b1lo.x));
    A[1] = f2bf(lrelu(xi[1]*s1lo.y + b1lo.y));
    A[2] = f2bf(lrelu(xi[2]*s1lo.z + b1lo.z));
    A[3] = f2bf(lrelu(xi[3]*s1lo.w + b1lo.w));
    A[4] = f2bf(lrelu(xi[4]*s1hi.x + b1hi.x));
    A[5] = f2bf(lrelu(xi[5]*s1hi.y + b1hi.y));
    A[6] = f2bf(lrelu(xi[6]*s1hi.z + b1hi.z));
    A[7] = f2bf(lrelu(xi[7]*s1hi.w + b1hi.w));

    f32x4 cz = {0.f,0.f,0.f,0.f};
    f32x4 D0 = __builtin_amdgcn_mfma_f32_16x16x32_bf16(A, B0, cz, 0, 0, 0);
    f32x4 D1 = __builtin_amdgcn_mfma_f32_16x16x32_bf16(A, B1, cz, 0, 0, 0);

    float qc0 = q2[p*H + mA];
    float qc1 = q2[p*H + mA + 16];
    float W0[4],V0[4],W1[4],V1[4];
    int ids[4] = {idD.x, idD.y, idD.z, idD.w};
    #pragma unroll
    for (int r=0;r<4;r++){
        const float* kvp = kv2 + 2*(((size_t)b*NP + ids[r])*H);
        float2 kva = *(const float2*)(kvp + 2*mA);
        float2 kvb = *(const float2*)(kvp + 2*(mA+16));
        float x0 = lrelu(D0[r]*sl2a + bl2a);
        float x1 = lrelu(D1[r]*sl2b + bl2b);
        W0[r] = x0*(kva.x - qc0); V0[r] = kva.y;
        W1[r] = x1*(kvb.x - qc1); V1[r] = kvb.y;
    }
    float mx0 = fmaxf(fmaxf(W0[0],W0[1]),fmaxf(W0[2],W0[3]));
    float mx1 = fmaxf(fmaxf(W1[0],W1[1]),fmaxf(W1[2],W1[3]));
    mx0 = fmaxf(mx0, __shfl_xor(mx0,16,64)); mx0 = fmaxf(mx0, __shfl_xor(mx0,32,64));
    mx1 = fmaxf(mx1, __shfl_xor(mx1,16,64)); mx1 = fmaxf(mx1, __shfl_xor(mx1,32,64));
    float den0=0.f, ac0=0.f, den1=0.f, ac1=0.f;
    #pragma unroll
    for (int r=0;r<4;r++){
        float e0 = __expf(W0[r]-mx0); den0 += e0; ac0 = fmaf(e0, V0[r], ac0);
        float e1 = __expf(W1[r]-mx1); den1 += e1; ac1 = fmaf(e1, V1[r], ac1);
    }
    den0 += __shfl_xor(den0,16,64); den0 += __shfl_xor(den0,32,64);
    ac0  += __shfl_xor(ac0, 16,64); ac0  += __shfl_xor(ac0, 32,64);
    den1 += __shfl_xor(den1,16,64); den1 += __shfl_xor(den1,32,64);
    ac1  += __shfl_xor(ac1, 16,64); ac1  += __shfl_xor(ac1, 32,64);
    float out0 = ac0/den0;
    float out1 = ac1/den1;

    if (l < 16){ bc[wv][l] = out0; bc[wv][l+16] = out1; }

    float a2 = 0.f;
    #pragma unroll
    for (int jj=0;jj<8;jj++){
        float4 xv = *(const float4*)&bc[wv][jj*4];
        float4 w4 = *(const float4*)&we[l*36 + jj*4];
        a2 += w4.x*xv.x + w4.y*xv.y + w4.z*xv.z + w4.w*xv.w;
    }
    f3[p*64 + l] = lrelu(a2*s2[l] + b2[l]);
}

// ---------------- K4: MFMA GEMM. out[p,o]=lrelu(X[p,:]@Wbig[:,o]+bb[o]),
// X=[f3|ftp] (K=128), Wbig scale-folded. Wave w: outputs [w*32,w*32+32), 64 pts/block.
__global__ __launch_bounds__(256) void k_final(
    const float* __restrict__ ftp, const float* __restrict__ f3,
    const float* __restrict__ m2w, const float* __restrict__ m2s, const float* __restrict__ m2b,
    const float* __restrict__ rw, const float* __restrict__ rs, const float* __restrict__ rb,
    float* __restrict__ out)
{
    int t = threadIdx.x;
    int l  = t & 63;
    int w  = t >> 6;          // wave 0..3
    int lr = l & 15;
    int lg = l >> 4;
    int ot0 = w * 32;

    // A-frags: weights, loop-invariant. A[mt][kk]: row = ot0+mt*16+lr, k = kk*32+lg*8+i
    bf16x8s A[2][4];
    float bias[2][4];
    #pragma unroll
    for (int mt=0; mt<2; mt++){
        int o = ot0 + mt*16 + lr;
        float scm = m2s[o], scr = rs[o];
        const float* pm = m2w + (size_t)o*64 + lg*8;
        const float* pr = rw  + (size_t)o*64 + lg*8;
        #pragma unroll
        for (int kk=0;kk<2;kk++)
            A[mt][kk] = pack8(*(const float4*)(pm + kk*32),
                              *(const float4*)(pm + kk*32 + 4), scm);
        #pragma unroll
        for (int kk=0;kk<2;kk++)
            A[mt][2+kk] = pack8(*(const float4*)(pr + kk*32),
                                *(const float4*)(pr + kk*32 + 4), scr);
        int od = ot0 + mt*16 + lg*4;
        #pragma unroll
        for (int r=0;r<4;r++) bias[mt][r] = m2b[od+r] + rb[od+r];
    }

    size_t pbase = (size_t)blockIdx.x * 64;
    int b = (int)(pbase >> 12);           // 64 | 4096 -> whole block same batch
    float* ob = out + ((size_t)b*128)*NP;

    #pragma unroll
    for (int ti=0; ti<4; ti++){
        size_t p0 = pbase + ti*16;
        int n0 = (int)(p0 & (NP-1));
        size_t prow = (p0 + lr)*64 + lg*8;
        bf16x8s Bf[4];
        #pragma unroll
        for (int kk=0;kk<2;kk++)
            Bf[kk] = pack8(*(const float4*)(f3 + prow + kk*32),
                           *(const float4*)(f3 + prow + kk*32 + 4), 1.f);
        #pragma unroll
        for (int kk=0;kk<2;kk++)
            Bf[2+kk] = pack8(*(const float4*)(ftp + prow + kk*32),
                             *(const float4*)(ftp + prow + kk*32 + 4), 1.f);
        #pragma unroll
        for (int mt=0;mt<2;mt++){
            f32x4 D = {0.f,0.f,0.f,0.f};
            #pragma unroll
            for (int kk=0;kk<4;kk++)
                D = __builtin_amdgcn_mfma_f32_16x16x32_bf16(A[mt][kk], Bf[kk], D, 0, 0, 0);
            #pragma unroll
            for (int r=0;r<4;r++){
                int od = ot0 + mt*16 + lg*4 + r;
                ob[(size_t)od*NP + n0 + lr] = lrelu(D[r] + bias[mt][r]);
            }
        }
    }
}

extern "C" void kernel_launch(void* const* d_in, const int* in_sizes, int n_in,
                              void* d_out, int out_size, void* d_ws, size_t ws_size,
                              hipStream_t stream)
{
    (void)in_sizes; (void)n_in; (void)out_size; (void)ws_size;
    const float* x     = (const float*)d_in[0];
    const float* feat  = (const float*)d_in[1];
    const int*   nidx  = (const int*)  d_in[2];
    const float* m1w=(const float*)d_in[3],  *m1s=(const float*)d_in[4],  *m1b=(const float*)d_in[5];
    const float* l1w=(const float*)d_in[6],  *l1s=(const float*)d_in[7],  *l1b=(const float*)d_in[8];
    const float* p1wq=(const float*)d_in[9],  *p1sq=(const float*)d_in[10], *p1bq=(const float*)d_in[11];
    const float* p1wk=(const float*)d_in[12], *p1sk=(const float*)d_in[13], *p1bk=(const float*)d_in[14];
    const float* p1wv=(const float*)d_in[15], *p1sv=(const float*)d_in[16], *p1bv=(const float*)d_in[17];
    const float* p1w2=(const float*)d_in[18], *p1s2=(const float*)d_in[19], *p1b2=(const float*)d_in[20];
    const float* p2wq=(const float*)d_in[21], *p2sq=(const float*)d_in[22], *p2bq=(const float*)d_in[23];
    const float* p2wk=(const float*)d_in[24], *p2sk=(const float*)d_in[25], *p2bk=(const float*)d_in[26];
    const float* p2wv=(const float*)d_in[27], *p2sv=(const float*)d_in[28], *p2bv=(const float*)d_in[29];
    const float* p2w2=(const float*)d_in[30], *p2s2=(const float*)d_in[31], *p2b2=(const float*)d_in[32];
    const float* l2w=(const float*)d_in[33], *l2s=(const float*)d_in[34], *l2b=(const float*)d_in[35];
    const float* m2w=(const float*)d_in[36], *m2s=(const float*)d_in[37], *m2b=(const float*)d_in[38];
    const float* rw =(const float*)d_in[39], *rs =(const float*)d_in[40], *rb =(const float*)d_in[41];

    float* ws = (float*)d_ws;
    float* q1  = ws;                    // PN*32
    float* kv1 = ws + PN*32;            // PN*64
    float* q2  = ws + PN*96;            // PN*32
    float* kv2 = ws + PN*128;           // PN*64
    float* xp  = ws + PN*192;           // PN*4
    float* ftp = ws + PN*196;           // PN*64
    float* f3  = ws;                    // PN*64 (aliases q1+kv1, dead after pool1)

    float* outp = (float*)d_out;

    k_pointwise<<<dim3(PN/64),dim3(256),0,stream>>>(feat, x, m1w,m1s,m1b,
        p1wq,p1sq,p1bq, p1wk,p1sk,p1bk, p1wv,p1sv,p1bv, q1,kv1, xp, ftp);
    k_pool1<<<dim3(PN/8),dim3(256),0,stream>>>(xp,nidx, q1,kv1,
        l1w,l1s,l1b, p1w2,p1s2,p1b2,
        p2wq,p2sq,p2bq, p2wk,p2sk,p2bk, p2wv,p2sv,p2bv, q2,kv2);
    k_pool2<<<dim3(PN/4),dim3(256),0,stream>>>(xp,nidx, q2,kv2,
        l1w,l1s,l1b, l2w,l2s,l2b, p2w2,p2s2,p2b2, f3);
    k_final<<<dim3(PN/64),dim3(256),0,stream>>>(ftp, f3, m2w,m2s,m2b, rw,rs,rb, outp);
}

// Round 7
// 380.813 us; speedup vs baseline: 2.8927x; 1.0161x over previous
//
#include <hip/hip_runtime.h>
#include <cstdint>
#include <cstddef>

#define NB 16
#define NP 4096
#define KNN 16
#define CIN 64
#define H 32
#define OCC 64
#define PN ((size_t)NB*NP)

__device__ __forceinline__ float lrelu(float v){ return v > 0.f ? v : 0.2f*v; }
__device__ __forceinline__ float reluf(float v){ return v > 0.f ? v : 0.f; }

typedef __attribute__((ext_vector_type(8))) short bf16x8s;
typedef __attribute__((ext_vector_type(4))) float f32x4;

__device__ __forceinline__ short f2bf(float f){
    union { float f; unsigned u; } v; v.f = f;
    unsigned r = v.u + 0x7fffu + ((v.u >> 16) & 1u);   // RNE
    return (short)(r >> 16);
}

__device__ __forceinline__ bf16x8s pack8(float4 a, float4 b, float sc){
    bf16x8s r;
    r[0]=f2bf(a.x*sc); r[1]=f2bf(a.y*sc); r[2]=f2bf(a.z*sc); r[3]=f2bf(a.w*sc);
    r[4]=f2bf(b.x*sc); r[5]=f2bf(b.y*sc); r[6]=f2bf(b.z*sc); r[7]=f2bf(b.w*sc);
    return r;
}

// ---------------- K1: f1 = lrelu(cbn(ft,mlp1)); q1/kv1 = relu(cbn(f1,p1_*))
__global__ __launch_bounds__(256) void k_pointwise(
    const float* __restrict__ feat, const float* __restrict__ xpos,
    const float* __restrict__ w1, const float* __restrict__ s1, const float* __restrict__ b1,
    const float* __restrict__ wq, const float* __restrict__ sq, const float* __restrict__ bq,
    const float* __restrict__ wk, const float* __restrict__ sk, const float* __restrict__ bk,
    const float* __restrict__ wv, const float* __restrict__ sv, const float* __restrict__ bv,
    float* __restrict__ q1, float* __restrict__ kv1,
    float* __restrict__ xp, float* __restrict__ ftp)
{
    __shared__ float ftile[CIN][65];
    __shared__ float f1t[H][65];
    int t = threadIdx.x;
    int l = t & 63;
    int g = __builtin_amdgcn_readfirstlane(t >> 6);
    int bid = blockIdx.x;
    int b  = bid >> 6;
    int n0 = (bid & 63) * 64;
    int n  = n0 + l;
    size_t p = (size_t)b*NP + n;

    const float* fb = feat + ((size_t)b*CIN)*NP + n;
    float fv[16];
    #pragma unroll
    for (int k=0;k<16;k++){
        int c = g*16 + k;
        fv[k] = fb[(size_t)c*NP];
        ftile[c][l] = fv[k];
    }
    #pragma unroll
    for (int k4=0;k4<4;k4++)
        *(float4*)(ftp + p*64 + g*16 + k4*4) =
            make_float4(fv[k4*4],fv[k4*4+1],fv[k4*4+2],fv[k4*4+3]);
    if (g == 0){
        const float* xb = xpos + (size_t)b*3*NP;
        *(float4*)(xp + 4*p) = make_float4(xb[n], xb[NP+n], xb[2*NP+n], 0.f);
    }
    __syncthreads();

    float acc[8];
    #pragma unroll
    for (int u=0;u<8;u++) acc[u] = 0.f;
    #pragma unroll
    for (int c=0;c<CIN;c++){
        float x = ftile[c][l];
        #pragma unroll
        for (int u=0;u<8;u++) acc[u] = fmaf(w1[(g*8+u)*CIN+c], x, acc[u]);
    }
    #pragma unroll
    for (int u=0;u<8;u++){
        int h = g*8+u;
        f1t[h][l] = lrelu(acc[u]*s1[h] + b1[h]);
    }
    __syncthreads();

    float aq[8], ak[8], av[8];
    #pragma unroll
    for (int u=0;u<8;u++){ aq[u]=0.f; ak[u]=0.f; av[u]=0.f; }
    #pragma unroll
    for (int j=0;j<H;j++){
        float x = f1t[j][l];
        #pragma unroll
        for (int u=0;u<8;u++){
            int h = g*8+u;
            aq[u] = fmaf(wq[h*H+j], x, aq[u]);
            ak[u] = fmaf(wk[h*H+j], x, ak[u]);
            av[u] = fmaf(wv[h*H+j], x, av[u]);
        }
    }
    float qr[8], kr[8], vr[8];
    #pragma unroll
    for (int u=0;u<8;u++){
        int h = g*8+u;
        qr[u] = reluf(aq[u]*sq[h]+bq[h]);
        kr[u] = reluf(ak[u]*sk[h]+bk[h]);
        vr[u] = reluf(av[u]*sv[h]+bv[h]);
    }
    size_t qb = p*H + g*8;
    *(float4*)(q1+qb)   = make_float4(qr[0],qr[1],qr[2],qr[3]);
    *(float4*)(q1+qb+4) = make_float4(qr[4],qr[5],qr[6],qr[7]);
    size_t kb = (p*H + g*8)*2;
    #pragma unroll
    for (int u2=0;u2<4;u2++)
        *(float4*)(kv1+kb+u2*4) = make_float4(kr[u2*2],vr[u2*2],kr[u2*2+1],vr[u2*2+1]);
}

// ---------------- K2: pool1, MFMA edition. One wave per point.
// x_info = lrelu(cbn(geom @ lse1^T)) via 2x mfma_16x16x32_bf16 with K=10 zero-padded.
// A: m = nbr (lane&15), k = geom feature (lanes g4>=2 hold zeros).
// B: n = channel (lane&15), k same map. D: m = g4*4+r (nbr), n = channel.
__global__ __launch_bounds__(256) void k_pool1(
    const float* __restrict__ xp, const int* __restrict__ nidx,
    const float* __restrict__ q1, const float* __restrict__ kv1,
    const float* __restrict__ l1w, const float* __restrict__ l1s, const float* __restrict__ l1b,
    const float* __restrict__ w2, const float* __restrict__ s2, const float* __restrict__ b2,
    const float* __restrict__ wq, const float* __restrict__ sq, const float* __restrict__ bq,
    const float* __restrict__ wk, const float* __restrict__ sk, const float* __restrict__ bk,
    const float* __restrict__ wv, const float* __restrict__ sv, const float* __restrict__ bv,
    float* __restrict__ q2, float* __restrict__ kv2)
{
    __shared__ float wl[4][32*36];    // w2, wq, wk, wv (rows padded to 36)
    __shared__ float bcp[4][32];      // pooled out per wave
    __shared__ float bcf[4][32];      // feat2 per wave
    int t = threadIdx.x;
    {
        const float* wsrc[4] = {w2, wq, wk, wv};
        #pragma unroll
        for (int m=0;m<4;m++)
            for (int i=t;i<1024;i+=256)
                wl[m][(i>>5)*36 + (i&31)] = wsrc[m][i];
    }
    __syncthreads();

    int wv_ = t >> 6;                 // wave = point within block
    int l   = t & 63;
    int mA  = l & 15;                 // A row (nbr) / B col (channel)
    int g4  = l >> 4;
    size_t p = (size_t)blockIdx.x*4 + wv_;
    int b = (int)(p >> 12);

    // B fragments: lse1^T, zero-padded K (j>=10 -> 0)
    bf16x8s B0, B1;
    #pragma unroll
    for (int i=0;i<8;i++){
        int j = g4*8 + i;
        B0[i] = (j<10) ? f2bf(l1w[mA*10 + j])      : (short)0;
        B1[i] = (j<10) ? f2bf(l1w[(mA+16)*10 + j]) : (short)0;
    }
    float sl1a = l1s[mA],    bl1a = l1b[mA];
    float sl1b = l1s[mA+16], bl1b = l1b[mA+16];

    const int* irow = nidx + p*KNN;
    int idA = irow[mA];                          // neighbor for geometry (A row)
    int4 idD = *(const int4*)(irow + g4*4);      // neighbors for D rows

    float4 cp = *(const float4*)(xp + 4*p);
    float4 nv = *(const float4*)(xp + 4*((size_t)(b<<12) + idA));
    float dx = nv.x-cp.x, dy = nv.y-cp.y, dz = nv.z-cp.z;
    float dist = sqrtf(dx*dx+dy*dy+dz*dz + 1e-12f);

    float a8[8] = {0.f,0.f,0.f,0.f,0.f,0.f,0.f,0.f};
    if (g4 == 0){
        a8[0]=cp.x; a8[1]=cp.y; a8[2]=cp.z; a8[3]=nv.x;
        a8[4]=nv.y; a8[5]=nv.z; a8[6]=dx;   a8[7]=dy;
    } else if (g4 == 1){
        a8[0]=dz; a8[1]=dist;
    }
    bf16x8s A;
    #pragma unroll
    for (int i=0;i<8;i++) A[i] = f2bf(a8[i]);

    f32x4 cz = {0.f,0.f,0.f,0.f};
    f32x4 D0 = __builtin_amdgcn_mfma_f32_16x16x32_bf16(A, B0, cz, 0, 0, 0);
    f32x4 D1 = __builtin_amdgcn_mfma_f32_16x16x32_bf16(A, B1, cz, 0, 0, 0);
    // D?[r] = x_info pre-act for (nbr m = g4*4+r, channel mA / mA+16)

    float qc0 = q1[p*H + mA];
    float qc1 = q1[p*H + mA + 16];
    float W0[4],V0[4],W1[4],V1[4];
    int ids[4] = {idD.x, idD.y, idD.z, idD.w};
    #pragma unroll
    for (int r=0;r<4;r++){
        const float* kvp = kv1 + 2*(((size_t)b*NP + ids[r])*H);
        float2 kva = *(const float2*)(kvp + 2*mA);
        float2 kvb = *(const float2*)(kvp + 2*(mA+16));
        float x0 = lrelu(D0[r]*sl1a + bl1a);
        float x1 = lrelu(D1[r]*sl1b + bl1b);
        W0[r] = x0*(kva.x - qc0); V0[r] = kva.y;
        W1[r] = x1*(kvb.x - qc1); V1[r] = kvb.y;
    }
    float mx0 = fmaxf(fmaxf(W0[0],W0[1]),fmaxf(W0[2],W0[3]));
    float mx1 = fmaxf(fmaxf(W1[0],W1[1]),fmaxf(W1[2],W1[3]));
    mx0 = fmaxf(mx0, __shfl_xor(mx0,16,64)); mx0 = fmaxf(mx0, __shfl_xor(mx0,32,64));
    mx1 = fmaxf(mx1, __shfl_xor(mx1,16,64)); mx1 = fmaxf(mx1, __shfl_xor(mx1,32,64));
    float den0=0.f, ac0=0.f, den1=0.f, ac1=0.f;
    #pragma unroll
    for (int r=0;r<4;r++){
        float e0 = __expf(W0[r]-mx0); den0 += e0; ac0 = fmaf(e0, V0[r], ac0);
        float e1 = __expf(W1[r]-mx1); den1 += e1; ac1 = fmaf(e1, V1[r], ac1);
    }
    den0 += __shfl_xor(den0,16,64); den0 += __shfl_xor(den0,32,64);
    ac0  += __shfl_xor(ac0, 16,64); ac0  += __shfl_xor(ac0, 32,64);
    den1 += __shfl_xor(den1,16,64); den1 += __shfl_xor(den1,32,64);
    ac1  += __shfl_xor(ac1, 16,64); ac1  += __shfl_xor(ac1, 32,64);
    float out0 = ac0/den0;     // pooled, channel mA
    float out1 = ac1/den1;     // pooled, channel mA+16

    if (l < 16){ bcp[wv_][l] = out0; bcp[wv_][l+16] = out1; }
    // same-wave LDS write->read: in-order

    // feat2 = lrelu(cbn(out, p1_w2)); lanes duplicate x2 over c = l&31
    int c = l & 31;
    int sel = l >> 5;
    float f2a = 0.f;
    #pragma unroll
    for (int jj=0;jj<8;jj++){
        float4 xv = *(const float4*)&bcp[wv_][jj*4];
        float4 w4 = *(const float4*)&wl[0][c*36 + jj*4];
        f2a += w4.x*xv.x + w4.y*xv.y + w4.z*xv.z + w4.w*xv.w;
    }
    float f2 = lrelu(f2a*s2[c] + b2[c]);
    if (l < 32) bcf[wv_][c] = f2;

    // q2 (sel=0) / k2 (sel=1), v2 on all lanes (sel=1 discards)
    const float* wqk = sel ? &wl[2][0] : &wl[1][0];
    float a1 = 0.f, avv = 0.f;
    #pragma unroll
    for (int jj=0;jj<8;jj++){
        float4 xv = *(const float4*)&bcf[wv_][jj*4];
        float4 w4 = *(const float4*)&wqk[c*36 + jj*4];
        float4 w5 = *(const float4*)&wl[3][c*36 + jj*4];
        a1  += w4.x*xv.x + w4.y*xv.y + w4.z*xv.z + w4.w*xv.w;
        avv += w5.x*xv.x + w5.y*xv.y + w5.z*xv.z + w5.w*xv.w;
    }
    size_t base = p*H + c;
    if (sel == 0){
        q2[base] = reluf(a1*sq[c]+bq[c]);
        kv2[2*base+1] = reluf(avv*sv[c]+bv[c]);
    } else {
        kv2[2*base] = reluf(a1*sk[c]+bk[c]);
    }
}

// ---------------- K3: pool2, MFMA edition. One wave per point.
__global__ __launch_bounds__(256) void k_pool2(
    const float* __restrict__ xp, const int* __restrict__ nidx,
    const float* __restrict__ q2, const float* __restrict__ kv2,
    const float* __restrict__ l1w, const float* __restrict__ l1s, const float* __restrict__ l1b,
    const float* __restrict__ l2w, const float* __restrict__ l2s, const float* __restrict__ l2b,
    const float* __restrict__ w2, const float* __restrict__ s2, const float* __restrict__ b2,
    float* __restrict__ f3)
{
    __shared__ float wt1[10][32];     // lse1^T : wt1[j][c] = l1w[c*10+j]
    __shared__ float we[64*36];       // p2_w2 rows padded to 36
    __shared__ float bc[4][32];       // per-wave pooled-output broadcast
    int t = threadIdx.x;
    if (t < 320) wt1[t>>5][t&31] = l1w[(t&31)*10 + (t>>5)];
    for (int i=t;i<2048;i+=256) we[(i>>5)*36 + (i&31)] = w2[i];
    __syncthreads();

    int wv = t >> 6;
    int l  = t & 63;
    int mA  = l & 15;
    int g4  = l >> 4;
    int ch0 = g4 * 8;
    size_t p = (size_t)blockIdx.x*4 + wv;
    int b = (int)(p >> 12);

    bf16x8s B0, B1;
    {
        const float* r0 = l2w + mA*32 + ch0;
        const float* r1 = l2w + (mA+16)*32 + ch0;
        #pragma unroll
        for (int i=0;i<8;i++){ B0[i] = f2bf(r0[i]); B1[i] = f2bf(r1[i]); }
    }
    float sl2a = l2s[mA],    bl2a = l2b[mA];
    float sl2b = l2s[mA+16], bl2b = l2b[mA+16];

    const int* irow = nidx + p*KNN;
    int idA = irow[mA];
    int4 idD = *(const int4*)(irow + g4*4);

    float4 cp = *(const float4*)(xp + 4*p);
    float4 nv = *(const float4*)(xp + 4*((size_t)(b<<12) + idA));
    float dx = nv.x-cp.x, dy = nv.y-cp.y, dz = nv.z-cp.z;
    float dist = sqrtf(dx*dx+dy*dy+dz*dz + 1e-12f);
    float gv[10] = {cp.x,cp.y,cp.z,nv.x,nv.y,nv.z,dx,dy,dz,dist};

    float xi[8] = {0.f,0.f,0.f,0.f,0.f,0.f,0.f,0.f};
    #pragma unroll
    for (int j=0;j<10;j++){
        float4 wA = *(const float4*)&wt1[j][ch0];
        float4 wB = *(const float4*)&wt1[j][ch0+4];
        float g = gv[j];
        xi[0]=fmaf(wA.x,g,xi[0]); xi[1]=fmaf(wA.y,g,xi[1]);
        xi[2]=fmaf(wA.z,g,xi[2]); xi[3]=fmaf(wA.w,g,xi[3]);
        xi[4]=fmaf(wB.x,g,xi[4]); xi[5]=fmaf(wB.y,g,xi[5]);
        xi[6]=fmaf(wB.z,g,xi[6]); xi[7]=fmaf(wB.w,g,xi[7]);
    }
    float4 s1lo = *(const float4*)(l1s + ch0), s1hi = *(const float4*)(l1s + ch0 + 4);
    float4 b1lo = *(const float4*)(l1b + ch0), b1hi = *(const float4*)(l1b + ch0 + 4);
    bf16x8s A;
    A[0] = f2bf(lrelu(xi[0]*s1lo.x + b1lo.x));
    A[1] = f2bf(lrelu(xi[1]*s1lo.y + b1lo.y));
    A[2] = f2bf(lrelu(xi[2]*s1lo.z + b1lo.z));
    A[3] = f2bf(lrelu(xi[3]*s1lo.w + b1lo.w));
    A[4] = f2bf(lrelu(xi[4]*s1hi.x + b1hi.x));
    A[5] = f2bf(lrelu(xi[5]*s1hi.y + b1hi.y));
    A[6] = f2bf(lrelu(xi[6]*s1hi.z + b1hi.z));
    A[7] = f2bf(lrelu(xi[7]*s1hi.w + b1hi.w));

    f32x4 cz = {0.f,0.f,0.f,0.f};
    f32x4 D0 = __builtin_amdgcn_mfma_f32_16x16x32_bf16(A, B0, cz, 0, 0, 0);
    f32x4 D1 = __builtin_amdgcn_mfma_f32_16x16x32_bf16(A, B1, cz, 0, 0, 0);

    float qc0 = q2[p*H + mA];
    float qc1 = q2[p*H + mA + 16];
    float W0[4],V0[4],W1[4],V1[4];
    int ids[4] = {idD.x, idD.y, idD.z, idD.w};
    #pragma unroll
    for (int r=0;r<4;r++){
        const float* kvp = kv2 + 2*(((size_t)b*NP + ids[r])*H);
        float2 kva = *(const float2*)(kvp + 2*mA);
        float2 kvb = *(const float2*)(kvp + 2*(mA+16));
        float x0 = lrelu(D0[r]*sl2a + bl2a);
        float x1 = lrelu(D1[r]*sl2b + bl2b);
        W0[r] = x0*(kva.x - qc0); V0[r] = kva.y;
        W1[r] = x1*(kvb.x - qc1); V1[r] = kvb.y;
    }
    float mx0 = fmaxf(fmaxf(W0[0],W0[1]),fmaxf(W0[2],W0[3]));
    float mx1 = fmaxf(fmaxf(W1[0],W1[1]),fmaxf(W1[2],W1[3]));
    mx0 = fmaxf(mx0, __shfl_xor(mx0,16,64)); mx0 = fmaxf(mx0, __shfl_xor(mx0,32,64));
    mx1 = fmaxf(mx1, __shfl_xor(mx1,16,64)); mx1 = fmaxf(mx1, __shfl_xor(mx1,32,64));
    float den0=0.f, ac0=0.f, den1=0.f, ac1=0.f;
    #pragma unroll
    for (int r=0;r<4;r++){
        float e0 = __expf(W0[r]-mx0); den0 += e0; ac0 = fmaf(e0, V0[r], ac0);
        float e1 = __expf(W1[r]-mx1); den1 += e1; ac1 = fmaf(e1, V1[r], ac1);
    }
    den0 += __shfl_xor(den0,16,64); den0 += __shfl_xor(den0,32,64);
    ac0  += __shfl_xor(ac0, 16,64); ac0  += __shfl_xor(ac0, 32,64);
    den1 += __shfl_xor(den1,16,64); den1 += __shfl_xor(den1,32,64);
    ac1  += __shfl_xor(ac1, 16,64); ac1  += __shfl_xor(ac1, 32,64);
    float out0 = ac0/den0;
    float out1 = ac1/den1;

    if (l < 16){ bc[wv][l] = out0; bc[wv][l+16] = out1; }

    float a2 = 0.f;
    #pragma unroll
    for (int jj=0;jj<8;jj++){
        float4 xv = *(const float4*)&bc[wv][jj*4];
        float4 w4 = *(const float4*)&we[l*36 + jj*4];
        a2 += w4.x*xv.x + w4.y*xv.y + w4.z*xv.z + w4.w*xv.w;
    }
    f3[p*64 + l] = lrelu(a2*s2[l] + b2[l]);
}

// ---------------- K4: MFMA GEMM. out[p,o]=lrelu(X[p,:]@Wbig[:,o]+bb[o])
__global__ __launch_bounds__(256) void k_final(
    const float* __restrict__ ftp, const float* __restrict__ f3,
    const float* __restrict__ m2w, const float* __restrict__ m2s, const float* __restrict__ m2b,
    const float* __restrict__ rw, const float* __restrict__ rs, const float* __restrict__ rb,
    float* __restrict__ out)
{
    int t = threadIdx.x;
    int l  = t & 63;
    int w  = t >> 6;
    int lr = l & 15;
    int lg = l >> 4;
    int ot0 = w * 32;

    bf16x8s A[2][4];
    float bias[2][4];
    #pragma unroll
    for (int mt=0; mt<2; mt++){
        int o = ot0 + mt*16 + lr;
        float scm = m2s[o], scr = rs[o];
        const float* pm = m2w + (size_t)o*64 + lg*8;
        const float* pr = rw  + (size_t)o*64 + lg*8;
        #pragma unroll
        for (int kk=0;kk<2;kk++)
            A[mt][kk] = pack8(*(const float4*)(pm + kk*32),
                              *(const float4*)(pm + kk*32 + 4), scm);
        #pragma unroll
        for (int kk=0;kk<2;kk++)
            A[mt][2+kk] = pack8(*(const float4*)(pr + kk*32),
                                *(const float4*)(pr + kk*32 + 4), scr);
        int od = ot0 + mt*16 + lg*4;
        #pragma unroll
        for (int r=0;r<4;r++) bias[mt][r] = m2b[od+r] + rb[od+r];
    }

    size_t pbase = (size_t)blockIdx.x * 64;
    int b = (int)(pbase >> 12);
    float* ob = out + ((size_t)b*128)*NP;

    #pragma unroll
    for (int ti=0; ti<4; ti++){
        size_t p0 = pbase + ti*16;
        int n0 = (int)(p0 & (NP-1));
        size_t prow = (p0 + lr)*64 + lg*8;
        bf16x8s Bf[4];
        #pragma unroll
        for (int kk=0;kk<2;kk++)
            Bf[kk] = pack8(*(const float4*)(f3 + prow + kk*32),
                           *(const float4*)(f3 + prow + kk*32 + 4), 1.f);
        #pragma unroll
        for (int kk=0;kk<2;kk++)
            Bf[2+kk] = pack8(*(const float4*)(ftp + prow + kk*32),
                             *(const float4*)(ftp + prow + kk*32 + 4), 1.f);
        #pragma unroll
        for (int mt=0;mt<2;mt++){
            f32x4 D = {0.f,0.f,0.f,0.f};
            #pragma unroll
            for (int kk=0;kk<4;kk++)
                D = __builtin_amdgcn_mfma_f32_16x16x32_bf16(A[mt][kk], Bf[kk], D, 0, 0, 0);
            #pragma unroll
            for (int r=0;r<4;r++){
                int od = ot0 + mt*16 + lg*4 + r;
                ob[(size_t)od*NP + n0 + lr] = lrelu(D[r] + bias[mt][r]);
            }
        }
    }
}

extern "C" void kernel_launch(void* const* d_in, const int* in_sizes, int n_in,
                              void* d_out, int out_size, void* d_ws, size_t ws_size,
                              hipStream_t stream)
{
    (void)in_sizes; (void)n_in; (void)out_size; (void)ws_size;
    const float* x     = (const float*)d_in[0];
    const float* feat  = (const float*)d_in[1];
    const int*   nidx  = (const int*)  d_in[2];
    const float* m1w=(const float*)d_in[3],  *m1s=(const float*)d_in[4],  *m1b=(const float*)d_in[5];
    const float* l1w=(const float*)d_in[6],  *l1s=(const float*)d_in[7],  *l1b=(const float*)d_in[8];
    const float* p1wq=(const float*)d_in[9],  *p1sq=(const float*)d_in[10], *p1bq=(const float*)d_in[11];
    const float* p1wk=(const float*)d_in[12], *p1sk=(const float*)d_in[13], *p1bk=(const float*)d_in[14];
    const float* p1wv=(const float*)d_in[15], *p1sv=(const float*)d_in[16], *p1bv=(const float*)d_in[17];
    const float* p1w2=(const float*)d_in[18], *p1s2=(const float*)d_in[19], *p1b2=(const float*)d_in[20];
    const float* p2wq=(const float*)d_in[21], *p2sq=(const float*)d_in[22], *p2bq=(const float*)d_in[23];
    const float* p2wk=(const float*)d_in[24], *p2sk=(const float*)d_in[25], *p2bk=(const float*)d_in[26];
    const float* p2wv=(const float*)d_in[27], *p2sv=(const float*)d_in[28], *p2bv=(const float*)d_in[29];
    const float* p2w2=(const float*)d_in[30], *p2s2=(const float*)d_in[31], *p2b2=(const float*)d_in[32];
    const float* l2w=(const float*)d_in[33], *l2s=(const float*)d_in[34], *l2b=(const float*)d_in[35];
    const float* m2w=(const float*)d_in[36], *m2s=(const float*)d_in[37], *m2b=(const float*)d_in[38];
    const float* rw =(const float*)d_in[39], *rs =(const float*)d_in[40], *rb =(const float*)d_in[41];

    float* ws = (float*)d_ws;
    float* q1  = ws;                    // PN*32
    float* kv1 = ws + PN*32;            // PN*64
    float* q2  = ws + PN*96;            // PN*32
    float* kv2 = ws + PN*128;           // PN*64
    float* xp  = ws + PN*192;           // PN*4
    float* ftp = ws + PN*196;           // PN*64
    float* f3  = ws;                    // PN*64 (aliases q1+kv1, dead after pool1)

    float* outp = (float*)d_out;

    k_pointwise<<<dim3(PN/64),dim3(256),0,stream>>>(feat, x, m1w,m1s,m1b,
        p1wq,p1sq,p1bq, p1wk,p1sk,p1bk, p1wv,p1sv,p1bv, q1,kv1, xp, ftp);
    k_pool1<<<dim3(PN/4),dim3(256),0,stream>>>(xp,nidx, q1,kv1,
        l1w,l1s,l1b, p1w2,p1s2,p1b2,
        p2wq,p2sq,p2bq, p2wk,p2sk,p2bk, p2wv,p2sv,p2bv, q2,kv2);
    k_pool2<<<dim3(PN/4),dim3(256),0,stream>>>(xp,nidx, q2,kv2,
        l1w,l1s,l1b, l2w,l2s,l2b, p2w2,p2s2,p2b2, f3);
    k_final<<<dim3(PN/64),dim3(256),0,stream>>>(ftp, f3, m2w,m2s,m2b, rw,rs,rb, outp);
}

// Round 8
// 325.868 us; speedup vs baseline: 3.3805x; 1.1686x over previous
//
#include <hip/hip_runtime.h>
#include <cstdint>
#include <cstddef>

#define NB 16
#define NP 4096
#define KNN 16
#define CIN 64
#define H 32
#define OCC 64
#define PN ((size_t)NB*NP)

__device__ __forceinline__ float lrelu(float v){ return v > 0.f ? v : 0.2f*v; }
__device__ __forceinline__ float reluf(float v){ return v > 0.f ? v : 0.f; }

typedef __attribute__((ext_vector_type(8)))  short bf16x8s;
typedef __attribute__((ext_vector_type(4)))  float f32x4;
typedef __attribute__((ext_vector_type(16))) float f32x16;

__device__ __forceinline__ short f2bf(float f){
    union { float f; unsigned u; } v; v.f = f;
    unsigned r = v.u + 0x7fffu + ((v.u >> 16) & 1u);   // RNE
    return (short)(r >> 16);
}

__device__ __forceinline__ bf16x8s pack8(float4 a, float4 b, float sc){
    bf16x8s r;
    r[0]=f2bf(a.x*sc); r[1]=f2bf(a.y*sc); r[2]=f2bf(a.z*sc); r[3]=f2bf(a.w*sc);
    r[4]=f2bf(b.x*sc); r[5]=f2bf(b.y*sc); r[6]=f2bf(b.z*sc); r[7]=f2bf(b.w*sc);
    return r;
}

// ---------------- K1: f1 = lrelu(cbn(ft,mlp1)); q1/kv1 = relu(cbn(f1,p1_*))
__global__ __launch_bounds__(256) void k_pointwise(
    const float* __restrict__ feat, const float* __restrict__ xpos,
    const float* __restrict__ w1, const float* __restrict__ s1, const float* __restrict__ b1,
    const float* __restrict__ wq, const float* __restrict__ sq, const float* __restrict__ bq,
    const float* __restrict__ wk, const float* __restrict__ sk, const float* __restrict__ bk,
    const float* __restrict__ wv, const float* __restrict__ sv, const float* __restrict__ bv,
    float* __restrict__ q1, float* __restrict__ kv1,
    float* __restrict__ xp, float* __restrict__ ftp)
{
    __shared__ float ftile[CIN][65];
    __shared__ float f1t[H][65];
    int t = threadIdx.x;
    int l = t & 63;
    int g = __builtin_amdgcn_readfirstlane(t >> 6);
    int bid = blockIdx.x;
    int b  = bid >> 6;
    int n0 = (bid & 63) * 64;
    int n  = n0 + l;
    size_t p = (size_t)b*NP + n;

    const float* fb = feat + ((size_t)b*CIN)*NP + n;
    float fv[16];
    #pragma unroll
    for (int k=0;k<16;k++){
        int c = g*16 + k;
        fv[k] = fb[(size_t)c*NP];
        ftile[c][l] = fv[k];
    }
    #pragma unroll
    for (int k4=0;k4<4;k4++)
        *(float4*)(ftp + p*64 + g*16 + k4*4) =
            make_float4(fv[k4*4],fv[k4*4+1],fv[k4*4+2],fv[k4*4+3]);
    if (g == 0){
        const float* xb = xpos + (size_t)b*3*NP;
        *(float4*)(xp + 4*p) = make_float4(xb[n], xb[NP+n], xb[2*NP+n], 0.f);
    }
    __syncthreads();

    float acc[8];
    #pragma unroll
    for (int u=0;u<8;u++) acc[u] = 0.f;
    #pragma unroll
    for (int c=0;c<CIN;c++){
        float x = ftile[c][l];
        #pragma unroll
        for (int u=0;u<8;u++) acc[u] = fmaf(w1[(g*8+u)*CIN+c], x, acc[u]);
    }
    #pragma unroll
    for (int u=0;u<8;u++){
        int h = g*8+u;
        f1t[h][l] = lrelu(acc[u]*s1[h] + b1[h]);
    }
    __syncthreads();

    float aq[8], ak[8], av[8];
    #pragma unroll
    for (int u=0;u<8;u++){ aq[u]=0.f; ak[u]=0.f; av[u]=0.f; }
    #pragma unroll
    for (int j=0;j<H;j++){
        float x = f1t[j][l];
        #pragma unroll
        for (int u=0;u<8;u++){
            int h = g*8+u;
            aq[u] = fmaf(wq[h*H+j], x, aq[u]);
            ak[u] = fmaf(wk[h*H+j], x, ak[u]);
            av[u] = fmaf(wv[h*H+j], x, av[u]);
        }
    }
    float qr[8], kr[8], vr[8];
    #pragma unroll
    for (int u=0;u<8;u++){
        int h = g*8+u;
        qr[u] = reluf(aq[u]*sq[h]+bq[h]);
        kr[u] = reluf(ak[u]*sk[h]+bk[h]);
        vr[u] = reluf(av[u]*sv[h]+bv[h]);
    }
    size_t qb = p*H + g*8;
    *(float4*)(q1+qb)   = make_float4(qr[0],qr[1],qr[2],qr[3]);
    *(float4*)(q1+qb+4) = make_float4(qr[4],qr[5],qr[6],qr[7]);
    size_t kb = (p*H + g*8)*2;
    #pragma unroll
    for (int u2=0;u2<4;u2++)
        *(float4*)(kv1+kb+u2*4) = make_float4(kr[u2*2],vr[u2*2],kr[u2*2+1],vr[u2*2+1]);
}

// ---------------- K2: pool1, 2 points/wave via mfma_32x32x16 (K=10 padded to 16).
// A: m=lane&31 -> (pt=m>>4, nbr=m&15), k=(lane>>5)*8+i (geometry features).
// B: n=lane&31 (x_info channel), same k map.
// D: col n=lane&31, row m=(reg&3)+8*(reg>>2)+4*(lane>>5); regs 0-7 pt0, 8-15 pt1.
__global__ __launch_bounds__(256) void k_pool1(
    const float* __restrict__ xp, const int* __restrict__ nidx,
    const float* __restrict__ q1, const float* __restrict__ kv1,
    const float* __restrict__ l1w, const float* __restrict__ l1s, const float* __restrict__ l1b,
    const float* __restrict__ w2, const float* __restrict__ s2, const float* __restrict__ b2,
    const float* __restrict__ wq, const float* __restrict__ sq, const float* __restrict__ bq,
    const float* __restrict__ wk, const float* __restrict__ sk, const float* __restrict__ bk,
    const float* __restrict__ wv, const float* __restrict__ sv, const float* __restrict__ bv,
    float* __restrict__ q2, float* __restrict__ kv2)
{
    __shared__ float wl[4][32*36];    // w2, wq, wk, wv (rows padded to 36)
    __shared__ float bcp[4][2][32];   // pooled out per wave per point
    __shared__ float bcf[4][2][32];   // feat2 per wave per point
    int t = threadIdx.x;
    {
        const float* wsrc[4] = {w2, wq, wk, wv};
        #pragma unroll
        for (int m=0;m<4;m++)
            for (int i=t;i<1024;i+=256)
                wl[m][(i>>5)*36 + (i&31)] = wsrc[m][i];
    }
    __syncthreads();

    int wv_ = t >> 6;
    int l   = t & 63;
    int n_  = l & 31;                 // channel (B col / D col)
    int hi  = l >> 5;
    size_t p0 = (size_t)blockIdx.x*8 + (size_t)wv_*2;
    int b = (int)(p0 >> 12);          // 8 | 4096 -> whole block same batch

    // B frag: lse1^T zero-padded K (k>=10 -> 0)
    bf16x8s Bf;
    if (hi == 0){
        #pragma unroll
        for (int i=0;i<8;i++) Bf[i] = f2bf(l1w[n_*10 + i]);
    } else {
        Bf[0] = f2bf(l1w[n_*10 + 8]);
        Bf[1] = f2bf(l1w[n_*10 + 9]);
        #pragma unroll
        for (int i=2;i<8;i++) Bf[i] = 0;
    }

    // A frag: geometry of (ptA = (l&31)>>4, nbrA = l&15)
    int ptA  = (l >> 4) & 1;
    int nbrA = l & 15;
    size_t pA = p0 + ptA;
    int idA = nidx[pA*KNN + nbrA];
    float4 cp = *(const float4*)(xp + 4*pA);
    float4 nv = *(const float4*)(xp + 4*((size_t)(b<<12)+idA));
    float dx = nv.x-cp.x, dy = nv.y-cp.y, dz = nv.z-cp.z;
    float dist = sqrtf(dx*dx+dy*dy+dz*dz + 1e-12f);
    bf16x8s A;
    if (hi == 0){
        A[0]=f2bf(cp.x); A[1]=f2bf(cp.y); A[2]=f2bf(cp.z); A[3]=f2bf(nv.x);
        A[4]=f2bf(nv.y); A[5]=f2bf(nv.z); A[6]=f2bf(dx);   A[7]=f2bf(dy);
    } else {
        A[0]=f2bf(dz); A[1]=f2bf(dist);
        A[2]=0; A[3]=0; A[4]=0; A[5]=0; A[6]=0; A[7]=0;
    }

    f32x16 cz = {0.f,0.f,0.f,0.f,0.f,0.f,0.f,0.f,0.f,0.f,0.f,0.f,0.f,0.f,0.f,0.f};
    f32x16 D = __builtin_amdgcn_mfma_f32_32x32x16_bf16(A, Bf, cz, 0, 0, 0);

    float sl1 = l1s[n_], bl1 = l1b[n_];
    const int* irow0 = nidx + p0*KNN;
    float outv[2];
    #pragma unroll
    for (int pt=0; pt<2; pt++){
        size_t p = p0 + pt;
        float qc = q1[p*H + n_];
        int4 idlo = *(const int4*)(irow0 + pt*KNN + 4*hi);       // nbrs 4hi..4hi+3
        int4 idhi = *(const int4*)(irow0 + pt*KNN + 8 + 4*hi);   // nbrs 8+4hi..
        int ids[8] = {idlo.x,idlo.y,idlo.z,idlo.w, idhi.x,idhi.y,idhi.z,idhi.w};
        float W[8], V[8];
        #pragma unroll
        for (int rr=0; rr<8; rr++){
            float xi = lrelu(D[pt*8+rr]*sl1 + bl1);
            float2 kv = *(const float2*)(kv1 + 2*(((size_t)b*NP + ids[rr])*H + n_));
            W[rr] = xi*(kv.x - qc);
            V[rr] = kv.y;
        }
        float mx = W[0];
        #pragma unroll
        for (int rr=1;rr<8;rr++) mx = fmaxf(mx, W[rr]);
        mx = fmaxf(mx, __shfl_xor(mx, 32, 64));
        float den = 0.f, ac = 0.f;
        #pragma unroll
        for (int rr=0;rr<8;rr++){
            float e = __expf(W[rr]-mx);
            den += e; ac = fmaf(e, V[rr], ac);
        }
        den += __shfl_xor(den, 32, 64);
        ac  += __shfl_xor(ac,  32, 64);
        outv[pt] = ac/den;
    }
    if (l < 32){ bcp[wv_][0][n_] = outv[0]; bcp[wv_][1][n_] = outv[1]; }
    // same-wave LDS write->read: in-order

    // feat2 = lrelu(cbn(out, p1_w2)); lane -> (pt=hi, c=n_)
    int c = n_;
    float f2a = 0.f;
    #pragma unroll
    for (int jj=0;jj<8;jj++){
        float4 xv = *(const float4*)&bcp[wv_][hi][jj*4];
        float4 w4 = *(const float4*)&wl[0][c*36 + jj*4];
        f2a += w4.x*xv.x + w4.y*xv.y + w4.z*xv.z + w4.w*xv.w;
    }
    float f2 = lrelu(f2a*s2[c] + b2[c]);
    bcf[wv_][hi][c] = f2;

    // q/k/v = relu(cbn(feat2, p2_*)); lane -> (pt=hi, c)
    float aq=0.f, ak=0.f, av=0.f;
    #pragma unroll
    for (int jj=0;jj<8;jj++){
        float4 xv  = *(const float4*)&bcf[wv_][hi][jj*4];
        float4 wq4 = *(const float4*)&wl[1][c*36 + jj*4];
        float4 wk4 = *(const float4*)&wl[2][c*36 + jj*4];
        float4 wv4 = *(const float4*)&wl[3][c*36 + jj*4];
        aq += wq4.x*xv.x + wq4.y*xv.y + wq4.z*xv.z + wq4.w*xv.w;
        ak += wk4.x*xv.x + wk4.y*xv.y + wk4.z*xv.z + wk4.w*xv.w;
        av += wv4.x*xv.x + wv4.y*xv.y + wv4.z*xv.z + wv4.w*xv.w;
    }
    size_t base = (p0 + hi)*H + c;
    q2[base] = reluf(aq*sq[c]+bq[c]);
    *(float2*)(kv2 + 2*base) = make_float2(reluf(ak*sk[c]+bk[c]), reluf(av*sv[c]+bv[c]));
}

// ---------------- K3: pool2, 2 points/wave via 2x mfma_32x32x16 (K=32 chained).
__global__ __launch_bounds__(256) void k_pool2(
    const float* __restrict__ xp, const int* __restrict__ nidx,
    const float* __restrict__ q2, const float* __restrict__ kv2,
    const float* __restrict__ l1w, const float* __restrict__ l1s, const float* __restrict__ l1b,
    const float* __restrict__ l2w, const float* __restrict__ l2s, const float* __restrict__ l2b,
    const float* __restrict__ w2, const float* __restrict__ s2, const float* __restrict__ b2,
    float* __restrict__ f3)
{
    __shared__ float wt1[10][32];     // lse1^T : wt1[j][c] = l1w[c*10+j]
    __shared__ float we[64*36];       // p2_w2 rows padded to 36
    __shared__ float bc[4][2][32];
    int t = threadIdx.x;
    if (t < 320) wt1[t>>5][t&31] = l1w[(t&31)*10 + (t>>5)];
    for (int i=t;i<2048;i+=256) we[(i>>5)*36 + (i&31)] = w2[i];
    __syncthreads();

    int wv_ = t >> 6;
    int l   = t & 63;
    int n_  = l & 31;
    int hi  = l >> 5;
    size_t p0 = (size_t)blockIdx.x*8 + (size_t)wv_*2;
    int b = (int)(p0 >> 12);

    // geometry of (ptA, nbrA)
    int ptA  = (l >> 4) & 1;
    int nbrA = l & 15;
    size_t pA = p0 + ptA;
    int idA = nidx[pA*KNN + nbrA];
    float4 cp = *(const float4*)(xp + 4*pA);
    float4 nv = *(const float4*)(xp + 4*((size_t)(b<<12)+idA));
    float dx = nv.x-cp.x, dy = nv.y-cp.y, dz = nv.z-cp.z;
    float dist = sqrtf(dx*dx+dy*dy+dz*dz + 1e-12f);
    float gv[10] = {cp.x,cp.y,cp.z,nv.x,nv.y,nv.z,dx,dy,dz,dist};

    // x_info for 16 lse1-channels: ch = hi*8+i (step0) and 16+hi*8+i (step1)
    int ch0 = hi*8;
    float xa[8] = {0,0,0,0,0,0,0,0}, xb2[8] = {0,0,0,0,0,0,0,0};
    #pragma unroll
    for (int j=0;j<10;j++){
        float g = gv[j];
        float4 wA = *(const float4*)&wt1[j][ch0];
        float4 wB = *(const float4*)&wt1[j][ch0+4];
        float4 wC = *(const float4*)&wt1[j][16+ch0];
        float4 wD = *(const float4*)&wt1[j][16+ch0+4];
        xa[0]=fmaf(wA.x,g,xa[0]); xa[1]=fmaf(wA.y,g,xa[1]);
        xa[2]=fmaf(wA.z,g,xa[2]); xa[3]=fmaf(wA.w,g,xa[3]);
        xa[4]=fmaf(wB.x,g,xa[4]); xa[5]=fmaf(wB.y,g,xa[5]);
        xa[6]=fmaf(wB.z,g,xa[6]); xa[7]=fmaf(wB.w,g,xa[7]);
        xb2[0]=fmaf(wC.x,g,xb2[0]); xb2[1]=fmaf(wC.y,g,xb2[1]);
        xb2[2]=fmaf(wC.z,g,xb2[2]); xb2[3]=fmaf(wC.w,g,xb2[3]);
        xb2[4]=fmaf(wD.x,g,xb2[4]); xb2[5]=fmaf(wD.y,g,xb2[5]);
        xb2[6]=fmaf(wD.z,g,xb2[6]); xb2[7]=fmaf(wD.w,g,xb2[7]);
    }
    float4 s1a = *(const float4*)(l1s + ch0), s1b = *(const float4*)(l1s + ch0 + 4);
    float4 s1c = *(const float4*)(l1s + 16 + ch0), s1d = *(const float4*)(l1s + 16 + ch0 + 4);
    float4 b1a = *(const float4*)(l1b + ch0), b1b = *(const float4*)(l1b + ch0 + 4);
    float4 b1c = *(const float4*)(l1b + 16 + ch0), b1d = *(const float4*)(l1b + 16 + ch0 + 4);
    bf16x8s A0, A1;
    A0[0]=f2bf(lrelu(xa[0]*s1a.x+b1a.x)); A0[1]=f2bf(lrelu(xa[1]*s1a.y+b1a.y));
    A0[2]=f2bf(lrelu(xa[2]*s1a.z+b1a.z)); A0[3]=f2bf(lrelu(xa[3]*s1a.w+b1a.w));
    A0[4]=f2bf(lrelu(xa[4]*s1b.x+b1b.x)); A0[5]=f2bf(lrelu(xa[5]*s1b.y+b1b.y));
    A0[6]=f2bf(lrelu(xa[6]*s1b.z+b1b.z)); A0[7]=f2bf(lrelu(xa[7]*s1b.w+b1b.w));
    A1[0]=f2bf(lrelu(xb2[0]*s1c.x+b1c.x)); A1[1]=f2bf(lrelu(xb2[1]*s1c.y+b1c.y));
    A1[2]=f2bf(lrelu(xb2[2]*s1c.z+b1c.z)); A1[3]=f2bf(lrelu(xb2[3]*s1c.w+b1c.w));
    A1[4]=f2bf(lrelu(xb2[4]*s1d.x+b1d.x)); A1[5]=f2bf(lrelu(xb2[5]*s1d.y+b1d.y));
    A1[6]=f2bf(lrelu(xb2[6]*s1d.z+b1d.z)); A1[7]=f2bf(lrelu(xb2[7]*s1d.w+b1d.w));

    // B frags: B[n][k] = l2w[n*32+k]; step s covers k = s*16 + hi*8 + i
    bf16x8s B0, B1;
    {
        const float* r0 = l2w + n_*32 + ch0;
        #pragma unroll
        for (int i=0;i<8;i++){ B0[i] = f2bf(r0[i]); B1[i] = f2bf(r0[16+i]); }
    }

    f32x16 cz = {0.f,0.f,0.f,0.f,0.f,0.f,0.f,0.f,0.f,0.f,0.f,0.f,0.f,0.f,0.f,0.f};
    f32x16 D = __builtin_amdgcn_mfma_f32_32x32x16_bf16(A0, B0, cz, 0, 0, 0);
    D = __builtin_amdgcn_mfma_f32_32x32x16_bf16(A1, B1, D, 0, 0, 0);

    float sl2 = l2s[n_], bl2 = l2b[n_];
    const int* irow0 = nidx + p0*KNN;
    float outv[2];
    #pragma unroll
    for (int pt=0; pt<2; pt++){
        size_t p = p0 + pt;
        float qc = q2[p*H + n_];
        int4 idlo = *(const int4*)(irow0 + pt*KNN + 4*hi);
        int4 idhi = *(const int4*)(irow0 + pt*KNN + 8 + 4*hi);
        int ids[8] = {idlo.x,idlo.y,idlo.z,idlo.w, idhi.x,idhi.y,idhi.z,idhi.w};
        float W[8], V[8];
        #pragma unroll
        for (int rr=0; rr<8; rr++){
            float xi2 = lrelu(D[pt*8+rr]*sl2 + bl2);
            float2 kv = *(const float2*)(kv2 + 2*(((size_t)b*NP + ids[rr])*H + n_));
            W[rr] = xi2*(kv.x - qc);
            V[rr] = kv.y;
        }
        float mx = W[0];
        #pragma unroll
        for (int rr=1;rr<8;rr++) mx = fmaxf(mx, W[rr]);
        mx = fmaxf(mx, __shfl_xor(mx, 32, 64));
        float den = 0.f, ac = 0.f;
        #pragma unroll
        for (int rr=0;rr<8;rr++){
            float e = __expf(W[rr]-mx);
            den += e; ac = fmaf(e, V[rr], ac);
        }
        den += __shfl_xor(den, 32, 64);
        ac  += __shfl_xor(ac,  32, 64);
        outv[pt] = ac/den;
    }
    if (l < 32){ bc[wv_][0][n_] = outv[0]; bc[wv_][1][n_] = outv[1]; }

    // feat3 rows c=n_ and n_+32 for pt=hi; write point-major
    float fa=0.f, fb2=0.f;
    #pragma unroll
    for (int jj=0;jj<8;jj++){
        float4 xv  = *(const float4*)&bc[wv_][hi][jj*4];
        float4 wa4 = *(const float4*)&we[n_*36 + jj*4];
        float4 wb4 = *(const float4*)&we[(n_+32)*36 + jj*4];
        fa  += wa4.x*xv.x + wa4.y*xv.y + wa4.z*xv.z + wa4.w*xv.w;
        fb2 += wb4.x*xv.x + wb4.y*xv.y + wb4.z*xv.z + wb4.w*xv.w;
    }
    size_t pp = p0 + hi;
    f3[pp*64 + n_]      = lrelu(fa *s2[n_]    + b2[n_]);
    f3[pp*64 + 32 + n_] = lrelu(fb2*s2[n_+32] + b2[n_+32]);
}

// ---------------- K4: MFMA GEMM. out[p,o]=lrelu(X[p,:]@Wbig[:,o]+bb[o])
__global__ __launch_bounds__(256) void k_final(
    const float* __restrict__ ftp, const float* __restrict__ f3,
    const float* __restrict__ m2w, const float* __restrict__ m2s, const float* __restrict__ m2b,
    const float* __restrict__ rw, const float* __restrict__ rs, const float* __restrict__ rb,
    float* __restrict__ out)
{
    int t = threadIdx.x;
    int l  = t & 63;
    int w  = t >> 6;
    int lr = l & 15;
    int lg = l >> 4;
    int ot0 = w * 32;

    bf16x8s A[2][4];
    float bias[2][4];
    #pragma unroll
    for (int mt=0; mt<2; mt++){
        int o = ot0 + mt*16 + lr;
        float scm = m2s[o], scr = rs[o];
        const float* pm = m2w + (size_t)o*64 + lg*8;
        const float* pr = rw  + (size_t)o*64 + lg*8;
        #pragma unroll
        for (int kk=0;kk<2;kk++)
            A[mt][kk] = pack8(*(const float4*)(pm + kk*32),
                              *(const float4*)(pm + kk*32 + 4), scm);
        #pragma unroll
        for (int kk=0;kk<2;kk++)
            A[mt][2+kk] = pack8(*(const float4*)(pr + kk*32),
                                *(const float4*)(pr + kk*32 + 4), scr);
        int od = ot0 + mt*16 + lg*4;
        #pragma unroll
        for (int r=0;r<4;r++) bias[mt][r] = m2b[od+r] + rb[od+r];
    }

    size_t pbase = (size_t)blockIdx.x * 64;
    int b = (int)(pbase >> 12);
    float* ob = out + ((size_t)b*128)*NP;

    #pragma unroll
    for (int ti=0; ti<4; ti++){
        size_t p0 = pbase + ti*16;
        int n0 = (int)(p0 & (NP-1));
        size_t prow = (p0 + lr)*64 + lg*8;
        bf16x8s Bf[4];
        #pragma unroll
        for (int kk=0;kk<2;kk++)
            Bf[kk] = pack8(*(const float4*)(f3 + prow + kk*32),
                           *(const float4*)(f3 + prow + kk*32 + 4), 1.f);
        #pragma unroll
        for (int kk=0;kk<2;kk++)
            Bf[2+kk] = pack8(*(const float4*)(ftp + prow + kk*32),
                             *(const float4*)(ftp + prow + kk*32 + 4), 1.f);
        #pragma unroll
        for (int mt=0;mt<2;mt++){
            f32x4 D = {0.f,0.f,0.f,0.f};
            #pragma unroll
            for (int kk=0;kk<4;kk++)
                D = __builtin_amdgcn_mfma_f32_16x16x32_bf16(A[mt][kk], Bf[kk], D, 0, 0, 0);
            #pragma unroll
            for (int r=0;r<4;r++){
                int od = ot0 + mt*16 + lg*4 + r;
                ob[(size_t)od*NP + n0 + lr] = lrelu(D[r] + bias[mt][r]);
            }
        }
    }
}

extern "C" void kernel_launch(void* const* d_in, const int* in_sizes, int n_in,
                              void* d_out, int out_size, void* d_ws, size_t ws_size,
                              hipStream_t stream)
{
    (void)in_sizes; (void)n_in; (void)out_size; (void)ws_size;
    const float* x     = (const float*)d_in[0];
    const float* feat  = (const float*)d_in[1];
    const int*   nidx  = (const int*)  d_in[2];
    const float* m1w=(const float*)d_in[3],  *m1s=(const float*)d_in[4],  *m1b=(const float*)d_in[5];
    const float* l1w=(const float*)d_in[6],  *l1s=(const float*)d_in[7],  *l1b=(const float*)d_in[8];
    const float* p1wq=(const float*)d_in[9],  *p1sq=(const float*)d_in[10], *p1bq=(const float*)d_in[11];
    const float* p1wk=(const float*)d_in[12], *p1sk=(const float*)d_in[13], *p1bk=(const float*)d_in[14];
    const float* p1wv=(const float*)d_in[15], *p1sv=(const float*)d_in[16], *p1bv=(const float*)d_in[17];
    const float* p1w2=(const float*)d_in[18], *p1s2=(const float*)d_in[19], *p1b2=(const float*)d_in[20];
    const float* p2wq=(const float*)d_in[21], *p2sq=(const float*)d_in[22], *p2bq=(const float*)d_in[23];
    const float* p2wk=(const float*)d_in[24], *p2sk=(const float*)d_in[25], *p2bk=(const float*)d_in[26];
    const float* p2wv=(const float*)d_in[27], *p2sv=(const float*)d_in[28], *p2bv=(const float*)d_in[29];
    const float* p2w2=(const float*)d_in[30], *p2s2=(const float*)d_in[31], *p2b2=(const float*)d_in[32];
    const float* l2w=(const float*)d_in[33], *l2s=(const float*)d_in[34], *l2b=(const float*)d_in[35];
    const float* m2w=(const float*)d_in[36], *m2s=(const float*)d_in[37], *m2b=(const float*)d_in[38];
    const float* rw =(const float*)d_in[39], *rs =(const float*)d_in[40], *rb =(const float*)d_in[41];

    float* ws = (float*)d_ws;
    float* q1  = ws;                    // PN*32
    float* kv1 = ws + PN*32;            // PN*64
    float* q2  = ws + PN*96;            // PN*32
    float* kv2 = ws + PN*128;           // PN*64
    float* xp  = ws + PN*192;           // PN*4
    float* ftp = ws + PN*196;           // PN*64
    float* f3  = ws;                    // PN*64 (aliases q1+kv1, dead after pool1)

    float* outp = (float*)d_out;

    k_pointwise<<<dim3(PN/64),dim3(256),0,stream>>>(feat, x, m1w,m1s,m1b,
        p1wq,p1sq,p1bq, p1wk,p1sk,p1bk, p1wv,p1sv,p1bv, q1,kv1, xp, ftp);
    k_pool1<<<dim3(PN/8),dim3(256),0,stream>>>(xp,nidx, q1,kv1,
        l1w,l1s,l1b, p1w2,p1s2,p1b2,
        p2wq,p2sq,p2bq, p2wk,p2sk,p2bk, p2wv,p2sv,p2bv, q2,kv2);
    k_pool2<<<dim3(PN/8),dim3(256),0,stream>>>(xp,nidx, q2,kv2,
        l1w,l1s,l1b, l2w,l2s,l2b, p2w2,p2s2,p2b2, f3);
    k_final<<<dim3(PN/64),dim3(256),0,stream>>>(ftp, f3, m2w,m2s,m2b, rw,rs,rb, outp);
}

// Round 9
// 308.926 us; speedup vs baseline: 3.5659x; 1.0548x over previous
//
#include <hip/hip_runtime.h>
#include <cstdint>
#include <cstddef>

#define NB 16
#define NP 4096
#define KNN 16
#define CIN 64
#define H 32
#define OCC 64
#define PN ((size_t)NB*NP)

__device__ __forceinline__ float lrelu(float v){ return v > 0.f ? v : 0.2f*v; }
__device__ __forceinline__ float reluf(float v){ return v > 0.f ? v : 0.f; }

typedef __attribute__((ext_vector_type(8)))  short bf16x8s;
typedef __attribute__((ext_vector_type(4)))  float f32x4;
typedef __attribute__((ext_vector_type(16))) float f32x16;

__device__ __forceinline__ short f2bf(float f){
    union { float f; unsigned u; } v; v.f = f;
    unsigned r = v.u + 0x7fffu + ((v.u >> 16) & 1u);   // RNE
    return (short)(r >> 16);
}

__device__ __forceinline__ bf16x8s pack8(float4 a, float4 b, float sc){
    bf16x8s r;
    r[0]=f2bf(a.x*sc); r[1]=f2bf(a.y*sc); r[2]=f2bf(a.z*sc); r[3]=f2bf(a.w*sc);
    r[4]=f2bf(b.x*sc); r[5]=f2bf(b.y*sc); r[6]=f2bf(b.z*sc); r[7]=f2bf(b.w*sc);
    return r;
}

// ---------------- K1: f1 = lrelu(cbn(ft,mlp1)); q1/kv1 = relu(cbn(f1,p1_*))
// ftp emitted as bf16 (point-major) for k_final's MFMA B-operand.
__global__ __launch_bounds__(256) void k_pointwise(
    const float* __restrict__ feat, const float* __restrict__ xpos,
    const float* __restrict__ w1, const float* __restrict__ s1, const float* __restrict__ b1,
    const float* __restrict__ wq, const float* __restrict__ sq, const float* __restrict__ bq,
    const float* __restrict__ wk, const float* __restrict__ sk, const float* __restrict__ bk,
    const float* __restrict__ wv, const float* __restrict__ sv, const float* __restrict__ bv,
    float* __restrict__ q1, float* __restrict__ kv1,
    float* __restrict__ xp, short* __restrict__ ftp)
{
    __shared__ float ftile[CIN][65];
    __shared__ float f1t[H][65];
    int t = threadIdx.x;
    int l = t & 63;
    int g = __builtin_amdgcn_readfirstlane(t >> 6);
    int bid = blockIdx.x;
    int b  = bid >> 6;
    int n0 = (bid & 63) * 64;
    int n  = n0 + l;
    size_t p = (size_t)b*NP + n;

    const float* fb = feat + ((size_t)b*CIN)*NP + n;
    float fv[16];
    #pragma unroll
    for (int k=0;k<16;k++){
        int c = g*16 + k;
        fv[k] = fb[(size_t)c*NP];
        ftile[c][l] = fv[k];
    }
    {
        bf16x8s h0, h1;
        #pragma unroll
        for (int i=0;i<8;i++){ h0[i] = f2bf(fv[i]); h1[i] = f2bf(fv[8+i]); }
        *(bf16x8s*)(ftp + p*64 + g*16)     = h0;
        *(bf16x8s*)(ftp + p*64 + g*16 + 8) = h1;
    }
    if (g == 0){
        const float* xb = xpos + (size_t)b*3*NP;
        *(float4*)(xp + 4*p) = make_float4(xb[n], xb[NP+n], xb[2*NP+n], 0.f);
    }
    __syncthreads();

    float acc[8];
    #pragma unroll
    for (int u=0;u<8;u++) acc[u] = 0.f;
    #pragma unroll
    for (int c=0;c<CIN;c++){
        float x = ftile[c][l];
        #pragma unroll
        for (int u=0;u<8;u++) acc[u] = fmaf(w1[(g*8+u)*CIN+c], x, acc[u]);
    }
    #pragma unroll
    for (int u=0;u<8;u++){
        int h = g*8+u;
        f1t[h][l] = lrelu(acc[u]*s1[h] + b1[h]);
    }
    __syncthreads();

    float aq[8], ak[8], av[8];
    #pragma unroll
    for (int u=0;u<8;u++){ aq[u]=0.f; ak[u]=0.f; av[u]=0.f; }
    #pragma unroll
    for (int j=0;j<H;j++){
        float x = f1t[j][l];
        #pragma unroll
        for (int u=0;u<8;u++){
            int h = g*8+u;
            aq[u] = fmaf(wq[h*H+j], x, aq[u]);
            ak[u] = fmaf(wk[h*H+j], x, ak[u]);
            av[u] = fmaf(wv[h*H+j], x, av[u]);
        }
    }
    float qr[8], kr[8], vr[8];
    #pragma unroll
    for (int u=0;u<8;u++){
        int h = g*8+u;
        qr[u] = reluf(aq[u]*sq[h]+bq[h]);
        kr[u] = reluf(ak[u]*sk[h]+bk[h]);
        vr[u] = reluf(av[u]*sv[h]+bv[h]);
    }
    size_t qb = p*H + g*8;
    *(float4*)(q1+qb)   = make_float4(qr[0],qr[1],qr[2],qr[3]);
    *(float4*)(q1+qb+4) = make_float4(qr[4],qr[5],qr[6],qr[7]);
    size_t kb = (p*H + g*8)*2;
    #pragma unroll
    for (int u2=0;u2<4;u2++)
        *(float4*)(kv1+kb+u2*4) = make_float4(kr[u2*2],vr[u2*2],kr[u2*2+1],vr[u2*2+1]);
}

// ---------------- K2: pool1, 2 points/wave via mfma_32x32x16. XCD-swizzled blocks.
__global__ __launch_bounds__(256) void k_pool1(
    const float* __restrict__ xp, const int* __restrict__ nidx,
    const float* __restrict__ q1, const float* __restrict__ kv1,
    const float* __restrict__ l1w, const float* __restrict__ l1s, const float* __restrict__ l1b,
    const float* __restrict__ w2, const float* __restrict__ s2, const float* __restrict__ b2,
    const float* __restrict__ wq, const float* __restrict__ sq, const float* __restrict__ bq,
    const float* __restrict__ wk, const float* __restrict__ sk, const float* __restrict__ bk,
    const float* __restrict__ wv, const float* __restrict__ sv, const float* __restrict__ bv,
    float* __restrict__ q2, float* __restrict__ kv2)
{
    __shared__ float wl[4][32*36];    // w2, wq, wk, wv (rows padded to 36)
    __shared__ float bcp[4][2][32];
    __shared__ float bcf[4][2][32];
    int t = threadIdx.x;
    {
        const float* wsrc[4] = {w2, wq, wk, wv};
        #pragma unroll
        for (int m=0;m<4;m++)
            for (int i=t;i<1024;i+=256)
                wl[m][(i>>5)*36 + (i&31)] = wsrc[m][i];
    }
    __syncthreads();

    int wv_ = t >> 6;
    int l   = t & 63;
    int n_  = l & 31;
    int hi  = l >> 5;
    // XCD-bijective swizzle: nwg = PN/8 = 8192, cpx = 1024 (= 2 batches per XCD)
    int bid = blockIdx.x;
    int sb  = ((bid & 7) << 10) | (bid >> 3);
    size_t p0 = (size_t)sb*8 + (size_t)wv_*2;
    int b = (int)(p0 >> 12);

    bf16x8s Bf;
    if (hi == 0){
        #pragma unroll
        for (int i=0;i<8;i++) Bf[i] = f2bf(l1w[n_*10 + i]);
    } else {
        Bf[0] = f2bf(l1w[n_*10 + 8]);
        Bf[1] = f2bf(l1w[n_*10 + 9]);
        #pragma unroll
        for (int i=2;i<8;i++) Bf[i] = 0;
    }

    int ptA  = (l >> 4) & 1;
    int nbrA = l & 15;
    size_t pA = p0 + ptA;
    int idA = nidx[pA*KNN + nbrA];
    float4 cp = *(const float4*)(xp + 4*pA);
    float4 nv = *(const float4*)(xp + 4*((size_t)(b<<12)+idA));
    float dx = nv.x-cp.x, dy = nv.y-cp.y, dz = nv.z-cp.z;
    float dist = sqrtf(dx*dx+dy*dy+dz*dz + 1e-12f);
    bf16x8s A;
    if (hi == 0){
        A[0]=f2bf(cp.x); A[1]=f2bf(cp.y); A[2]=f2bf(cp.z); A[3]=f2bf(nv.x);
        A[4]=f2bf(nv.y); A[5]=f2bf(nv.z); A[6]=f2bf(dx);   A[7]=f2bf(dy);
    } else {
        A[0]=f2bf(dz); A[1]=f2bf(dist);
        A[2]=0; A[3]=0; A[4]=0; A[5]=0; A[6]=0; A[7]=0;
    }

    f32x16 cz = {0.f,0.f,0.f,0.f,0.f,0.f,0.f,0.f,0.f,0.f,0.f,0.f,0.f,0.f,0.f,0.f};
    f32x16 D = __builtin_amdgcn_mfma_f32_32x32x16_bf16(A, Bf, cz, 0, 0, 0);

    float sl1 = l1s[n_], bl1 = l1b[n_];
    const int* irow0 = nidx + p0*KNN;
    float outv[2];
    #pragma unroll
    for (int pt=0; pt<2; pt++){
        size_t p = p0 + pt;
        float qc = q1[p*H + n_];
        int4 idlo = *(const int4*)(irow0 + pt*KNN + 4*hi);
        int4 idhi = *(const int4*)(irow0 + pt*KNN + 8 + 4*hi);
        int ids[8] = {idlo.x,idlo.y,idlo.z,idlo.w, idhi.x,idhi.y,idhi.z,idhi.w};
        float W[8], V[8];
        #pragma unroll
        for (int rr=0; rr<8; rr++){
            float xi = lrelu(D[pt*8+rr]*sl1 + bl1);
            float2 kv = *(const float2*)(kv1 + 2*(((size_t)b*NP + ids[rr])*H + n_));
            W[rr] = xi*(kv.x - qc);
            V[rr] = kv.y;
        }
        float mx = W[0];
        #pragma unroll
        for (int rr=1;rr<8;rr++) mx = fmaxf(mx, W[rr]);
        mx = fmaxf(mx, __shfl_xor(mx, 32, 64));
        float den = 0.f, ac = 0.f;
        #pragma unroll
        for (int rr=0;rr<8;rr++){
            float e = __expf(W[rr]-mx);
            den += e; ac = fmaf(e, V[rr], ac);
        }
        den += __shfl_xor(den, 32, 64);
        ac  += __shfl_xor(ac,  32, 64);
        outv[pt] = ac/den;
    }
    if (l < 32){ bcp[wv_][0][n_] = outv[0]; bcp[wv_][1][n_] = outv[1]; }

    int c = n_;
    float f2a = 0.f;
    #pragma unroll
    for (int jj=0;jj<8;jj++){
        float4 xv = *(const float4*)&bcp[wv_][hi][jj*4];
        float4 w4 = *(const float4*)&wl[0][c*36 + jj*4];
        f2a += w4.x*xv.x + w4.y*xv.y + w4.z*xv.z + w4.w*xv.w;
    }
    float f2 = lrelu(f2a*s2[c] + b2[c]);
    bcf[wv_][hi][c] = f2;

    float aq=0.f, ak=0.f, av=0.f;
    #pragma unroll
    for (int jj=0;jj<8;jj++){
        float4 xv  = *(const float4*)&bcf[wv_][hi][jj*4];
        float4 wq4 = *(const float4*)&wl[1][c*36 + jj*4];
        float4 wk4 = *(const float4*)&wl[2][c*36 + jj*4];
        float4 wv4 = *(const float4*)&wl[3][c*36 + jj*4];
        aq += wq4.x*xv.x + wq4.y*xv.y + wq4.z*xv.z + wq4.w*xv.w;
        ak += wk4.x*xv.x + wk4.y*xv.y + wk4.z*xv.z + wk4.w*xv.w;
        av += wv4.x*xv.x + wv4.y*xv.y + wv4.z*xv.z + wv4.w*xv.w;
    }
    size_t base = (p0 + hi)*H + c;
    q2[base] = reluf(aq*sq[c]+bq[c]);
    *(float2*)(kv2 + 2*base) = make_float2(reluf(ak*sk[c]+bk[c]), reluf(av*sv[c]+bv[c]));
}

// ---------------- K3: pool2, 2 points/wave via 2x mfma_32x32x16. XCD-swizzled.
// f3 emitted as bf16 (point-major).
__global__ __launch_bounds__(256) void k_pool2(
    const float* __restrict__ xp, const int* __restrict__ nidx,
    const float* __restrict__ q2, const float* __restrict__ kv2,
    const float* __restrict__ l1w, const float* __restrict__ l1s, const float* __restrict__ l1b,
    const float* __restrict__ l2w, const float* __restrict__ l2s, const float* __restrict__ l2b,
    const float* __restrict__ w2, const float* __restrict__ s2, const float* __restrict__ b2,
    short* __restrict__ f3)
{
    __shared__ float wt1[10][32];
    __shared__ float we[64*36];
    __shared__ float bc[4][2][32];
    int t = threadIdx.x;
    if (t < 320) wt1[t>>5][t&31] = l1w[(t&31)*10 + (t>>5)];
    for (int i=t;i<2048;i+=256) we[(i>>5)*36 + (i&31)] = w2[i];
    __syncthreads();

    int wv_ = t >> 6;
    int l   = t & 63;
    int n_  = l & 31;
    int hi  = l >> 5;
    int bid = blockIdx.x;
    int sb  = ((bid & 7) << 10) | (bid >> 3);
    size_t p0 = (size_t)sb*8 + (size_t)wv_*2;
    int b = (int)(p0 >> 12);

    int ptA  = (l >> 4) & 1;
    int nbrA = l & 15;
    size_t pA = p0 + ptA;
    int idA = nidx[pA*KNN + nbrA];
    float4 cp = *(const float4*)(xp + 4*pA);
    float4 nv = *(const float4*)(xp + 4*((size_t)(b<<12)+idA));
    float dx = nv.x-cp.x, dy = nv.y-cp.y, dz = nv.z-cp.z;
    float dist = sqrtf(dx*dx+dy*dy+dz*dz + 1e-12f);
    float gv[10] = {cp.x,cp.y,cp.z,nv.x,nv.y,nv.z,dx,dy,dz,dist};

    int ch0 = hi*8;
    float xa[8] = {0,0,0,0,0,0,0,0}, xb2[8] = {0,0,0,0,0,0,0,0};
    #pragma unroll
    for (int j=0;j<10;j++){
        float g = gv[j];
        float4 wA = *(const float4*)&wt1[j][ch0];
        float4 wB = *(const float4*)&wt1[j][ch0+4];
        float4 wC = *(const float4*)&wt1[j][16+ch0];
        float4 wD = *(const float4*)&wt1[j][16+ch0+4];
        xa[0]=fmaf(wA.x,g,xa[0]); xa[1]=fmaf(wA.y,g,xa[1]);
        xa[2]=fmaf(wA.z,g,xa[2]); xa[3]=fmaf(wA.w,g,xa[3]);
        xa[4]=fmaf(wB.x,g,xa[4]); xa[5]=fmaf(wB.y,g,xa[5]);
        xa[6]=fmaf(wB.z,g,xa[6]); xa[7]=fmaf(wB.w,g,xa[7]);
        xb2[0]=fmaf(wC.x,g,xb2[0]); xb2[1]=fmaf(wC.y,g,xb2[1]);
        xb2[2]=fmaf(wC.z,g,xb2[2]); xb2[3]=fmaf(wC.w,g,xb2[3]);
        xb2[4]=fmaf(wD.x,g,xb2[4]); xb2[5]=fmaf(wD.y,g,xb2[5]);
        xb2[6]=fmaf(wD.z,g,xb2[6]); xb2[7]=fmaf(wD.w,g,xb2[7]);
    }
    float4 s1a = *(const float4*)(l1s + ch0), s1b = *(const float4*)(l1s + ch0 + 4);
    float4 s1c = *(const float4*)(l1s + 16 + ch0), s1d = *(const float4*)(l1s + 16 + ch0 + 4);
    float4 b1a = *(const float4*)(l1b + ch0), b1b = *(const float4*)(l1b + ch0 + 4);
    float4 b1c = *(const float4*)(l1b + 16 + ch0), b1d = *(const float4*)(l1b + 16 + ch0 + 4);
    bf16x8s A0, A1;
    A0[0]=f2bf(lrelu(xa[0]*s1a.x+b1a.x)); A0[1]=f2bf(lrelu(xa[1]*s1a.y+b1a.y));
    A0[2]=f2bf(lrelu(xa[2]*s1a.z+b1a.z)); A0[3]=f2bf(lrelu(xa[3]*s1a.w+b1a.w));
    A0[4]=f2bf(lrelu(xa[4]*s1b.x+b1b.x)); A0[5]=f2bf(lrelu(xa[5]*s1b.y+b1b.y));
    A0[6]=f2bf(lrelu(xa[6]*s1b.z+b1b.z)); A0[7]=f2bf(lrelu(xa[7]*s1b.w+b1b.w));
    A1[0]=f2bf(lrelu(xb2[0]*s1c.x+b1c.x)); A1[1]=f2bf(lrelu(xb2[1]*s1c.y+b1c.y));
    A1[2]=f2bf(lrelu(xb2[2]*s1c.z+b1c.z)); A1[3]=f2bf(lrelu(xb2[3]*s1c.w+b1c.w));
    A1[4]=f2bf(lrelu(xb2[4]*s1d.x+b1d.x)); A1[5]=f2bf(lrelu(xb2[5]*s1d.y+b1d.y));
    A1[6]=f2bf(lrelu(xb2[6]*s1d.z+b1d.z)); A1[7]=f2bf(lrelu(xb2[7]*s1d.w+b1d.w));

    bf16x8s B0, B1;
    {
        const float* r0 = l2w + n_*32 + ch0;
        #pragma unroll
        for (int i=0;i<8;i++){ B0[i] = f2bf(r0[i]); B1[i] = f2bf(r0[16+i]); }
    }

    f32x16 cz = {0.f,0.f,0.f,0.f,0.f,0.f,0.f,0.f,0.f,0.f,0.f,0.f,0.f,0.f,0.f,0.f};
    f32x16 D = __builtin_amdgcn_mfma_f32_32x32x16_bf16(A0, B0, cz, 0, 0, 0);
    D = __builtin_amdgcn_mfma_f32_32x32x16_bf16(A1, B1, D, 0, 0, 0);

    float sl2 = l2s[n_], bl2 = l2b[n_];
    const int* irow0 = nidx + p0*KNN;
    float outv[2];
    #pragma unroll
    for (int pt=0; pt<2; pt++){
        size_t p = p0 + pt;
        float qc = q2[p*H + n_];
        int4 idlo = *(const int4*)(irow0 + pt*KNN + 4*hi);
        int4 idhi = *(const int4*)(irow0 + pt*KNN + 8 + 4*hi);
        int ids[8] = {idlo.x,idlo.y,idlo.z,idlo.w, idhi.x,idhi.y,idhi.z,idhi.w};
        float W[8], V[8];
        #pragma unroll
        for (int rr=0; rr<8; rr++){
            float xi2 = lrelu(D[pt*8+rr]*sl2 + bl2);
            float2 kv = *(const float2*)(kv2 + 2*(((size_t)b*NP + ids[rr])*H + n_));
            W[rr] = xi2*(kv.x - qc);
            V[rr] = kv.y;
        }
        float mx = W[0];
        #pragma unroll
        for (int rr=1;rr<8;rr++) mx = fmaxf(mx, W[rr]);
        mx = fmaxf(mx, __shfl_xor(mx, 32, 64));
        float den = 0.f, ac = 0.f;
        #pragma unroll
        for (int rr=0;rr<8;rr++){
            float e = __expf(W[rr]-mx);
            den += e; ac = fmaf(e, V[rr], ac);
        }
        den += __shfl_xor(den, 32, 64);
        ac  += __shfl_xor(ac,  32, 64);
        outv[pt] = ac/den;
    }
    if (l < 32){ bc[wv_][0][n_] = outv[0]; bc[wv_][1][n_] = outv[1]; }

    float fa=0.f, fb2=0.f;
    #pragma unroll
    for (int jj=0;jj<8;jj++){
        float4 xv  = *(const float4*)&bc[wv_][hi][jj*4];
        float4 wa4 = *(const float4*)&we[n_*36 + jj*4];
        float4 wb4 = *(const float4*)&we[(n_+32)*36 + jj*4];
        fa  += wa4.x*xv.x + wa4.y*xv.y + wa4.z*xv.z + wa4.w*xv.w;
        fb2 += wb4.x*xv.x + wb4.y*xv.y + wb4.z*xv.z + wb4.w*xv.w;
    }
    size_t pp = p0 + hi;
    f3[pp*64 + n_]      = f2bf(lrelu(fa *s2[n_]    + b2[n_]));
    f3[pp*64 + 32 + n_] = f2bf(lrelu(fb2*s2[n_+32] + b2[n_+32]));
}

// ---------------- K4: MFMA GEMM with bf16 B-operands loaded directly.
__global__ __launch_bounds__(256) void k_final(
    const short* __restrict__ ftp, const short* __restrict__ f3,
    const float* __restrict__ m2w, const float* __restrict__ m2s, const float* __restrict__ m2b,
    const float* __restrict__ rw, const float* __restrict__ rs, const float* __restrict__ rb,
    float* __restrict__ out)
{
    int t = threadIdx.x;
    int l  = t & 63;
    int w  = t >> 6;
    int lr = l & 15;
    int lg = l >> 4;
    int ot0 = w * 32;

    bf16x8s A[2][4];
    float bias[2][4];
    #pragma unroll
    for (int mt=0; mt<2; mt++){
        int o = ot0 + mt*16 + lr;
        float scm = m2s[o], scr = rs[o];
        const float* pm = m2w + (size_t)o*64 + lg*8;
        const float* pr = rw  + (size_t)o*64 + lg*8;
        #pragma unroll
        for (int kk=0;kk<2;kk++)
            A[mt][kk] = pack8(*(const float4*)(pm + kk*32),
                              *(const float4*)(pm + kk*32 + 4), scm);
        #pragma unroll
        for (int kk=0;kk<2;kk++)
            A[mt][2+kk] = pack8(*(const float4*)(pr + kk*32),
                                *(const float4*)(pr + kk*32 + 4), scr);
        int od = ot0 + mt*16 + lg*4;
        #pragma unroll
        for (int r=0;r<4;r++) bias[mt][r] = m2b[od+r] + rb[od+r];
    }

    size_t pbase = (size_t)blockIdx.x * 64;
    int b = (int)(pbase >> 12);
    float* ob = out + ((size_t)b*128)*NP;

    #pragma unroll
    for (int ti=0; ti<4; ti++){
        size_t p0 = pbase + ti*16;
        int n0 = (int)(p0 & (NP-1));
        const short* fp3 = f3  + (p0 + lr)*64 + lg*8;
        const short* fpt = ftp + (p0 + lr)*64 + lg*8;
        bf16x8s Bf[4];
        Bf[0] = *(const bf16x8s*)(fp3);
        Bf[1] = *(const bf16x8s*)(fp3 + 32);
        Bf[2] = *(const bf16x8s*)(fpt);
        Bf[3] = *(const bf16x8s*)(fpt + 32);
        #pragma unroll
        for (int mt=0;mt<2;mt++){
            f32x4 D = {0.f,0.f,0.f,0.f};
            #pragma unroll
            for (int kk=0;kk<4;kk++)
                D = __builtin_amdgcn_mfma_f32_16x16x32_bf16(A[mt][kk], Bf[kk], D, 0, 0, 0);
            #pragma unroll
            for (int r=0;r<4;r++){
                int od = ot0 + mt*16 + lg*4 + r;
                ob[(size_t)od*NP + n0 + lr] = lrelu(D[r] + bias[mt][r]);
            }
        }
    }
}

extern "C" void kernel_launch(void* const* d_in, const int* in_sizes, int n_in,
                              void* d_out, int out_size, void* d_ws, size_t ws_size,
                              hipStream_t stream)
{
    (void)in_sizes; (void)n_in; (void)out_size; (void)ws_size;
    const float* x     = (const float*)d_in[0];
    const float* feat  = (const float*)d_in[1];
    const int*   nidx  = (const int*)  d_in[2];
    const float* m1w=(const float*)d_in[3],  *m1s=(const float*)d_in[4],  *m1b=(const float*)d_in[5];
    const float* l1w=(const float*)d_in[6],  *l1s=(const float*)d_in[7],  *l1b=(const float*)d_in[8];
    const float* p1wq=(const float*)d_in[9],  *p1sq=(const float*)d_in[10], *p1bq=(const float*)d_in[11];
    const float* p1wk=(const float*)d_in[12], *p1sk=(const float*)d_in[13], *p1bk=(const float*)d_in[14];
    const float* p1wv=(const float*)d_in[15], *p1sv=(const float*)d_in[16], *p1bv=(const float*)d_in[17];
    const float* p1w2=(const float*)d_in[18], *p1s2=(const float*)d_in[19], *p1b2=(const float*)d_in[20];
    const float* p2wq=(const float*)d_in[21], *p2sq=(const float*)d_in[22], *p2bq=(const float*)d_in[23];
    const float* p2wk=(const float*)d_in[24], *p2sk=(const float*)d_in[25], *p2bk=(const float*)d_in[26];
    const float* p2wv=(const float*)d_in[27], *p2sv=(const float*)d_in[28], *p2bv=(const float*)d_in[29];
    const float* p2w2=(const float*)d_in[30], *p2s2=(const float*)d_in[31], *p2b2=(const float*)d_in[32];
    const float* l2w=(const float*)d_in[33], *l2s=(const float*)d_in[34], *l2b=(const float*)d_in[35];
    const float* m2w=(const float*)d_in[36], *m2s=(const float*)d_in[37], *m2b=(const float*)d_in[38];
    const float* rw =(const float*)d_in[39], *rs =(const float*)d_in[40], *rb =(const float*)d_in[41];

    float* ws = (float*)d_ws;
    float* q1  = ws;                    // PN*32 f32
    float* kv1 = ws + PN*32;            // PN*64 f32
    float* q2  = ws + PN*96;            // PN*32 f32
    float* kv2 = ws + PN*128;           // PN*64 f32
    float* xp  = ws + PN*192;           // PN*4 f32
    short* ftp = (short*)(ws + PN*196); // PN*64 bf16 (= PN*32 f32 slots)
    short* f3  = (short*)ws;            // PN*64 bf16 (aliases q1, dead after pool1)

    float* outp = (float*)d_out;

    k_pointwise<<<dim3(PN/64),dim3(256),0,stream>>>(feat, x, m1w,m1s,m1b,
        p1wq,p1sq,p1bq, p1wk,p1sk,p1bk, p1wv,p1sv,p1bv, q1,kv1, xp, ftp);
    k_pool1<<<dim3(PN/8),dim3(256),0,stream>>>(xp,nidx, q1,kv1,
        l1w,l1s,l1b, p1w2,p1s2,p1b2,
        p2wq,p2sq,p2bq, p2wk,p2sk,p2bk, p2wv,p2sv,p2bv, q2,kv2);
    k_pool2<<<dim3(PN/8),dim3(256),0,stream>>>(xp,nidx, q2,kv2,
        l1w,l1s,l1b, l2w,l2s,l2b, p2w2,p2s2,p2b2, f3);
    k_final<<<dim3(PN/64),dim3(256),0,stream>>>(ftp, f3, m2w,m2s,m2b, rw,rs,rb, outp);
}

// Round 10
// 303.203 us; speedup vs baseline: 3.6332x; 1.0189x over previous
//
#include <hip/hip_runtime.h>
#include <cstdint>
#include <cstddef>

#define NB 16
#define NP 4096
#define KNN 16
#define CIN 64
#define H 32
#define OCC 64
#define PN ((size_t)NB*NP)

__device__ __forceinline__ float lrelu(float v){ return v > 0.f ? v : 0.2f*v; }
__device__ __forceinline__ float reluf(float v){ return v > 0.f ? v : 0.f; }

typedef __attribute__((ext_vector_type(8)))  short bf16x8s;
typedef __attribute__((ext_vector_type(4)))  float f32x4;
typedef __attribute__((ext_vector_type(16))) float f32x16;

__device__ __forceinline__ short f2bf(float f){
    union { float f; unsigned u; } v; v.f = f;
    unsigned r = v.u + 0x7fffu + ((v.u >> 16) & 1u);   // RNE
    return (short)(r >> 16);
}

__device__ __forceinline__ bf16x8s pack8(float4 a, float4 b, float sc){
    bf16x8s r;
    r[0]=f2bf(a.x*sc); r[1]=f2bf(a.y*sc); r[2]=f2bf(a.z*sc); r[3]=f2bf(a.w*sc);
    r[4]=f2bf(b.x*sc); r[5]=f2bf(b.y*sc); r[6]=f2bf(b.z*sc); r[7]=f2bf(b.w*sc);
    return r;
}

// ---------------- K1: f1 = lrelu(cbn(ft,mlp1)); q1/kv1 = relu(cbn(f1,p1_*))
__global__ __launch_bounds__(256) void k_pointwise(
    const float* __restrict__ feat, const float* __restrict__ xpos,
    const float* __restrict__ w1, const float* __restrict__ s1, const float* __restrict__ b1,
    const float* __restrict__ wq, const float* __restrict__ sq, const float* __restrict__ bq,
    const float* __restrict__ wk, const float* __restrict__ sk, const float* __restrict__ bk,
    const float* __restrict__ wv, const float* __restrict__ sv, const float* __restrict__ bv,
    float* __restrict__ q1, float* __restrict__ kv1,
    float* __restrict__ xp, short* __restrict__ ftp)
{
    __shared__ float ftile[CIN][65];
    __shared__ float f1t[H][65];
    int t = threadIdx.x;
    int l = t & 63;
    int g = __builtin_amdgcn_readfirstlane(t >> 6);
    int bid = blockIdx.x;
    int b  = bid >> 6;
    int n0 = (bid & 63) * 64;
    int n  = n0 + l;
    size_t p = (size_t)b*NP + n;

    const float* fb = feat + ((size_t)b*CIN)*NP + n;
    float fv[16];
    #pragma unroll
    for (int k=0;k<16;k++){
        int c = g*16 + k;
        fv[k] = fb[(size_t)c*NP];
        ftile[c][l] = fv[k];
    }
    {
        bf16x8s h0, h1;
        #pragma unroll
        for (int i=0;i<8;i++){ h0[i] = f2bf(fv[i]); h1[i] = f2bf(fv[8+i]); }
        *(bf16x8s*)(ftp + p*64 + g*16)     = h0;
        *(bf16x8s*)(ftp + p*64 + g*16 + 8) = h1;
    }
    if (g == 0){
        const float* xb = xpos + (size_t)b*3*NP;
        *(float4*)(xp + 4*p) = make_float4(xb[n], xb[NP+n], xb[2*NP+n], 0.f);
    }
    __syncthreads();

    float acc[8];
    #pragma unroll
    for (int u=0;u<8;u++) acc[u] = 0.f;
    #pragma unroll
    for (int c=0;c<CIN;c++){
        float x = ftile[c][l];
        #pragma unroll
        for (int u=0;u<8;u++) acc[u] = fmaf(w1[(g*8+u)*CIN+c], x, acc[u]);
    }
    #pragma unroll
    for (int u=0;u<8;u++){
        int h = g*8+u;
        f1t[h][l] = lrelu(acc[u]*s1[h] + b1[h]);
    }
    __syncthreads();

    float aq[8], ak[8], av[8];
    #pragma unroll
    for (int u=0;u<8;u++){ aq[u]=0.f; ak[u]=0.f; av[u]=0.f; }
    #pragma unroll
    for (int j=0;j<H;j++){
        float x = f1t[j][l];
        #pragma unroll
        for (int u=0;u<8;u++){
            int h = g*8+u;
            aq[u] = fmaf(wq[h*H+j], x, aq[u]);
            ak[u] = fmaf(wk[h*H+j], x, ak[u]);
            av[u] = fmaf(wv[h*H+j], x, av[u]);
        }
    }
    float qr[8], kr[8], vr[8];
    #pragma unroll
    for (int u=0;u<8;u++){
        int h = g*8+u;
        qr[u] = reluf(aq[u]*sq[h]+bq[h]);
        kr[u] = reluf(ak[u]*sk[h]+bk[h]);
        vr[u] = reluf(av[u]*sv[h]+bv[h]);
    }
    size_t qb = p*H + g*8;
    *(float4*)(q1+qb)   = make_float4(qr[0],qr[1],qr[2],qr[3]);
    *(float4*)(q1+qb+4) = make_float4(qr[4],qr[5],qr[6],qr[7]);
    size_t kb = (p*H + g*8)*2;
    #pragma unroll
    for (int u2=0;u2<4;u2++)
        *(float4*)(kv1+kb+u2*4) = make_float4(kr[u2*2],vr[u2*2],kr[u2*2+1],vr[u2*2+1]);
}

// ---------------- K2: pool1, 2 points/wave via mfma_32x32x16. XCD-swizzled blocks.
__global__ __launch_bounds__(256) void k_pool1(
    const float* __restrict__ xp, const int* __restrict__ nidx,
    const float* __restrict__ q1, const float* __restrict__ kv1,
    const float* __restrict__ l1w, const float* __restrict__ l1s, const float* __restrict__ l1b,
    const float* __restrict__ w2, const float* __restrict__ s2, const float* __restrict__ b2,
    const float* __restrict__ wq, const float* __restrict__ sq, const float* __restrict__ bq,
    const float* __restrict__ wk, const float* __restrict__ sk, const float* __restrict__ bk,
    const float* __restrict__ wv, const float* __restrict__ sv, const float* __restrict__ bv,
    float* __restrict__ q2, float* __restrict__ kv2)
{
    __shared__ float wl[4][32*36];    // w2, wq, wk, wv (rows padded to 36)
    __shared__ float bcp[4][2][32];
    __shared__ float bcf[4][2][32];
    int t = threadIdx.x;
    {
        const float* wsrc[4] = {w2, wq, wk, wv};
        #pragma unroll
        for (int m=0;m<4;m++)
            for (int i=t;i<1024;i+=256)
                wl[m][(i>>5)*36 + (i&31)] = wsrc[m][i];
    }
    __syncthreads();

    int wv_ = t >> 6;
    int l   = t & 63;
    int n_  = l & 31;
    int hi  = l >> 5;
    // XCD-bijective swizzle: nwg = PN/8 = 8192, cpx = 1024 (= 2 batches per XCD)
    int bid = blockIdx.x;
    int sb  = ((bid & 7) << 10) | (bid >> 3);
    size_t p0 = (size_t)sb*8 + (size_t)wv_*2;
    int b = (int)(p0 >> 12);

    bf16x8s Bf;
    if (hi == 0){
        #pragma unroll
        for (int i=0;i<8;i++) Bf[i] = f2bf(l1w[n_*10 + i]);
    } else {
        Bf[0] = f2bf(l1w[n_*10 + 8]);
        Bf[1] = f2bf(l1w[n_*10 + 9]);
        #pragma unroll
        for (int i=2;i<8;i++) Bf[i] = 0;
    }

    int ptA  = (l >> 4) & 1;
    int nbrA = l & 15;
    size_t pA = p0 + ptA;
    int idA = nidx[pA*KNN + nbrA];
    float4 cp = *(const float4*)(xp + 4*pA);
    float4 nv = *(const float4*)(xp + 4*((size_t)(b<<12)+idA));
    float dx = nv.x-cp.x, dy = nv.y-cp.y, dz = nv.z-cp.z;
    float dist = sqrtf(dx*dx+dy*dy+dz*dz + 1e-12f);
    bf16x8s A;
    if (hi == 0){
        A[0]=f2bf(cp.x); A[1]=f2bf(cp.y); A[2]=f2bf(cp.z); A[3]=f2bf(nv.x);
        A[4]=f2bf(nv.y); A[5]=f2bf(nv.z); A[6]=f2bf(dx);   A[7]=f2bf(dy);
    } else {
        A[0]=f2bf(dz); A[1]=f2bf(dist);
        A[2]=0; A[3]=0; A[4]=0; A[5]=0; A[6]=0; A[7]=0;
    }

    f32x16 cz = {0.f,0.f,0.f,0.f,0.f,0.f,0.f,0.f,0.f,0.f,0.f,0.f,0.f,0.f,0.f,0.f};
    f32x16 D = __builtin_amdgcn_mfma_f32_32x32x16_bf16(A, Bf, cz, 0, 0, 0);

    float sl1 = l1s[n_], bl1 = l1b[n_];
    const int* irow0 = nidx + p0*KNN;
    float outv[2];
    #pragma unroll
    for (int pt=0; pt<2; pt++){
        size_t p = p0 + pt;
        float qc = q1[p*H + n_];
        int4 idlo = *(const int4*)(irow0 + pt*KNN + 4*hi);
        int4 idhi = *(const int4*)(irow0 + pt*KNN + 8 + 4*hi);
        int ids[8] = {idlo.x,idlo.y,idlo.z,idlo.w, idhi.x,idhi.y,idhi.z,idhi.w};
        float W[8], V[8];
        #pragma unroll
        for (int rr=0; rr<8; rr++){
            float xi = lrelu(D[pt*8+rr]*sl1 + bl1);
            float2 kv = *(const float2*)(kv1 + 2*(((size_t)b*NP + ids[rr])*H + n_));
            W[rr] = xi*(kv.x - qc);
            V[rr] = kv.y;
        }
        float mx = W[0];
        #pragma unroll
        for (int rr=1;rr<8;rr++) mx = fmaxf(mx, W[rr]);
        mx = fmaxf(mx, __shfl_xor(mx, 32, 64));
        float den = 0.f, ac = 0.f;
        #pragma unroll
        for (int rr=0;rr<8;rr++){
            float e = __expf(W[rr]-mx);
            den += e; ac = fmaf(e, V[rr], ac);
        }
        den += __shfl_xor(den, 32, 64);
        ac  += __shfl_xor(ac,  32, 64);
        outv[pt] = ac/den;
    }
    if (l < 32){ bcp[wv_][0][n_] = outv[0]; bcp[wv_][1][n_] = outv[1]; }

    int c = n_;
    float f2a = 0.f;
    #pragma unroll
    for (int jj=0;jj<8;jj++){
        float4 xv = *(const float4*)&bcp[wv_][hi][jj*4];
        float4 w4 = *(const float4*)&wl[0][c*36 + jj*4];
        f2a += w4.x*xv.x + w4.y*xv.y + w4.z*xv.z + w4.w*xv.w;
    }
    float f2 = lrelu(f2a*s2[c] + b2[c]);
    bcf[wv_][hi][c] = f2;

    float aq=0.f, ak=0.f, av=0.f;
    #pragma unroll
    for (int jj=0;jj<8;jj++){
        float4 xv  = *(const float4*)&bcf[wv_][hi][jj*4];
        float4 wq4 = *(const float4*)&wl[1][c*36 + jj*4];
        float4 wk4 = *(const float4*)&wl[2][c*36 + jj*4];
        float4 wv4 = *(const float4*)&wl[3][c*36 + jj*4];
        aq += wq4.x*xv.x + wq4.y*xv.y + wq4.z*xv.z + wq4.w*xv.w;
        ak += wk4.x*xv.x + wk4.y*xv.y + wk4.z*xv.z + wk4.w*xv.w;
        av += wv4.x*xv.x + wv4.y*xv.y + wv4.z*xv.z + wv4.w*xv.w;
    }
    size_t base = (p0 + hi)*H + c;
    q2[base] = reluf(aq*sq[c]+bq[c]);
    *(float2*)(kv2 + 2*base) = make_float2(reluf(ak*sk[c]+bk[c]), reluf(av*sv[c]+bv[c]));
}

// ---------------- K3: pool2 — chained MFMA: x_info via MFMA1 (geom@lse1^T),
// per-wave LDS transpose (bf16, row stride 40 u16 = 80 B, 16B-aligned),
// then x_info2 via 2x mfma_32x32x16 over K=32. f3 emitted bf16 point-major.
__global__ __launch_bounds__(256) void k_pool2(
    const float* __restrict__ xp, const int* __restrict__ nidx,
    const float* __restrict__ q2, const float* __restrict__ kv2,
    const float* __restrict__ l1w, const float* __restrict__ l1s, const float* __restrict__ l1b,
    const float* __restrict__ l2w, const float* __restrict__ l2s, const float* __restrict__ l2b,
    const float* __restrict__ w2, const float* __restrict__ s2, const float* __restrict__ b2,
    short* __restrict__ f3)
{
    __shared__ float we[64*36];                 // p2_w2 rows padded to 36
    __shared__ float bc[4][2][32];
    __shared__ unsigned short xiT[4][32*40];    // per-wave x_info transpose tile
    int t = threadIdx.x;
    for (int i=t;i<2048;i+=256) we[(i>>5)*36 + (i&31)] = w2[i];
    __syncthreads();

    int wv_ = t >> 6;
    int l   = t & 63;
    int n_  = l & 31;
    int hi  = l >> 5;
    int bid = blockIdx.x;
    int sb  = ((bid & 7) << 10) | (bid >> 3);
    size_t p0 = (size_t)sb*8 + (size_t)wv_*2;
    int b = (int)(p0 >> 12);

    // ---- MFMA1: x_info preact = geom @ lse1^T (K=10 padded to 16) ----
    bf16x8s Bf1;
    if (hi == 0){
        #pragma unroll
        for (int i=0;i<8;i++) Bf1[i] = f2bf(l1w[n_*10 + i]);
    } else {
        Bf1[0] = f2bf(l1w[n_*10 + 8]);
        Bf1[1] = f2bf(l1w[n_*10 + 9]);
        #pragma unroll
        for (int i=2;i<8;i++) Bf1[i] = 0;
    }
    int ptA  = (l >> 4) & 1;
    int nbrA = l & 15;
    size_t pA = p0 + ptA;
    int idA = nidx[pA*KNN + nbrA];
    float4 cp = *(const float4*)(xp + 4*pA);
    float4 nv = *(const float4*)(xp + 4*((size_t)(b<<12)+idA));
    float dx = nv.x-cp.x, dy = nv.y-cp.y, dz = nv.z-cp.z;
    float dist = sqrtf(dx*dx+dy*dy+dz*dz + 1e-12f);
    bf16x8s Ag;
    if (hi == 0){
        Ag[0]=f2bf(cp.x); Ag[1]=f2bf(cp.y); Ag[2]=f2bf(cp.z); Ag[3]=f2bf(nv.x);
        Ag[4]=f2bf(nv.y); Ag[5]=f2bf(nv.z); Ag[6]=f2bf(dx);   Ag[7]=f2bf(dy);
    } else {
        Ag[0]=f2bf(dz); Ag[1]=f2bf(dist);
        Ag[2]=0; Ag[3]=0; Ag[4]=0; Ag[5]=0; Ag[6]=0; Ag[7]=0;
    }
    f32x16 cz = {0.f,0.f,0.f,0.f,0.f,0.f,0.f,0.f,0.f,0.f,0.f,0.f,0.f,0.f,0.f,0.f};
    f32x16 D1 = __builtin_amdgcn_mfma_f32_32x32x16_bf16(Ag, Bf1, cz, 0, 0, 0);

    // ---- cbn(lse1)+lrelu (channel = n_ lane-uniform), bf16, LDS transpose ----
    float sl1 = l1s[n_], bl1 = l1b[n_];
    #pragma unroll
    for (int r=0;r<16;r++){
        int m = (r&3) + 8*(r>>2) + 4*hi;     // row = (pt<<4)|nbr
        xiT[wv_][m*40 + n_] = (unsigned short)f2bf(lrelu(D1[r]*sl1 + bl1));
    }
    // same-wave write->read: in-order, compiler inserts lgkmcnt
    bf16x8s A20 = *(const bf16x8s*)&xiT[wv_][n_*40 + hi*8];        // row = l&31
    bf16x8s A21 = *(const bf16x8s*)&xiT[wv_][n_*40 + 16 + hi*8];

    // ---- MFMA2: x_info2 preact = x_info @ lse2^T (K=32, 2 chained) ----
    bf16x8s B0, B1;
    {
        const float* r0 = l2w + n_*32 + hi*8;
        #pragma unroll
        for (int i=0;i<8;i++){ B0[i] = f2bf(r0[i]); B1[i] = f2bf(r0[16+i]); }
    }
    f32x16 D = __builtin_amdgcn_mfma_f32_32x32x16_bf16(A20, B0, cz, 0, 0, 0);
    D = __builtin_amdgcn_mfma_f32_32x32x16_bf16(A21, B1, D, 0, 0, 0);

    float sl2 = l2s[n_], bl2 = l2b[n_];
    const int* irow0 = nidx + p0*KNN;
    float outv[2];
    #pragma unroll
    for (int pt=0; pt<2; pt++){
        size_t p = p0 + pt;
        float qc = q2[p*H + n_];
        int4 idlo = *(const int4*)(irow0 + pt*KNN + 4*hi);
        int4 idhi = *(const int4*)(irow0 + pt*KNN + 8 + 4*hi);
        int ids[8] = {idlo.x,idlo.y,idlo.z,idlo.w, idhi.x,idhi.y,idhi.z,idhi.w};
        float W[8], V[8];
        #pragma unroll
        for (int rr=0; rr<8; rr++){
            float xi2 = lrelu(D[pt*8+rr]*sl2 + bl2);
            float2 kv = *(const float2*)(kv2 + 2*(((size_t)b*NP + ids[rr])*H + n_));
            W[rr] = xi2*(kv.x - qc);
            V[rr] = kv.y;
        }
        float mx = W[0];
        #pragma unroll
        for (int rr=1;rr<8;rr++) mx = fmaxf(mx, W[rr]);
        mx = fmaxf(mx, __shfl_xor(mx, 32, 64));
        float den = 0.f, ac = 0.f;
        #pragma unroll
        for (int rr=0;rr<8;rr++){
            float e = __expf(W[rr]-mx);
            den += e; ac = fmaf(e, V[rr], ac);
        }
        den += __shfl_xor(den, 32, 64);
        ac  += __shfl_xor(ac,  32, 64);
        outv[pt] = ac/den;
    }
    if (l < 32){ bc[wv_][0][n_] = outv[0]; bc[wv_][1][n_] = outv[1]; }

    float fa=0.f, fb2=0.f;
    #pragma unroll
    for (int jj=0;jj<8;jj++){
        float4 xv  = *(const float4*)&bc[wv_][hi][jj*4];
        float4 wa4 = *(const float4*)&we[n_*36 + jj*4];
        float4 wb4 = *(const float4*)&we[(n_+32)*36 + jj*4];
        fa  += wa4.x*xv.x + wa4.y*xv.y + wa4.z*xv.z + wa4.w*xv.w;
        fb2 += wb4.x*xv.x + wb4.y*xv.y + wb4.z*xv.z + wb4.w*xv.w;
    }
    size_t pp = p0 + hi;
    f3[pp*64 + n_]      = f2bf(lrelu(fa *s2[n_]    + b2[n_]));
    f3[pp*64 + 32 + n_] = f2bf(lrelu(fb2*s2[n_+32] + b2[n_+32]));
}

// ---------------- K4: MFMA GEMM with bf16 B-operands loaded directly.
__global__ __launch_bounds__(256) void k_final(
    const short* __restrict__ ftp, const short* __restrict__ f3,
    const float* __restrict__ m2w, const float* __restrict__ m2s, const float* __restrict__ m2b,
    const float* __restrict__ rw, const float* __restrict__ rs, const float* __restrict__ rb,
    float* __restrict__ out)
{
    int t = threadIdx.x;
    int l  = t & 63;
    int w  = t >> 6;
    int lr = l & 15;
    int lg = l >> 4;
    int ot0 = w * 32;

    bf16x8s A[2][4];
    float bias[2][4];
    #pragma unroll
    for (int mt=0; mt<2; mt++){
        int o = ot0 + mt*16 + lr;
        float scm = m2s[o], scr = rs[o];
        const float* pm = m2w + (size_t)o*64 + lg*8;
        const float* pr = rw  + (size_t)o*64 + lg*8;
        #pragma unroll
        for (int kk=0;kk<2;kk++)
            A[mt][kk] = pack8(*(const float4*)(pm + kk*32),
                              *(const float4*)(pm + kk*32 + 4), scm);
        #pragma unroll
        for (int kk=0;kk<2;kk++)
            A[mt][2+kk] = pack8(*(const float4*)(pr + kk*32),
                                *(const float4*)(pr + kk*32 + 4), scr);
        int od = ot0 + mt*16 + lg*4;
        #pragma unroll
        for (int r=0;r<4;r++) bias[mt][r] = m2b[od+r] + rb[od+r];
    }

    size_t pbase = (size_t)blockIdx.x * 64;
    int b = (int)(pbase >> 12);
    float* ob = out + ((size_t)b*128)*NP;

    #pragma unroll
    for (int ti=0; ti<4; ti++){
        size_t p0 = pbase + ti*16;
        int n0 = (int)(p0 & (NP-1));
        const short* fp3 = f3  + (p0 + lr)*64 + lg*8;
        const short* fpt = ftp + (p0 + lr)*64 + lg*8;
        bf16x8s Bf[4];
        Bf[0] = *(const bf16x8s*)(fp3);
        Bf[1] = *(const bf16x8s*)(fp3 + 32);
        Bf[2] = *(const bf16x8s*)(fpt);
        Bf[3] = *(const bf16x8s*)(fpt + 32);
        #pragma unroll
        for (int mt=0;mt<2;mt++){
            f32x4 D = {0.f,0.f,0.f,0.f};
            #pragma unroll
            for (int kk=0;kk<4;kk++)
                D = __builtin_amdgcn_mfma_f32_16x16x32_bf16(A[mt][kk], Bf[kk], D, 0, 0, 0);
            #pragma unroll
            for (int r=0;r<4;r++){
                int od = ot0 + mt*16 + lg*4 + r;
                ob[(size_t)od*NP + n0 + lr] = lrelu(D[r] + bias[mt][r]);
            }
        }
    }
}

extern "C" void kernel_launch(void* const* d_in, const int* in_sizes, int n_in,
                              void* d_out, int out_size, void* d_ws, size_t ws_size,
                              hipStream_t stream)
{
    (void)in_sizes; (void)n_in; (void)out_size; (void)ws_size;
    const float* x     = (const float*)d_in[0];
    const float* feat  = (const float*)d_in[1];
    const int*   nidx  = (const int*)  d_in[2];
    const float* m1w=(const float*)d_in[3],  *m1s=(const float*)d_in[4],  *m1b=(const float*)d_in[5];
    const float* l1w=(const float*)d_in[6],  *l1s=(const float*)d_in[7],  *l1b=(const float*)d_in[8];
    const float* p1wq=(const float*)d_in[9],  *p1sq=(const float*)d_in[10], *p1bq=(const float*)d_in[11];
    const float* p1wk=(const float*)d_in[12], *p1sk=(const float*)d_in[13], *p1bk=(const float*)d_in[14];
    const float* p1wv=(const float*)d_in[15], *p1sv=(const float*)d_in[16], *p1bv=(const float*)d_in[17];
    const float* p1w2=(const float*)d_in[18], *p1s2=(const float*)d_in[19], *p1b2=(const float*)d_in[20];
    const float* p2wq=(const float*)d_in[21], *p2sq=(const float*)d_in[22], *p2bq=(const float*)d_in[23];
    const float* p2wk=(const float*)d_in[24], *p2sk=(const float*)d_in[25], *p2bk=(const float*)d_in[26];
    const float* p2wv=(const float*)d_in[27], *p2sv=(const float*)d_in[28], *p2bv=(const float*)d_in[29];
    const float* p2w2=(const float*)d_in[30], *p2s2=(const float*)d_in[31], *p2b2=(const float*)d_in[32];
    const float* l2w=(const float*)d_in[33], *l2s=(const float*)d_in[34], *l2b=(const float*)d_in[35];
    const float* m2w=(const float*)d_in[36], *m2s=(const float*)d_in[37], *m2b=(const float*)d_in[38];
    const float* rw =(const float*)d_in[39], *rs =(const float*)d_in[40], *rb =(const float*)d_in[41];

    float* ws = (float*)d_ws;
    float* q1  = ws;                    // PN*32 f32
    float* kv1 = ws + PN*32;            // PN*64 f32
    float* q2  = ws + PN*96;            // PN*32 f32
    float* kv2 = ws + PN*128;           // PN*64 f32
    float* xp  = ws + PN*192;           // PN*4 f32
    short* ftp = (short*)(ws + PN*196); // PN*64 bf16 (= PN*32 f32 slots)
    short* f3  = (short*)ws;            // PN*64 bf16 (aliases q1, dead after pool1)

    float* outp = (float*)d_out;

    k_pointwise<<<dim3(PN/64),dim3(256),0,stream>>>(feat, x, m1w,m1s,m1b,
        p1wq,p1sq,p1bq, p1wk,p1sk,p1bk, p1wv,p1sv,p1bv, q1,kv1, xp, ftp);
    k_pool1<<<dim3(PN/8),dim3(256),0,stream>>>(xp,nidx, q1,kv1,
        l1w,l1s,l1b, p1w2,p1s2,p1b2,
        p2wq,p2sq,p2bq, p2wk,p2sk,p2bk, p2wv,p2sv,p2bv, q2,kv2);
    k_pool2<<<dim3(PN/8),dim3(256),0,stream>>>(xp,nidx, q2,kv2,
        l1w,l1s,l1b, l2w,l2s,l2b, p2w2,p2s2,p2b2, f3);
    k_final<<<dim3(PN/64),dim3(256),0,stream>>>(ftp, f3, m2w,m2s,m2b, rw,rs,rb, outp);
}

// Round 11
// 301.938 us; speedup vs baseline: 3.6484x; 1.0042x over previous
//
#include <hip/hip_runtime.h>
#include <cstdint>
#include <cstddef>

#define NB 16
#define NP 4096
#define KNN 16
#define CIN 64
#define H 32
#define OCC 64
#define PN ((size_t)NB*NP)

__device__ __forceinline__ float lrelu(float v){ return v > 0.f ? v : 0.2f*v; }
__device__ __forceinline__ float reluf(float v){ return v > 0.f ? v : 0.f; }

typedef __attribute__((ext_vector_type(8)))  short bf16x8s;
typedef __attribute__((ext_vector_type(4)))  float f32x4;
typedef __attribute__((ext_vector_type(16))) float f32x16;

__device__ __forceinline__ short f2bf(float f){
    union { float f; unsigned u; } v; v.f = f;
    unsigned r = v.u + 0x7fffu + ((v.u >> 16) & 1u);   // RNE
    return (short)(r >> 16);
}

// ---------------- K1: f1 = lrelu(cbn(ft,mlp1)); q1/kv1 = relu(cbn(f1,p1_*))
// Also: block 0 preps bf16 weight tables for pool2's fused final GEMM.
__global__ __launch_bounds__(256) void k_pointwise(
    const float* __restrict__ feat, const float* __restrict__ xpos,
    const float* __restrict__ w1, const float* __restrict__ s1, const float* __restrict__ b1,
    const float* __restrict__ wq, const float* __restrict__ sq, const float* __restrict__ bq,
    const float* __restrict__ wk, const float* __restrict__ sk, const float* __restrict__ bk,
    const float* __restrict__ wv, const float* __restrict__ sv, const float* __restrict__ bv,
    float* __restrict__ q1, float* __restrict__ kv1,
    float* __restrict__ xp, short* __restrict__ ftp,
    const float* __restrict__ m2w, const float* __restrict__ m2s, const float* __restrict__ m2b,
    const float* __restrict__ rw, const float* __restrict__ rs, const float* __restrict__ rb,
    const float* __restrict__ p2w2,
    short* __restrict__ wbigW, short* __restrict__ w2bW, float* __restrict__ bbW)
{
    __shared__ float ftile[CIN][65];
    __shared__ float f1t[H][65];
    int t = threadIdx.x;
    int l = t & 63;
    int g = __builtin_amdgcn_readfirstlane(t >> 6);
    int bid = blockIdx.x;
    int b  = bid >> 6;
    int n0 = (bid & 63) * 64;
    int n  = n0 + l;
    size_t p = (size_t)b*NP + n;

    const float* fb = feat + ((size_t)b*CIN)*NP + n;
    float fv[16];
    #pragma unroll
    for (int k=0;k<16;k++){
        int c = g*16 + k;
        fv[k] = fb[(size_t)c*NP];
        ftile[c][l] = fv[k];
    }
    {
        bf16x8s h0, h1;
        #pragma unroll
        for (int i=0;i<8;i++){ h0[i] = f2bf(fv[i]); h1[i] = f2bf(fv[8+i]); }
        *(bf16x8s*)(ftp + p*64 + g*16)     = h0;
        *(bf16x8s*)(ftp + p*64 + g*16 + 8) = h1;
    }
    if (g == 0){
        const float* xb = xpos + (size_t)b*3*NP;
        *(float4*)(xp + 4*p) = make_float4(xb[n], xb[NP+n], xb[2*NP+n], 0.f);
    }
    __syncthreads();

    float acc[8];
    #pragma unroll
    for (int u=0;u<8;u++) acc[u] = 0.f;
    #pragma unroll
    for (int c=0;c<CIN;c++){
        float x = ftile[c][l];
        #pragma unroll
        for (int u=0;u<8;u++) acc[u] = fmaf(w1[(g*8+u)*CIN+c], x, acc[u]);
    }
    #pragma unroll
    for (int u=0;u<8;u++){
        int h = g*8+u;
        f1t[h][l] = lrelu(acc[u]*s1[h] + b1[h]);
    }
    __syncthreads();

    float aq[8], ak[8], av[8];
    #pragma unroll
    for (int u=0;u<8;u++){ aq[u]=0.f; ak[u]=0.f; av[u]=0.f; }
    #pragma unroll
    for (int j=0;j<H;j++){
        float x = f1t[j][l];
        #pragma unroll
        for (int u=0;u<8;u++){
            int h = g*8+u;
            aq[u] = fmaf(wq[h*H+j], x, aq[u]);
            ak[u] = fmaf(wk[h*H+j], x, ak[u]);
            av[u] = fmaf(wv[h*H+j], x, av[u]);
        }
    }
    float qr[8], kr[8], vr[8];
    #pragma unroll
    for (int u=0;u<8;u++){
        int h = g*8+u;
        qr[u] = reluf(aq[u]*sq[h]+bq[h]);
        kr[u] = reluf(ak[u]*sk[h]+bk[h]);
        vr[u] = reluf(av[u]*sv[h]+bv[h]);
    }
    size_t qb = p*H + g*8;
    *(float4*)(q1+qb)   = make_float4(qr[0],qr[1],qr[2],qr[3]);
    *(float4*)(q1+qb+4) = make_float4(qr[4],qr[5],qr[6],qr[7]);
    size_t kb = (p*H + g*8)*2;
    #pragma unroll
    for (int u2=0;u2<4;u2++)
        *(float4*)(kv1+kb+u2*4) = make_float4(kr[u2*2],vr[u2*2],kr[u2*2+1],vr[u2*2+1]);

    // ---- weight prep (block 0 only): Wbig bf16 scale-folded, p2_w2 bf16, fused bias
    if (bid == 0){
        int o = t >> 1, half = t & 1;
        const float* srcp = half ? (rw + (size_t)o*64) : (m2w + (size_t)o*64);
        float sc = half ? rs[o] : m2s[o];
        short* dst = wbigW + (size_t)o*128 + half*64;
        #pragma unroll
        for (int j=0;j<64;j+=8){
            bf16x8s v8;
            #pragma unroll
            for (int i=0;i<8;i++) v8[i] = f2bf(srcp[j+i]*sc);
            *(bf16x8s*)(dst + j) = v8;
        }
        if (!half) bbW[o] = m2b[o] + rb[o];
        {
            int i0 = t*8;      // 256*8 = 2048 = 64*32
            bf16x8s w8;
            #pragma unroll
            for (int i=0;i<8;i++) w8[i] = f2bf(p2w2[i0+i]);
            *(bf16x8s*)(w2bW + i0) = w8;
        }
    }
}

// ---------------- K2: pool1, 2 points/wave via mfma_32x32x16. XCD-swizzled blocks.
__global__ __launch_bounds__(256) void k_pool1(
    const float* __restrict__ xp, const int* __restrict__ nidx,
    const float* __restrict__ q1, const float* __restrict__ kv1,
    const float* __restrict__ l1w, const float* __restrict__ l1s, const float* __restrict__ l1b,
    const float* __restrict__ w2, const float* __restrict__ s2, const float* __restrict__ b2,
    const float* __restrict__ wq, const float* __restrict__ sq, const float* __restrict__ bq,
    const float* __restrict__ wk, const float* __restrict__ sk, const float* __restrict__ bk,
    const float* __restrict__ wv, const float* __restrict__ sv, const float* __restrict__ bv,
    float* __restrict__ q2, float* __restrict__ kv2)
{
    __shared__ float wl[4][32*36];
    __shared__ float bcp[4][2][32];
    __shared__ float bcf[4][2][32];
    int t = threadIdx.x;
    {
        const float* wsrc[4] = {w2, wq, wk, wv};
        #pragma unroll
        for (int m=0;m<4;m++)
            for (int i=t;i<1024;i+=256)
                wl[m][(i>>5)*36 + (i&31)] = wsrc[m][i];
    }
    __syncthreads();

    int wv_ = t >> 6;
    int l   = t & 63;
    int n_  = l & 31;
    int hi  = l >> 5;
    int bid = blockIdx.x;
    int sb  = ((bid & 7) << 10) | (bid >> 3);
    size_t p0 = (size_t)sb*8 + (size_t)wv_*2;
    int b = (int)(p0 >> 12);

    bf16x8s Bf;
    if (hi == 0){
        #pragma unroll
        for (int i=0;i<8;i++) Bf[i] = f2bf(l1w[n_*10 + i]);
    } else {
        Bf[0] = f2bf(l1w[n_*10 + 8]);
        Bf[1] = f2bf(l1w[n_*10 + 9]);
        #pragma unroll
        for (int i=2;i<8;i++) Bf[i] = 0;
    }

    int ptA  = (l >> 4) & 1;
    int nbrA = l & 15;
    size_t pA = p0 + ptA;
    int idA = nidx[pA*KNN + nbrA];
    float4 cp = *(const float4*)(xp + 4*pA);
    float4 nv = *(const float4*)(xp + 4*((size_t)(b<<12)+idA));
    float dx = nv.x-cp.x, dy = nv.y-cp.y, dz = nv.z-cp.z;
    float dist = sqrtf(dx*dx+dy*dy+dz*dz + 1e-12f);
    bf16x8s A;
    if (hi == 0){
        A[0]=f2bf(cp.x); A[1]=f2bf(cp.y); A[2]=f2bf(cp.z); A[3]=f2bf(nv.x);
        A[4]=f2bf(nv.y); A[5]=f2bf(nv.z); A[6]=f2bf(dx);   A[7]=f2bf(dy);
    } else {
        A[0]=f2bf(dz); A[1]=f2bf(dist);
        A[2]=0; A[3]=0; A[4]=0; A[5]=0; A[6]=0; A[7]=0;
    }

    f32x16 cz = {0.f,0.f,0.f,0.f,0.f,0.f,0.f,0.f,0.f,0.f,0.f,0.f,0.f,0.f,0.f,0.f};
    f32x16 D = __builtin_amdgcn_mfma_f32_32x32x16_bf16(A, Bf, cz, 0, 0, 0);

    float sl1 = l1s[n_], bl1 = l1b[n_];
    const int* irow0 = nidx + p0*KNN;
    float outv[2];
    #pragma unroll
    for (int pt=0; pt<2; pt++){
        size_t p = p0 + pt;
        float qc = q1[p*H + n_];
        int4 idlo = *(const int4*)(irow0 + pt*KNN + 4*hi);
        int4 idhi = *(const int4*)(irow0 + pt*KNN + 8 + 4*hi);
        int ids[8] = {idlo.x,idlo.y,idlo.z,idlo.w, idhi.x,idhi.y,idhi.z,idhi.w};
        float W[8], V[8];
        #pragma unroll
        for (int rr=0; rr<8; rr++){
            float xi = lrelu(D[pt*8+rr]*sl1 + bl1);
            float2 kv = *(const float2*)(kv1 + 2*(((size_t)b*NP + ids[rr])*H + n_));
            W[rr] = xi*(kv.x - qc);
            V[rr] = kv.y;
        }
        float mx = W[0];
        #pragma unroll
        for (int rr=1;rr<8;rr++) mx = fmaxf(mx, W[rr]);
        mx = fmaxf(mx, __shfl_xor(mx, 32, 64));
        float den = 0.f, ac = 0.f;
        #pragma unroll
        for (int rr=0;rr<8;rr++){
            float e = __expf(W[rr]-mx);
            den += e; ac = fmaf(e, V[rr], ac);
        }
        den += __shfl_xor(den, 32, 64);
        ac  += __shfl_xor(ac,  32, 64);
        outv[pt] = ac/den;
    }
    if (l < 32){ bcp[wv_][0][n_] = outv[0]; bcp[wv_][1][n_] = outv[1]; }

    int c = n_;
    float f2a = 0.f;
    #pragma unroll
    for (int jj=0;jj<8;jj++){
        float4 xv = *(const float4*)&bcp[wv_][hi][jj*4];
        float4 w4 = *(const float4*)&wl[0][c*36 + jj*4];
        f2a += w4.x*xv.x + w4.y*xv.y + w4.z*xv.z + w4.w*xv.w;
    }
    float f2 = lrelu(f2a*s2[c] + b2[c]);
    bcf[wv_][hi][c] = f2;

    float aq=0.f, ak=0.f, av=0.f;
    #pragma unroll
    for (int jj=0;jj<8;jj++){
        float4 xv  = *(const float4*)&bcf[wv_][hi][jj*4];
        float4 wq4 = *(const float4*)&wl[1][c*36 + jj*4];
        float4 wk4 = *(const float4*)&wl[2][c*36 + jj*4];
        float4 wv4 = *(const float4*)&wl[3][c*36 + jj*4];
        aq += wq4.x*xv.x + wq4.y*xv.y + wq4.z*xv.z + wq4.w*xv.w;
        ak += wk4.x*xv.x + wk4.y*xv.y + wk4.z*xv.z + wk4.w*xv.w;
        av += wv4.x*xv.x + wv4.y*xv.y + wv4.z*xv.z + wv4.w*xv.w;
    }
    size_t base = (p0 + hi)*H + c;
    q2[base] = reluf(aq*sq[c]+bq[c]);
    *(float2*)(kv2 + 2*base) = make_float2(reluf(ak*sk[c]+bk[c]), reluf(av*sv[c]+bv[c]));
}

// ---------------- K3: pool2 FUSED — pooling (chained MFMA) + feat3 MFMA + final GEMM.
// 512 threads = 8 waves = 16 points/block. out written directly (k_final eliminated).
__global__ __launch_bounds__(512) void k_pool2(
    const float* __restrict__ xp, const int* __restrict__ nidx,
    const float* __restrict__ q2, const float* __restrict__ kv2,
    const float* __restrict__ l1w, const float* __restrict__ l1s, const float* __restrict__ l1b,
    const float* __restrict__ l2w, const float* __restrict__ l2s, const float* __restrict__ l2b,
    const short* __restrict__ w2bf, const float* __restrict__ s2, const float* __restrict__ b2,
    const short* __restrict__ ftp, const short* __restrict__ wbig, const float* __restrict__ bb,
    float* __restrict__ out)
{
    __shared__ unsigned short xiT[8][32*40];   // per-wave x_info transpose (20KB)
    __shared__ unsigned short bcb[16][40];     // pooled bf16 [pt][ch<32], pad 40
    __shared__ unsigned short xf[16][72];      // f3 bf16 [pt][ch<64], pad 72
    int t = threadIdx.x;
    int wv_ = t >> 6;
    int l   = t & 63;
    int n_  = l & 31;
    int hi  = l >> 5;
    int bid = blockIdx.x;
    int sb  = ((bid & 7) << 9) | (bid >> 3);   // nwg 4096 = 8 * 512, bijective
    size_t pbase = (size_t)sb * 16;
    size_t p0 = pbase + (size_t)wv_*2;
    int b = (int)(pbase >> 12);

    // ---- MFMA1: x_info preact = geom @ lse1^T ----
    bf16x8s Bf1;
    if (hi == 0){
        #pragma unroll
        for (int i=0;i<8;i++) Bf1[i] = f2bf(l1w[n_*10 + i]);
    } else {
        Bf1[0] = f2bf(l1w[n_*10 + 8]);
        Bf1[1] = f2bf(l1w[n_*10 + 9]);
        #pragma unroll
        for (int i=2;i<8;i++) Bf1[i] = 0;
    }
    int ptA  = (l >> 4) & 1;
    int nbrA = l & 15;
    size_t pA = p0 + ptA;
    int idA = nidx[pA*KNN + nbrA];
    float4 cp = *(const float4*)(xp + 4*pA);
    float4 nv = *(const float4*)(xp + 4*((size_t)(b<<12)+idA));
    float dx = nv.x-cp.x, dy = nv.y-cp.y, dz = nv.z-cp.z;
    float dist = sqrtf(dx*dx+dy*dy+dz*dz + 1e-12f);
    bf16x8s Ag;
    if (hi == 0){
        Ag[0]=f2bf(cp.x); Ag[1]=f2bf(cp.y); Ag[2]=f2bf(cp.z); Ag[3]=f2bf(nv.x);
        Ag[4]=f2bf(nv.y); Ag[5]=f2bf(nv.z); Ag[6]=f2bf(dx);   Ag[7]=f2bf(dy);
    } else {
        Ag[0]=f2bf(dz); Ag[1]=f2bf(dist);
        Ag[2]=0; Ag[3]=0; Ag[4]=0; Ag[5]=0; Ag[6]=0; Ag[7]=0;
    }
    f32x16 cz = {0.f,0.f,0.f,0.f,0.f,0.f,0.f,0.f,0.f,0.f,0.f,0.f,0.f,0.f,0.f,0.f};
    f32x16 D1 = __builtin_amdgcn_mfma_f32_32x32x16_bf16(Ag, Bf1, cz, 0, 0, 0);

    // ---- cbn+lrelu, LDS transpose, MFMA2: x_info2 = x_info @ lse2^T ----
    float sl1 = l1s[n_], bl1 = l1b[n_];
    #pragma unroll
    for (int r=0;r<16;r++){
        int m = (r&3) + 8*(r>>2) + 4*hi;
        xiT[wv_][m*40 + n_] = (unsigned short)f2bf(lrelu(D1[r]*sl1 + bl1));
    }
    bf16x8s A20 = *(const bf16x8s*)&xiT[wv_][n_*40 + hi*8];
    bf16x8s A21 = *(const bf16x8s*)&xiT[wv_][n_*40 + 16 + hi*8];
    bf16x8s B0, B1;
    {
        const float* r0 = l2w + n_*32 + hi*8;
        #pragma unroll
        for (int i=0;i<8;i++){ B0[i] = f2bf(r0[i]); B1[i] = f2bf(r0[16+i]); }
    }
    f32x16 D = __builtin_amdgcn_mfma_f32_32x32x16_bf16(A20, B0, cz, 0, 0, 0);
    D = __builtin_amdgcn_mfma_f32_32x32x16_bf16(A21, B1, D, 0, 0, 0);

    // ---- gather + softmax pooling ----
    float sl2 = l2s[n_], bl2 = l2b[n_];
    const int* irow0 = nidx + p0*KNN;
    float outv[2];
    #pragma unroll
    for (int pt=0; pt<2; pt++){
        size_t p = p0 + pt;
        float qc = q2[p*H + n_];
        int4 idlo = *(const int4*)(irow0 + pt*KNN + 4*hi);
        int4 idhi = *(const int4*)(irow0 + pt*KNN + 8 + 4*hi);
        int ids[8] = {idlo.x,idlo.y,idlo.z,idlo.w, idhi.x,idhi.y,idhi.z,idhi.w};
        float W[8], V[8];
        #pragma unroll
        for (int rr=0; rr<8; rr++){
            float xi2 = lrelu(D[pt*8+rr]*sl2 + bl2);
            float2 kv = *(const float2*)(kv2 + 2*(((size_t)b*NP + ids[rr])*H + n_));
            W[rr] = xi2*(kv.x - qc);
            V[rr] = kv.y;
        }
        float mx = W[0];
        #pragma unroll
        for (int rr=1;rr<8;rr++) mx = fmaxf(mx, W[rr]);
        mx = fmaxf(mx, __shfl_xor(mx, 32, 64));
        float den = 0.f, ac = 0.f;
        #pragma unroll
        for (int rr=0;rr<8;rr++){
            float e = __expf(W[rr]-mx);
            den += e; ac = fmaf(e, V[rr], ac);
        }
        den += __shfl_xor(den, 32, 64);
        ac  += __shfl_xor(ac,  32, 64);
        outv[pt] = ac/den;
    }
    if (l < 32){
        bcb[wv_*2 + 0][n_] = (unsigned short)f2bf(outv[0]);
        bcb[wv_*2 + 1][n_] = (unsigned short)f2bf(outv[1]);
    }
    __syncthreads();

    int lr = l & 15, kg = l >> 4;
    // ---- feat3 = lrelu(cbn(pooled @ p2_w2^T)) via MFMA (waves 0-3, 16pts dense) ----
    if (wv_ < 4){
        bf16x8s Aw = *(const bf16x8s*)(w2bf + (wv_*16 + lr)*32 + kg*8);
        bf16x8s Bp = *(const bf16x8s*)&bcb[lr][kg*8];
        f32x4 zz = {0.f,0.f,0.f,0.f};
        f32x4 Df = __builtin_amdgcn_mfma_f32_16x16x32_bf16(Aw, Bp, zz, 0, 0, 0);
        int ch0 = wv_*16 + kg*4;
        float4 s4 = *(const float4*)(s2 + ch0);
        float4 b4 = *(const float4*)(b2 + ch0);
        xf[lr][ch0+0] = (unsigned short)f2bf(lrelu(Df[0]*s4.x + b4.x));
        xf[lr][ch0+1] = (unsigned short)f2bf(lrelu(Df[1]*s4.y + b4.y));
        xf[lr][ch0+2] = (unsigned short)f2bf(lrelu(Df[2]*s4.z + b4.z));
        xf[lr][ch0+3] = (unsigned short)f2bf(lrelu(Df[3]*s4.w + b4.w));
    }
    __syncthreads();

    // ---- final GEMM: out[p,o]=lrelu([f3|ftp]@Wbig^T + bb), wave = 16-out tile ----
    int o0 = wv_ * 16;
    const short* wr = wbig + (size_t)(o0 + lr)*128 + kg*8;
    bf16x8s Af0 = *(const bf16x8s*)(wr);
    bf16x8s Af1 = *(const bf16x8s*)(wr + 32);
    bf16x8s Af2 = *(const bf16x8s*)(wr + 64);
    bf16x8s Af3 = *(const bf16x8s*)(wr + 96);
    bf16x8s Bx0 = *(const bf16x8s*)&xf[lr][kg*8];
    bf16x8s Bx1 = *(const bf16x8s*)&xf[lr][32 + kg*8];
    const short* fr = ftp + (pbase + lr)*64 + kg*8;
    bf16x8s Bx2 = *(const bf16x8s*)(fr);
    bf16x8s Bx3 = *(const bf16x8s*)(fr + 32);
    f32x4 Dq = {0.f,0.f,0.f,0.f};
    Dq = __builtin_amdgcn_mfma_f32_16x16x32_bf16(Af0, Bx0, Dq, 0, 0, 0);
    Dq = __builtin_amdgcn_mfma_f32_16x16x32_bf16(Af1, Bx1, Dq, 0, 0, 0);
    Dq = __builtin_amdgcn_mfma_f32_16x16x32_bf16(Af2, Bx2, Dq, 0, 0, 0);
    Dq = __builtin_amdgcn_mfma_f32_16x16x32_bf16(Af3, Bx3, Dq, 0, 0, 0);
    float4 bb4 = *(const float4*)(bb + o0 + kg*4);
    int n0 = (int)(pbase & (NP-1));
    float* ob = out + ((size_t)b*128)*NP + n0 + lr;
    ob[(size_t)(o0 + kg*4 + 0)*NP] = lrelu(Dq[0] + bb4.x);
    ob[(size_t)(o0 + kg*4 + 1)*NP] = lrelu(Dq[1] + bb4.y);
    ob[(size_t)(o0 + kg*4 + 2)*NP] = lrelu(Dq[2] + bb4.z);
    ob[(size_t)(o0 + kg*4 + 3)*NP] = lrelu(Dq[3] + bb4.w);
}

extern "C" void kernel_launch(void* const* d_in, const int* in_sizes, int n_in,
                              void* d_out, int out_size, void* d_ws, size_t ws_size,
                              hipStream_t stream)
{
    (void)in_sizes; (void)n_in; (void)out_size; (void)ws_size;
    const float* x     = (const float*)d_in[0];
    const float* feat  = (const float*)d_in[1];
    const int*   nidx  = (const int*)  d_in[2];
    const float* m1w=(const float*)d_in[3],  *m1s=(const float*)d_in[4],  *m1b=(const float*)d_in[5];
    const float* l1w=(const float*)d_in[6],  *l1s=(const float*)d_in[7],  *l1b=(const float*)d_in[8];
    const float* p1wq=(const float*)d_in[9],  *p1sq=(const float*)d_in[10], *p1bq=(const float*)d_in[11];
    const float* p1wk=(const float*)d_in[12], *p1sk=(const float*)d_in[13], *p1bk=(const float*)d_in[14];
    const float* p1wv=(const float*)d_in[15], *p1sv=(const float*)d_in[16], *p1bv=(const float*)d_in[17];
    const float* p1w2=(const float*)d_in[18], *p1s2=(const float*)d_in[19], *p1b2=(const float*)d_in[20];
    const float* p2wq=(const float*)d_in[21], *p2sq=(const float*)d_in[22], *p2bq=(const float*)d_in[23];
    const float* p2wk=(const float*)d_in[24], *p2sk=(const float*)d_in[25], *p2bk=(const float*)d_in[26];
    const float* p2wv=(const float*)d_in[27], *p2sv=(const float*)d_in[28], *p2bv=(const float*)d_in[29];
    const float* p2w2=(const float*)d_in[30], *p2s2=(const float*)d_in[31], *p2b2=(const float*)d_in[32];
    const float* l2w=(const float*)d_in[33], *l2s=(const float*)d_in[34], *l2b=(const float*)d_in[35];
    const float* m2w=(const float*)d_in[36], *m2s=(const float*)d_in[37], *m2b=(const float*)d_in[38];
    const float* rw =(const float*)d_in[39], *rs =(const float*)d_in[40], *rb =(const float*)d_in[41];

    float* ws = (float*)d_ws;
    float* q1  = ws;                    // PN*32 f32
    float* kv1 = ws + PN*32;            // PN*64 f32
    float* q2  = ws + PN*96;            // PN*32 f32
    float* kv2 = ws + PN*128;           // PN*64 f32
    float* xp  = ws + PN*192;           // PN*4 f32
    short* ftp = (short*)(ws + PN*196); // PN*64 bf16 -> ends at PN*228 f32
    short* wbig = (short*)(ws + PN*228);        // 128*128 bf16 (scale-folded [m2w|rw])
    short* w2bf = wbig + 16384;                 // 64*32 bf16 (p2_w2)
    float* bb   = (float*)(w2bf + 2048);        // 128 f32 (m2b + rb)

    float* outp = (float*)d_out;

    k_pointwise<<<dim3(PN/64),dim3(256),0,stream>>>(feat, x, m1w,m1s,m1b,
        p1wq,p1sq,p1bq, p1wk,p1sk,p1bk, p1wv,p1sv,p1bv, q1,kv1, xp, ftp,
        m2w,m2s,m2b, rw,rs,rb, p2w2, wbig, w2bf, bb);
    k_pool1<<<dim3(PN/8),dim3(256),0,stream>>>(xp,nidx, q1,kv1,
        l1w,l1s,l1b, p1w2,p1s2,p1b2,
        p2wq,p2sq,p2bq, p2wk,p2sk,p2bk, p2wv,p2sv,p2bv, q2,kv2);
    k_pool2<<<dim3(PN/16),dim3(512),0,stream>>>(xp,nidx, q2,kv2,
        l1w,l1s,l1b, l2w,l2s,l2b, w2bf, p2s2, p2b2, ftp, wbig, bb, outp);
}

// Round 12
// 294.555 us; speedup vs baseline: 3.7399x; 1.0251x over previous
//
#include <hip/hip_runtime.h>
#include <cstdint>
#include <cstddef>

#define NB 16
#define NP 4096
#define KNN 16
#define CIN 64
#define H 32
#define OCC 64
#define PN ((size_t)NB*NP)

__device__ __forceinline__ float lrelu(float v){ return v > 0.f ? v : 0.2f*v; }
__device__ __forceinline__ float reluf(float v){ return v > 0.f ? v : 0.f; }

typedef __attribute__((ext_vector_type(8)))  short bf16x8s;
typedef __attribute__((ext_vector_type(4)))  float f32x4;
typedef __attribute__((ext_vector_type(16))) float f32x16;

__device__ __forceinline__ short f2bf(float f){
    union { float f; unsigned u; } v; v.f = f;
    unsigned r = v.u + 0x7fffu + ((v.u >> 16) & 1u);   // RNE
    return (short)(r >> 16);
}

// ---------------- K1: MFMA edition. f1 = lrelu(cbn(ft,mlp1)); q1/kv1 = relu(cbn(f1,p1_*))
// Block = 256 thr = 4 waves, 64 points. Wave w owns points w*16..w*16+15.
// Also: block 0 preps bf16 weight tables for pool2's fused final GEMM.
__global__ __launch_bounds__(256) void k_pointwise(
    const float* __restrict__ feat, const float* __restrict__ xpos,
    const float* __restrict__ w1, const float* __restrict__ s1, const float* __restrict__ b1,
    const float* __restrict__ wq, const float* __restrict__ sq, const float* __restrict__ bq,
    const float* __restrict__ wk, const float* __restrict__ sk, const float* __restrict__ bk,
    const float* __restrict__ wv, const float* __restrict__ sv, const float* __restrict__ bv,
    float* __restrict__ q1, float* __restrict__ kv1,
    float* __restrict__ xp, short* __restrict__ ftp,
    const float* __restrict__ m2w, const float* __restrict__ m2s, const float* __restrict__ m2b,
    const float* __restrict__ rw, const float* __restrict__ rs, const float* __restrict__ rb,
    const float* __restrict__ p2w2,
    short* __restrict__ wbigW, short* __restrict__ w2bW, float* __restrict__ bbW)
{
    __shared__ unsigned short ftb[64*72];   // [pt][ch<64] bf16, row 144B
    __shared__ unsigned short f1b[64*40];   // [pt][ch<32] bf16, row 80B
    int t = threadIdx.x;
    int l = t & 63;                         // point (staging)
    int g = t >> 6;                         // wave / channel group
    int bid = blockIdx.x;
    int b  = bid >> 6;
    int n0 = (bid & 63) * 64;
    int n  = n0 + l;
    size_t p = (size_t)b*NP + n;

    // ---- stage feat -> bf16 LDS + ftp global ----
    {
        const float* fb = feat + ((size_t)b*CIN)*NP + n;
        float fv[16];
        #pragma unroll
        for (int k=0;k<16;k++) fv[k] = fb[(size_t)(g*16+k)*NP];   // coalesced rows
        bf16x8s h0, h1;
        #pragma unroll
        for (int i=0;i<8;i++){ h0[i] = f2bf(fv[i]); h1[i] = f2bf(fv[8+i]); }
        *(bf16x8s*)(ftp + p*64 + g*16)     = h0;
        *(bf16x8s*)(ftp + p*64 + g*16 + 8) = h1;
        *(bf16x8s*)&ftb[l*72 + g*16]       = h0;
        *(bf16x8s*)&ftb[l*72 + g*16 + 8]   = h1;
    }
    if (g == 0){
        const float* xb = xpos + (size_t)b*3*NP;
        *(float4*)(xp + 4*p) = make_float4(xb[n], xb[NP+n], xb[2*NP+n], 0.f);
    }
    // ---- weight prep (block 0 only) ----
    if (bid == 0){
        int o = t >> 1, half = t & 1;
        const float* srcp = half ? (rw + (size_t)o*64) : (m2w + (size_t)o*64);
        float sc = half ? rs[o] : m2s[o];
        short* dst = wbigW + (size_t)o*128 + half*64;
        #pragma unroll
        for (int j=0;j<64;j+=8){
            bf16x8s v8;
            #pragma unroll
            for (int i=0;i<8;i++) v8[i] = f2bf(srcp[j+i]*sc);
            *(bf16x8s*)(dst + j) = v8;
        }
        if (!half) bbW[o] = m2b[o] + rb[o];
        {
            int i0 = t*8;
            bf16x8s w8;
            #pragma unroll
            for (int i=0;i<8;i++) w8[i] = f2bf(p2w2[i0+i]);
            *(bf16x8s*)(w2bW + i0) = w8;
        }
    }
    __syncthreads();

    int lr = t & 15;
    int kg = (t >> 4) & 3;
    int prow = g*16 + lr;                      // local point this lane maps to (B col)
    size_t pg = (size_t)b*NP + n0 + prow;      // global point for stores

    // ---- f1 GEMM: D = ftb @ (w1*s1)^T ; 2 m-tiles x 2 k-steps ----
    f32x4 Df0 = {0.f,0.f,0.f,0.f}, Df1 = {0.f,0.f,0.f,0.f};
    #pragma unroll
    for (int kk=0; kk<2; kk++){
        bf16x8s Bf = *(const bf16x8s*)&ftb[prow*72 + kk*32 + kg*8];
        {
            int h = lr;
            float sc = s1[h];
            const float* wr = w1 + h*64 + kk*32 + kg*8;
            bf16x8s Aw;
            #pragma unroll
            for (int i=0;i<8;i++) Aw[i] = f2bf(wr[i]*sc);
            Df0 = __builtin_amdgcn_mfma_f32_16x16x32_bf16(Aw, Bf, Df0, 0, 0, 0);
        }
        {
            int h = 16 + lr;
            float sc = s1[h];
            const float* wr = w1 + h*64 + kk*32 + kg*8;
            bf16x8s Aw;
            #pragma unroll
            for (int i=0;i<8;i++) Aw[i] = f2bf(wr[i]*sc);
            Df1 = __builtin_amdgcn_mfma_f32_16x16x32_bf16(Aw, Bf, Df1, 0, 0, 0);
        }
    }
    // f1 = lrelu(D + b1) -> bf16 -> f1b (intra-wave LDS, no barrier needed)
    {
        int ch = kg*4;
        float4 b4 = *(const float4*)(b1 + ch);
        unsigned u0 = (unsigned short)f2bf(lrelu(Df0[0]+b4.x))
                    | ((unsigned)(unsigned short)f2bf(lrelu(Df0[1]+b4.y)) << 16);
        unsigned u1 = (unsigned short)f2bf(lrelu(Df0[2]+b4.z))
                    | ((unsigned)(unsigned short)f2bf(lrelu(Df0[3]+b4.w)) << 16);
        *(uint2*)&f1b[prow*40 + ch] = make_uint2(u0, u1);
    }
    {
        int ch = 16 + kg*4;
        float4 b4 = *(const float4*)(b1 + ch);
        unsigned u0 = (unsigned short)f2bf(lrelu(Df1[0]+b4.x))
                    | ((unsigned)(unsigned short)f2bf(lrelu(Df1[1]+b4.y)) << 16);
        unsigned u1 = (unsigned short)f2bf(lrelu(Df1[2]+b4.z))
                    | ((unsigned)(unsigned short)f2bf(lrelu(Df1[3]+b4.w)) << 16);
        *(uint2*)&f1b[prow*40 + ch] = make_uint2(u0, u1);
    }

    // ---- q/k/v GEMM: K=32, 6 m-tiles (q:0-1, k:2-3, v:4-5) ----
    bf16x8s Bq = *(const bf16x8s*)&f1b[prow*40 + kg*8];
    float qv[6][4];
    {
        const float* wsrc[3] = {wq, wk, wv};
        const float* ssrc[3] = {sq, sk, sv};
        const float* bsrc[3] = {bq, bk, bv};
        #pragma unroll
        for (int m3=0; m3<3; m3++){
            #pragma unroll
            for (int mt=0; mt<2; mt++){
                int h = mt*16 + lr;
                float sc = ssrc[m3][h];
                const float* wr = wsrc[m3] + h*32 + kg*8;
                bf16x8s Aw;
                #pragma unroll
                for (int i=0;i<8;i++) Aw[i] = f2bf(wr[i]*sc);
                f32x4 Dq = {0.f,0.f,0.f,0.f};
                Dq = __builtin_amdgcn_mfma_f32_16x16x32_bf16(Aw, Bq, Dq, 0, 0, 0);
                int ch = mt*16 + kg*4;
                float4 b4 = *(const float4*)(bsrc[m3] + ch);
                qv[m3*2+mt][0] = reluf(Dq[0] + b4.x);
                qv[m3*2+mt][1] = reluf(Dq[1] + b4.y);
                qv[m3*2+mt][2] = reluf(Dq[2] + b4.z);
                qv[m3*2+mt][3] = reluf(Dq[3] + b4.w);
            }
        }
    }
    // ---- stores: q1 point-major f32; kv1 interleaved f32 ----
    size_t qb = pg*H;
    *(float4*)(q1 + qb + kg*4)      = make_float4(qv[0][0],qv[0][1],qv[0][2],qv[0][3]);
    *(float4*)(q1 + qb + 16 + kg*4) = make_float4(qv[1][0],qv[1][1],qv[1][2],qv[1][3]);
    #pragma unroll
    for (int mt=0; mt<2; mt++){
        int ch = mt*16 + kg*4;
        *(float4*)(kv1 + 2*(qb+ch))     = make_float4(qv[2+mt][0], qv[4+mt][0],
                                                      qv[2+mt][1], qv[4+mt][1]);
        *(float4*)(kv1 + 2*(qb+ch) + 4) = make_float4(qv[2+mt][2], qv[4+mt][2],
                                                      qv[2+mt][3], qv[4+mt][3]);
    }
}

// ---------------- K2: pool1, 2 points/wave via mfma_32x32x16. XCD-swizzled blocks.
__global__ __launch_bounds__(256) void k_pool1(
    const float* __restrict__ xp, const int* __restrict__ nidx,
    const float* __restrict__ q1, const float* __restrict__ kv1,
    const float* __restrict__ l1w, const float* __restrict__ l1s, const float* __restrict__ l1b,
    const float* __restrict__ w2, const float* __restrict__ s2, const float* __restrict__ b2,
    const float* __restrict__ wq, const float* __restrict__ sq, const float* __restrict__ bq,
    const float* __restrict__ wk, const float* __restrict__ sk, const float* __restrict__ bk,
    const float* __restrict__ wv, const float* __restrict__ sv, const float* __restrict__ bv,
    float* __restrict__ q2, float* __restrict__ kv2)
{
    __shared__ float wl[4][32*36];
    __shared__ float bcp[4][2][32];
    __shared__ float bcf[4][2][32];
    int t = threadIdx.x;
    {
        const float* wsrc[4] = {w2, wq, wk, wv};
        #pragma unroll
        for (int m=0;m<4;m++)
            for (int i=t;i<1024;i+=256)
                wl[m][(i>>5)*36 + (i&31)] = wsrc[m][i];
    }
    __syncthreads();

    int wv_ = t >> 6;
    int l   = t & 63;
    int n_  = l & 31;
    int hi  = l >> 5;
    int bid = blockIdx.x;
    int sb  = ((bid & 7) << 10) | (bid >> 3);
    size_t p0 = (size_t)sb*8 + (size_t)wv_*2;
    int b = (int)(p0 >> 12);

    bf16x8s Bf;
    if (hi == 0){
        #pragma unroll
        for (int i=0;i<8;i++) Bf[i] = f2bf(l1w[n_*10 + i]);
    } else {
        Bf[0] = f2bf(l1w[n_*10 + 8]);
        Bf[1] = f2bf(l1w[n_*10 + 9]);
        #pragma unroll
        for (int i=2;i<8;i++) Bf[i] = 0;
    }

    int ptA  = (l >> 4) & 1;
    int nbrA = l & 15;
    size_t pA = p0 + ptA;
    int idA = nidx[pA*KNN + nbrA];
    float4 cp = *(const float4*)(xp + 4*pA);
    float4 nv = *(const float4*)(xp + 4*((size_t)(b<<12)+idA));
    float dx = nv.x-cp.x, dy = nv.y-cp.y, dz = nv.z-cp.z;
    float dist = sqrtf(dx*dx+dy*dy+dz*dz + 1e-12f);
    bf16x8s A;
    if (hi == 0){
        A[0]=f2bf(cp.x); A[1]=f2bf(cp.y); A[2]=f2bf(cp.z); A[3]=f2bf(nv.x);
        A[4]=f2bf(nv.y); A[5]=f2bf(nv.z); A[6]=f2bf(dx);   A[7]=f2bf(dy);
    } else {
        A[0]=f2bf(dz); A[1]=f2bf(dist);
        A[2]=0; A[3]=0; A[4]=0; A[5]=0; A[6]=0; A[7]=0;
    }

    f32x16 cz = {0.f,0.f,0.f,0.f,0.f,0.f,0.f,0.f,0.f,0.f,0.f,0.f,0.f,0.f,0.f,0.f};
    f32x16 D = __builtin_amdgcn_mfma_f32_32x32x16_bf16(A, Bf, cz, 0, 0, 0);

    float sl1 = l1s[n_], bl1 = l1b[n_];
    const int* irow0 = nidx + p0*KNN;
    float outv[2];
    #pragma unroll
    for (int pt=0; pt<2; pt++){
        size_t p = p0 + pt;
        float qc = q1[p*H + n_];
        int4 idlo = *(const int4*)(irow0 + pt*KNN + 4*hi);
        int4 idhi = *(const int4*)(irow0 + pt*KNN + 8 + 4*hi);
        int ids[8] = {idlo.x,idlo.y,idlo.z,idlo.w, idhi.x,idhi.y,idhi.z,idhi.w};
        float W[8], V[8];
        #pragma unroll
        for (int rr=0; rr<8; rr++){
            float xi = lrelu(D[pt*8+rr]*sl1 + bl1);
            float2 kv = *(const float2*)(kv1 + 2*(((size_t)b*NP + ids[rr])*H + n_));
            W[rr] = xi*(kv.x - qc);
            V[rr] = kv.y;
        }
        float mx = W[0];
        #pragma unroll
        for (int rr=1;rr<8;rr++) mx = fmaxf(mx, W[rr]);
        mx = fmaxf(mx, __shfl_xor(mx, 32, 64));
        float den = 0.f, ac = 0.f;
        #pragma unroll
        for (int rr=0;rr<8;rr++){
            float e = __expf(W[rr]-mx);
            den += e; ac = fmaf(e, V[rr], ac);
        }
        den += __shfl_xor(den, 32, 64);
        ac  += __shfl_xor(ac,  32, 64);
        outv[pt] = ac/den;
    }
    if (l < 32){ bcp[wv_][0][n_] = outv[0]; bcp[wv_][1][n_] = outv[1]; }

    int c = n_;
    float f2a = 0.f;
    #pragma unroll
    for (int jj=0;jj<8;jj++){
        float4 xv = *(const float4*)&bcp[wv_][hi][jj*4];
        float4 w4 = *(const float4*)&wl[0][c*36 + jj*4];
        f2a += w4.x*xv.x + w4.y*xv.y + w4.z*xv.z + w4.w*xv.w;
    }
    float f2 = lrelu(f2a*s2[c] + b2[c]);
    bcf[wv_][hi][c] = f2;

    float aq=0.f, ak=0.f, av=0.f;
    #pragma unroll
    for (int jj=0;jj<8;jj++){
        float4 xv  = *(const float4*)&bcf[wv_][hi][jj*4];
        float4 wq4 = *(const float4*)&wl[1][c*36 + jj*4];
        float4 wk4 = *(const float4*)&wl[2][c*36 + jj*4];
        float4 wv4 = *(const float4*)&wl[3][c*36 + jj*4];
        aq += wq4.x*xv.x + wq4.y*xv.y + wq4.z*xv.z + wq4.w*xv.w;
        ak += wk4.x*xv.x + wk4.y*xv.y + wk4.z*xv.z + wk4.w*xv.w;
        av += wv4.x*xv.x + wv4.y*xv.y + wv4.z*xv.z + wv4.w*xv.w;
    }
    size_t base = (p0 + hi)*H + c;
    q2[base] = reluf(aq*sq[c]+bq[c]);
    *(float2*)(kv2 + 2*base) = make_float2(reluf(ak*sk[c]+bk[c]), reluf(av*sv[c]+bv[c]));
}

// ---------------- K3: pool2 FUSED — pooling (chained MFMA) + feat3 MFMA + final GEMM.
__global__ __launch_bounds__(512) void k_pool2(
    const float* __restrict__ xp, const int* __restrict__ nidx,
    const float* __restrict__ q2, const float* __restrict__ kv2,
    const float* __restrict__ l1w, const float* __restrict__ l1s, const float* __restrict__ l1b,
    const float* __restrict__ l2w, const float* __restrict__ l2s, const float* __restrict__ l2b,
    const short* __restrict__ w2bf, const float* __restrict__ s2, const float* __restrict__ b2,
    const short* __restrict__ ftp, const short* __restrict__ wbig, const float* __restrict__ bb,
    float* __restrict__ out)
{
    __shared__ unsigned short xiT[8][32*40];
    __shared__ unsigned short bcb[16][40];
    __shared__ unsigned short xf[16][72];
    int t = threadIdx.x;
    int wv_ = t >> 6;
    int l   = t & 63;
    int n_  = l & 31;
    int hi  = l >> 5;
    int bid = blockIdx.x;
    int sb  = ((bid & 7) << 9) | (bid >> 3);
    size_t pbase = (size_t)sb * 16;
    size_t p0 = pbase + (size_t)wv_*2;
    int b = (int)(pbase >> 12);

    bf16x8s Bf1;
    if (hi == 0){
        #pragma unroll
        for (int i=0;i<8;i++) Bf1[i] = f2bf(l1w[n_*10 + i]);
    } else {
        Bf1[0] = f2bf(l1w[n_*10 + 8]);
        Bf1[1] = f2bf(l1w[n_*10 + 9]);
        #pragma unroll
        for (int i=2;i<8;i++) Bf1[i] = 0;
    }
    int ptA  = (l >> 4) & 1;
    int nbrA = l & 15;
    size_t pA = p0 + ptA;
    int idA = nidx[pA*KNN + nbrA];
    float4 cp = *(const float4*)(xp + 4*pA);
    float4 nv = *(const float4*)(xp + 4*((size_t)(b<<12)+idA));
    float dx = nv.x-cp.x, dy = nv.y-cp.y, dz = nv.z-cp.z;
    float dist = sqrtf(dx*dx+dy*dy+dz*dz + 1e-12f);
    bf16x8s Ag;
    if (hi == 0){
        Ag[0]=f2bf(cp.x); Ag[1]=f2bf(cp.y); Ag[2]=f2bf(cp.z); Ag[3]=f2bf(nv.x);
        Ag[4]=f2bf(nv.y); Ag[5]=f2bf(nv.z); Ag[6]=f2bf(dx);   Ag[7]=f2bf(dy);
    } else {
        Ag[0]=f2bf(dz); Ag[1]=f2bf(dist);
        Ag[2]=0; Ag[3]=0; Ag[4]=0; Ag[5]=0; Ag[6]=0; Ag[7]=0;
    }
    f32x16 cz = {0.f,0.f,0.f,0.f,0.f,0.f,0.f,0.f,0.f,0.f,0.f,0.f,0.f,0.f,0.f,0.f};
    f32x16 D1 = __builtin_amdgcn_mfma_f32_32x32x16_bf16(Ag, Bf1, cz, 0, 0, 0);

    float sl1 = l1s[n_], bl1 = l1b[n_];
    #pragma unroll
    for (int r=0;r<16;r++){
        int m = (r&3) + 8*(r>>2) + 4*hi;
        xiT[wv_][m*40 + n_] = (unsigned short)f2bf(lrelu(D1[r]*sl1 + bl1));
    }
    bf16x8s A20 = *(const bf16x8s*)&xiT[wv_][n_*40 + hi*8];
    bf16x8s A21 = *(const bf16x8s*)&xiT[wv_][n_*40 + 16 + hi*8];
    bf16x8s B0, B1;
    {
        const float* r0 = l2w + n_*32 + hi*8;
        #pragma unroll
        for (int i=0;i<8;i++){ B0[i] = f2bf(r0[i]); B1[i] = f2bf(r0[16+i]); }
    }
    f32x16 D = __builtin_amdgcn_mfma_f32_32x32x16_bf16(A20, B0, cz, 0, 0, 0);
    D = __builtin_amdgcn_mfma_f32_32x32x16_bf16(A21, B1, D, 0, 0, 0);

    float sl2 = l2s[n_], bl2 = l2b[n_];
    const int* irow0 = nidx + p0*KNN;
    float outv[2];
    #pragma unroll
    for (int pt=0; pt<2; pt++){
        size_t p = p0 + pt;
        float qc = q2[p*H + n_];
        int4 idlo = *(const int4*)(irow0 + pt*KNN + 4*hi);
        int4 idhi = *(const int4*)(irow0 + pt*KNN + 8 + 4*hi);
        int ids[8] = {idlo.x,idlo.y,idlo.z,idlo.w, idhi.x,idhi.y,idhi.z,idhi.w};
        float W[8], V[8];
        #pragma unroll
        for (int rr=0; rr<8; rr++){
            float xi2 = lrelu(D[pt*8+rr]*sl2 + bl2);
            float2 kv = *(const float2*)(kv2 + 2*(((size_t)b*NP + ids[rr])*H + n_));
            W[rr] = xi2*(kv.x - qc);
            V[rr] = kv.y;
        }
        float mx = W[0];
        #pragma unroll
        for (int rr=1;rr<8;rr++) mx = fmaxf(mx, W[rr]);
        mx = fmaxf(mx, __shfl_xor(mx, 32, 64));
        float den = 0.f, ac = 0.f;
        #pragma unroll
        for (int rr=0;rr<8;rr++){
            float e = __expf(W[rr]-mx);
            den += e; ac = fmaf(e, V[rr], ac);
        }
        den += __shfl_xor(den, 32, 64);
        ac  += __shfl_xor(ac,  32, 64);
        outv[pt] = ac/den;
    }
    if (l < 32){
        bcb[wv_*2 + 0][n_] = (unsigned short)f2bf(outv[0]);
        bcb[wv_*2 + 1][n_] = (unsigned short)f2bf(outv[1]);
    }
    __syncthreads();

    int lr = l & 15, kg = l >> 4;
    if (wv_ < 4){
        bf16x8s Aw = *(const bf16x8s*)(w2bf + (wv_*16 + lr)*32 + kg*8);
        bf16x8s Bp = *(const bf16x8s*)&bcb[lr][kg*8];
        f32x4 zz = {0.f,0.f,0.f,0.f};
        f32x4 Df = __builtin_amdgcn_mfma_f32_16x16x32_bf16(Aw, Bp, zz, 0, 0, 0);
        int ch0 = wv_*16 + kg*4;
        float4 s4 = *(const float4*)(s2 + ch0);
        float4 b4 = *(const float4*)(b2 + ch0);
        xf[lr][ch0+0] = (unsigned short)f2bf(lrelu(Df[0]*s4.x + b4.x));
        xf[lr][ch0+1] = (unsigned short)f2bf(lrelu(Df[1]*s4.y + b4.y));
        xf[lr][ch0+2] = (unsigned short)f2bf(lrelu(Df[2]*s4.z + b4.z));
        xf[lr][ch0+3] = (unsigned short)f2bf(lrelu(Df[3]*s4.w + b4.w));
    }
    __syncthreads();

    int o0 = wv_ * 16;
    const short* wr = wbig + (size_t)(o0 + lr)*128 + kg*8;
    bf16x8s Af0 = *(const bf16x8s*)(wr);
    bf16x8s Af1 = *(const bf16x8s*)(wr + 32);
    bf16x8s Af2 = *(const bf16x8s*)(wr + 64);
    bf16x8s Af3 = *(const bf16x8s*)(wr + 96);
    bf16x8s Bx0 = *(const bf16x8s*)&xf[lr][kg*8];
    bf16x8s Bx1 = *(const bf16x8s*)&xf[lr][32 + kg*8];
    const short* fr = ftp + (pbase + lr)*64 + kg*8;
    bf16x8s Bx2 = *(const bf16x8s*)(fr);
    bf16x8s Bx3 = *(const bf16x8s*)(fr + 32);
    f32x4 Dq = {0.f,0.f,0.f,0.f};
    Dq = __builtin_amdgcn_mfma_f32_16x16x32_bf16(Af0, Bx0, Dq, 0, 0, 0);
    Dq = __builtin_amdgcn_mfma_f32_16x16x32_bf16(Af1, Bx1, Dq, 0, 0, 0);
    Dq = __builtin_amdgcn_mfma_f32_16x16x32_bf16(Af2, Bx2, Dq, 0, 0, 0);
    Dq = __builtin_amdgcn_mfma_f32_16x16x32_bf16(Af3, Bx3, Dq, 0, 0, 0);
    float4 bb4 = *(const float4*)(bb + o0 + kg*4);
    int n0 = (int)(pbase & (NP-1));
    float* ob = out + ((size_t)b*128)*NP + n0 + lr;
    ob[(size_t)(o0 + kg*4 + 0)*NP] = lrelu(Dq[0] + bb4.x);
    ob[(size_t)(o0 + kg*4 + 1)*NP] = lrelu(Dq[1] + bb4.y);
    ob[(size_t)(o0 + kg*4 + 2)*NP] = lrelu(Dq[2] + bb4.z);
    ob[(size_t)(o0 + kg*4 + 3)*NP] = lrelu(Dq[3] + bb4.w);
}

extern "C" void kernel_launch(void* const* d_in, const int* in_sizes, int n_in,
                              void* d_out, int out_size, void* d_ws, size_t ws_size,
                              hipStream_t stream)
{
    (void)in_sizes; (void)n_in; (void)out_size; (void)ws_size;
    const float* x     = (const float*)d_in[0];
    const float* feat  = (const float*)d_in[1];
    const int*   nidx  = (const int*)  d_in[2];
    const float* m1w=(const float*)d_in[3],  *m1s=(const float*)d_in[4],  *m1b=(const float*)d_in[5];
    const float* l1w=(const float*)d_in[6],  *l1s=(const float*)d_in[7],  *l1b=(const float*)d_in[8];
    const float* p1wq=(const float*)d_in[9],  *p1sq=(const float*)d_in[10], *p1bq=(const float*)d_in[11];
    const float* p1wk=(const float*)d_in[12], *p1sk=(const float*)d_in[13], *p1bk=(const float*)d_in[14];
    const float* p1wv=(const float*)d_in[15], *p1sv=(const float*)d_in[16], *p1bv=(const float*)d_in[17];
    const float* p1w2=(const float*)d_in[18], *p1s2=(const float*)d_in[19], *p1b2=(const float*)d_in[20];
    const float* p2wq=(const float*)d_in[21], *p2sq=(const float*)d_in[22], *p2bq=(const float*)d_in[23];
    const float* p2wk=(const float*)d_in[24], *p2sk=(const float*)d_in[25], *p2bk=(const float*)d_in[26];
    const float* p2wv=(const float*)d_in[27], *p2sv=(const float*)d_in[28], *p2bv=(const float*)d_in[29];
    const float* p2w2=(const float*)d_in[30], *p2s2=(const float*)d_in[31], *p2b2=(const float*)d_in[32];
    const float* l2w=(const float*)d_in[33], *l2s=(const float*)d_in[34], *l2b=(const float*)d_in[35];
    const float* m2w=(const float*)d_in[36], *m2s=(const float*)d_in[37], *m2b=(const float*)d_in[38];
    const float* rw =(const float*)d_in[39], *rs =(const float*)d_in[40], *rb =(const float*)d_in[41];

    float* ws = (float*)d_ws;
    float* q1  = ws;                    // PN*32 f32
    float* kv1 = ws + PN*32;            // PN*64 f32
    float* q2  = ws + PN*96;            // PN*32 f32
    float* kv2 = ws + PN*128;           // PN*64 f32
    float* xp  = ws + PN*192;           // PN*4 f32
    short* ftp = (short*)(ws + PN*196); // PN*64 bf16 -> ends at PN*228 f32
    short* wbig = (short*)(ws + PN*228);        // 128*128 bf16
    short* w2bf = wbig + 16384;                 // 64*32 bf16
    float* bb   = (float*)(w2bf + 2048);        // 128 f32

    float* outp = (float*)d_out;

    k_pointwise<<<dim3(PN/64),dim3(256),0,stream>>>(feat, x, m1w,m1s,m1b,
        p1wq,p1sq,p1bq, p1wk,p1sk,p1bk, p1wv,p1sv,p1bv, q1,kv1, xp, ftp,
        m2w,m2s,m2b, rw,rs,rb, p2w2, wbig, w2bf, bb);
    k_pool1<<<dim3(PN/8),dim3(256),0,stream>>>(xp,nidx, q1,kv1,
        l1w,l1s,l1b, p1w2,p1s2,p1b2,
        p2wq,p2sq,p2bq, p2wk,p2sk,p2bk, p2wv,p2sv,p2bv, q2,kv2);
    k_pool2<<<dim3(PN/16),dim3(512),0,stream>>>(xp,nidx, q2,kv2,
        l1w,l1s,l1b, l2w,l2s,l2b, w2bf, p2s2, p2b2, ftp, wbig, bb, outp);
}

// Round 13
// 261.877 us; speedup vs baseline: 4.2065x; 1.1248x over previous
//
#include <hip/hip_runtime.h>
#include <cstdint>
#include <cstddef>

#define NB 16
#define NP 4096
#define KNN 16
#define CIN 64
#define H 32
#define OCC 64
#define PN ((size_t)NB*NP)

__device__ __forceinline__ float lrelu(float v){ return v > 0.f ? v : 0.2f*v; }
__device__ __forceinline__ float reluf(float v){ return v > 0.f ? v : 0.f; }

typedef __attribute__((ext_vector_type(8)))  short bf16x8s;
typedef __attribute__((ext_vector_type(4)))  float f32x4;
typedef __attribute__((ext_vector_type(16))) float f32x16;

__device__ __forceinline__ short f2bf(float f){
    union { float f; unsigned u; } v; v.f = f;
    unsigned r = v.u + 0x7fffu + ((v.u >> 16) & 1u);   // RNE
    return (short)(r >> 16);
}

// ---------------- K1: MFMA pointwise + one-time weight-table prep (block 0)
__global__ __launch_bounds__(256) void k_pointwise(
    const float* __restrict__ feat, const float* __restrict__ xpos,
    const float* __restrict__ w1, const float* __restrict__ s1, const float* __restrict__ b1,
    const float* __restrict__ wq, const float* __restrict__ sq, const float* __restrict__ bq,
    const float* __restrict__ wk, const float* __restrict__ sk, const float* __restrict__ bk,
    const float* __restrict__ wv, const float* __restrict__ sv, const float* __restrict__ bv,
    float* __restrict__ q1, float* __restrict__ kv1,
    float* __restrict__ xp, short* __restrict__ ftp,
    const float* __restrict__ m2w, const float* __restrict__ m2s, const float* __restrict__ m2b,
    const float* __restrict__ rw, const float* __restrict__ rs, const float* __restrict__ rb,
    const float* __restrict__ p2w2,
    const float* __restrict__ l1w, const float* __restrict__ l2w,
    const float* __restrict__ p1w2, const float* __restrict__ p1s2,
    const float* __restrict__ w2q, const float* __restrict__ s2q,
    const float* __restrict__ w2k, const float* __restrict__ s2k,
    const float* __restrict__ w2v, const float* __restrict__ s2v,
    short* __restrict__ wbigW, short* __restrict__ w2bW, float* __restrict__ bbW,
    short* __restrict__ l1wbW, short* __restrict__ l2wbW,
    short* __restrict__ p1w2bW, short* __restrict__ pqkvbW)
{
    __shared__ unsigned short ftb[64*72];   // [pt][ch<64] bf16, row 144B
    __shared__ unsigned short f1b[64*40];   // [pt][ch<32] bf16, row 80B
    int t = threadIdx.x;
    int l = t & 63;
    int g = t >> 6;
    int bid = blockIdx.x;
    int b  = bid >> 6;
    int n0 = (bid & 63) * 64;
    int n  = n0 + l;
    size_t p = (size_t)b*NP + n;

    {
        const float* fb = feat + ((size_t)b*CIN)*NP + n;
        float fv[16];
        #pragma unroll
        for (int k=0;k<16;k++) fv[k] = fb[(size_t)(g*16+k)*NP];
        bf16x8s h0, h1;
        #pragma unroll
        for (int i=0;i<8;i++){ h0[i] = f2bf(fv[i]); h1[i] = f2bf(fv[8+i]); }
        *(bf16x8s*)(ftp + p*64 + g*16)     = h0;
        *(bf16x8s*)(ftp + p*64 + g*16 + 8) = h1;
        *(bf16x8s*)&ftb[l*72 + g*16]       = h0;
        *(bf16x8s*)&ftb[l*72 + g*16 + 8]   = h1;
    }
    if (g == 0){
        const float* xb = xpos + (size_t)b*3*NP;
        *(float4*)(xp + 4*p) = make_float4(xb[n], xb[NP+n], xb[2*NP+n], 0.f);
    }
    // ---- weight prep (block 0 only) ----
    if (bid == 0){
        int o = t >> 1, half = t & 1;
        const float* srcp = half ? (rw + (size_t)o*64) : (m2w + (size_t)o*64);
        float sc = half ? rs[o] : m2s[o];
        short* dst = wbigW + (size_t)o*128 + half*64;
        #pragma unroll
        for (int j=0;j<64;j+=8){
            bf16x8s v8;
            #pragma unroll
            for (int i=0;i<8;i++) v8[i] = f2bf(srcp[j+i]*sc);
            *(bf16x8s*)(dst + j) = v8;
        }
        if (!half) bbW[o] = m2b[o] + rb[o];
        {
            int i0 = t*8;
            bf16x8s w8;
            #pragma unroll
            for (int i=0;i<8;i++) w8[i] = f2bf(p2w2[i0+i]);
            *(bf16x8s*)(w2bW + i0) = w8;
        }
        if (t < 32){
            #pragma unroll
            for (int j=0;j<16;j++)
                l1wbW[t*16+j] = (j<10) ? f2bf(l1w[t*10+j]) : (short)0;
        }
        if (t < 128){
            int c = t >> 2;
            int i0 = t*8;
            bf16x8s a8, c8, q8, k8, v8;
            float scw = p1s2[c], scq = s2q[c], sck = s2k[c], scv = s2v[c];
            #pragma unroll
            for (int i=0;i<8;i++){
                a8[i] = f2bf(l2w[i0+i]);
                c8[i] = f2bf(p1w2[i0+i]*scw);
                q8[i] = f2bf(w2q[i0+i]*scq);
                k8[i] = f2bf(w2k[i0+i]*sck);
                v8[i] = f2bf(w2v[i0+i]*scv);
            }
            *(bf16x8s*)(l2wbW  + i0) = a8;
            *(bf16x8s*)(p1w2bW + i0) = c8;
            *(bf16x8s*)(pqkvbW + i0)        = q8;
            *(bf16x8s*)(pqkvbW + 1024 + i0) = k8;
            *(bf16x8s*)(pqkvbW + 2048 + i0) = v8;
        }
    }
    __syncthreads();

    int lr = t & 15;
    int kg = (t >> 4) & 3;
    int prow = g*16 + lr;
    size_t pg = (size_t)b*NP + n0 + prow;

    f32x4 Df0 = {0.f,0.f,0.f,0.f}, Df1 = {0.f,0.f,0.f,0.f};
    #pragma unroll
    for (int kk=0; kk<2; kk++){
        bf16x8s Bf = *(const bf16x8s*)&ftb[prow*72 + kk*32 + kg*8];
        {
            int h = lr;
            float sc = s1[h];
            const float* wr = w1 + h*64 + kk*32 + kg*8;
            bf16x8s Aw;
            #pragma unroll
            for (int i=0;i<8;i++) Aw[i] = f2bf(wr[i]*sc);
            Df0 = __builtin_amdgcn_mfma_f32_16x16x32_bf16(Aw, Bf, Df0, 0, 0, 0);
        }
        {
            int h = 16 + lr;
            float sc = s1[h];
            const float* wr = w1 + h*64 + kk*32 + kg*8;
            bf16x8s Aw;
            #pragma unroll
            for (int i=0;i<8;i++) Aw[i] = f2bf(wr[i]*sc);
            Df1 = __builtin_amdgcn_mfma_f32_16x16x32_bf16(Aw, Bf, Df1, 0, 0, 0);
        }
    }
    {
        int ch = kg*4;
        float4 b4 = *(const float4*)(b1 + ch);
        unsigned u0 = (unsigned short)f2bf(lrelu(Df0[0]+b4.x))
                    | ((unsigned)(unsigned short)f2bf(lrelu(Df0[1]+b4.y)) << 16);
        unsigned u1 = (unsigned short)f2bf(lrelu(Df0[2]+b4.z))
                    | ((unsigned)(unsigned short)f2bf(lrelu(Df0[3]+b4.w)) << 16);
        *(uint2*)&f1b[prow*40 + ch] = make_uint2(u0, u1);
    }
    {
        int ch = 16 + kg*4;
        float4 b4 = *(const float4*)(b1 + ch);
        unsigned u0 = (unsigned short)f2bf(lrelu(Df1[0]+b4.x))
                    | ((unsigned)(unsigned short)f2bf(lrelu(Df1[1]+b4.y)) << 16);
        unsigned u1 = (unsigned short)f2bf(lrelu(Df1[2]+b4.z))
                    | ((unsigned)(unsigned short)f2bf(lrelu(Df1[3]+b4.w)) << 16);
        *(uint2*)&f1b[prow*40 + ch] = make_uint2(u0, u1);
    }

    bf16x8s Bq = *(const bf16x8s*)&f1b[prow*40 + kg*8];
    float qv[6][4];
    {
        const float* wsrc[3] = {wq, wk, wv};
        const float* ssrc[3] = {sq, sk, sv};
        const float* bsrc[3] = {bq, bk, bv};
        #pragma unroll
        for (int m3=0; m3<3; m3++){
            #pragma unroll
            for (int mt=0; mt<2; mt++){
                int h = mt*16 + lr;
                float sc = ssrc[m3][h];
                const float* wr = wsrc[m3] + h*32 + kg*8;
                bf16x8s Aw;
                #pragma unroll
                for (int i=0;i<8;i++) Aw[i] = f2bf(wr[i]*sc);
                f32x4 Dq = {0.f,0.f,0.f,0.f};
                Dq = __builtin_amdgcn_mfma_f32_16x16x32_bf16(Aw, Bq, Dq, 0, 0, 0);
                int ch = mt*16 + kg*4;
                float4 b4 = *(const float4*)(bsrc[m3] + ch);
                qv[m3*2+mt][0] = reluf(Dq[0] + b4.x);
                qv[m3*2+mt][1] = reluf(Dq[1] + b4.y);
                qv[m3*2+mt][2] = reluf(Dq[2] + b4.z);
                qv[m3*2+mt][3] = reluf(Dq[3] + b4.w);
            }
        }
    }
    size_t qb = pg*H;
    *(float4*)(q1 + qb + kg*4)      = make_float4(qv[0][0],qv[0][1],qv[0][2],qv[0][3]);
    *(float4*)(q1 + qb + 16 + kg*4) = make_float4(qv[1][0],qv[1][1],qv[1][2],qv[1][3]);
    #pragma unroll
    for (int mt=0; mt<2; mt++){
        int ch = mt*16 + kg*4;
        *(float4*)(kv1 + 2*(qb+ch))     = make_float4(qv[2+mt][0], qv[4+mt][0],
                                                      qv[2+mt][1], qv[4+mt][1]);
        *(float4*)(kv1 + 2*(qb+ch) + 4) = make_float4(qv[2+mt][2], qv[4+mt][2],
                                                      qv[2+mt][3], qv[4+mt][3]);
    }
}

// ---------------- K2: pool1, 512 thr = 16 points; MFMA pooling + MFMA epilogue.
__global__ __launch_bounds__(512) void k_pool1(
    const float* __restrict__ xp, const int* __restrict__ nidx,
    const float* __restrict__ q1, const float* __restrict__ kv1,
    const short* __restrict__ l1wb,
    const float* __restrict__ l1s, const float* __restrict__ l1b,
    const short* __restrict__ p1w2b, const float* __restrict__ b2,
    const short* __restrict__ pqkvb,
    const float* __restrict__ bq, const float* __restrict__ bk, const float* __restrict__ bv,
    float* __restrict__ q2, float* __restrict__ kv2)
{
    __shared__ unsigned short bcb[16][40];   // pooled bf16 [pt][ch]
    __shared__ unsigned short f2t[16][40];   // feat2 bf16 [pt][ch]
    int t = threadIdx.x;
    int wv_ = t >> 6;
    int l   = t & 63;
    int n_  = l & 31;
    int hi  = l >> 5;
    int bid = blockIdx.x;
    int sb  = ((bid & 7) << 9) | (bid >> 3);   // nwg 4096, bijective
    size_t pbase = (size_t)sb * 16;
    size_t p0 = pbase + (size_t)wv_*2;
    int b = (int)(pbase >> 12);

    bf16x8s Bf = *(const bf16x8s*)(l1wb + n_*16 + hi*8);

    int ptA  = (l >> 4) & 1;
    int nbrA = l & 15;
    size_t pA = p0 + ptA;
    int idA = nidx[pA*KNN + nbrA];
    float4 cp = *(const float4*)(xp + 4*pA);
    float4 nv = *(const float4*)(xp + 4*((size_t)(b<<12)+idA));
    float dx = nv.x-cp.x, dy = nv.y-cp.y, dz = nv.z-cp.z;
    float dist = sqrtf(dx*dx+dy*dy+dz*dz + 1e-12f);
    bf16x8s A;
    if (hi == 0){
        A[0]=f2bf(cp.x); A[1]=f2bf(cp.y); A[2]=f2bf(cp.z); A[3]=f2bf(nv.x);
        A[4]=f2bf(nv.y); A[5]=f2bf(nv.z); A[6]=f2bf(dx);   A[7]=f2bf(dy);
    } else {
        A[0]=f2bf(dz); A[1]=f2bf(dist);
        A[2]=0; A[3]=0; A[4]=0; A[5]=0; A[6]=0; A[7]=0;
    }

    f32x16 cz = {0.f,0.f,0.f,0.f,0.f,0.f,0.f,0.f,0.f,0.f,0.f,0.f,0.f,0.f,0.f,0.f};
    f32x16 D = __builtin_amdgcn_mfma_f32_32x32x16_bf16(A, Bf, cz, 0, 0, 0);

    float sl1 = l1s[n_], bl1 = l1b[n_];
    const int* irow0 = nidx + p0*KNN;
    float outv[2];
    #pragma unroll
    for (int pt=0; pt<2; pt++){
        size_t p = p0 + pt;
        float qc = q1[p*H + n_];
        int4 idlo = *(const int4*)(irow0 + pt*KNN + 4*hi);
        int4 idhi = *(const int4*)(irow0 + pt*KNN + 8 + 4*hi);
        int ids[8] = {idlo.x,idlo.y,idlo.z,idlo.w, idhi.x,idhi.y,idhi.z,idhi.w};
        float W[8], V[8];
        #pragma unroll
        for (int rr=0; rr<8; rr++){
            float xi = lrelu(D[pt*8+rr]*sl1 + bl1);
            float2 kv = *(const float2*)(kv1 + 2*(((size_t)b*NP + ids[rr])*H + n_));
            W[rr] = xi*(kv.x - qc);
            V[rr] = kv.y;
        }
        float mx = W[0];
        #pragma unroll
        for (int rr=1;rr<8;rr++) mx = fmaxf(mx, W[rr]);
        mx = fmaxf(mx, __shfl_xor(mx, 32, 64));
        float den = 0.f, ac = 0.f;
        #pragma unroll
        for (int rr=0;rr<8;rr++){
            float e = __expf(W[rr]-mx);
            den += e; ac = fmaf(e, V[rr], ac);
        }
        den += __shfl_xor(den, 32, 64);
        ac  += __shfl_xor(ac,  32, 64);
        outv[pt] = ac/den;
    }
    if (l < 32){
        bcb[wv_*2 + 0][n_] = (unsigned short)f2bf(outv[0]);
        bcb[wv_*2 + 1][n_] = (unsigned short)f2bf(outv[1]);
    }
    __syncthreads();

    int lr = l & 15, kg = l >> 4;
    // ---- feat2 = lrelu(pooled @ (p1_w2*s2)^T + b2) via MFMA (waves 0-1) ----
    if (wv_ < 2){
        bf16x8s Aw = *(const bf16x8s*)(p1w2b + (wv_*16 + lr)*32 + kg*8);
        bf16x8s Bp = *(const bf16x8s*)&bcb[lr][kg*8];
        f32x4 Df = {0.f,0.f,0.f,0.f};
        Df = __builtin_amdgcn_mfma_f32_16x16x32_bf16(Aw, Bp, Df, 0, 0, 0);
        int ch0 = wv_*16 + kg*4;
        float4 b4 = *(const float4*)(b2 + ch0);
        f2t[lr][ch0+0] = (unsigned short)f2bf(lrelu(Df[0] + b4.x));
        f2t[lr][ch0+1] = (unsigned short)f2bf(lrelu(Df[1] + b4.y));
        f2t[lr][ch0+2] = (unsigned short)f2bf(lrelu(Df[2] + b4.z));
        f2t[lr][ch0+3] = (unsigned short)f2bf(lrelu(Df[3] + b4.w));
    }
    __syncthreads();

    // ---- q2/k2/v2 = relu(feat2 @ (p2_w*s)^T + b) via MFMA (waves 0-5) ----
    if (wv_ < 6){
        int m3 = wv_ >> 1, mt = wv_ & 1;
        bf16x8s Aw = *(const bf16x8s*)(pqkvb + m3*1024 + (mt*16 + lr)*32 + kg*8);
        bf16x8s Bp = *(const bf16x8s*)&f2t[lr][kg*8];
        f32x4 Dq = {0.f,0.f,0.f,0.f};
        Dq = __builtin_amdgcn_mfma_f32_16x16x32_bf16(Aw, Bp, Dq, 0, 0, 0);
        int ch0 = mt*16 + kg*4;
        size_t p = pbase + lr;
        if (m3 == 0){
            float4 b4 = *(const float4*)(bq + ch0);
            *(float4*)(q2 + p*H + ch0) = make_float4(
                reluf(Dq[0]+b4.x), reluf(Dq[1]+b4.y), reluf(Dq[2]+b4.z), reluf(Dq[3]+b4.w));
        } else if (m3 == 1){
            float4 b4 = *(const float4*)(bk + ch0);
            kv2[2*(p*H + ch0 + 0)] = reluf(Dq[0]+b4.x);
            kv2[2*(p*H + ch0 + 1)] = reluf(Dq[1]+b4.y);
            kv2[2*(p*H + ch0 + 2)] = reluf(Dq[2]+b4.z);
            kv2[2*(p*H + ch0 + 3)] = reluf(Dq[3]+b4.w);
        } else {
            float4 b4 = *(const float4*)(bv + ch0);
            kv2[2*(p*H + ch0 + 0) + 1] = reluf(Dq[0]+b4.x);
            kv2[2*(p*H + ch0 + 1) + 1] = reluf(Dq[1]+b4.y);
            kv2[2*(p*H + ch0 + 2) + 1] = reluf(Dq[2]+b4.z);
            kv2[2*(p*H + ch0 + 3) + 1] = reluf(Dq[3]+b4.w);
        }
    }
}

// ---------------- K3: pool2 FUSED — pooling + feat3 MFMA + final GEMM.
__global__ __launch_bounds__(512) void k_pool2(
    const float* __restrict__ xp, const int* __restrict__ nidx,
    const float* __restrict__ q2, const float* __restrict__ kv2,
    const short* __restrict__ l1wb,
    const float* __restrict__ l1s, const float* __restrict__ l1b,
    const short* __restrict__ l2wb,
    const float* __restrict__ l2s, const float* __restrict__ l2b,
    const short* __restrict__ w2bf, const float* __restrict__ s2, const float* __restrict__ b2,
    const short* __restrict__ ftp, const short* __restrict__ wbig, const float* __restrict__ bb,
    float* __restrict__ out)
{
    __shared__ unsigned short xiT[8][32*40];
    __shared__ unsigned short bcb[16][40];
    __shared__ unsigned short xf[16][72];
    int t = threadIdx.x;
    int wv_ = t >> 6;
    int l   = t & 63;
    int n_  = l & 31;
    int hi  = l >> 5;
    int bid = blockIdx.x;
    int sb  = ((bid & 7) << 9) | (bid >> 3);
    size_t pbase = (size_t)sb * 16;
    size_t p0 = pbase + (size_t)wv_*2;
    int b = (int)(pbase >> 12);

    bf16x8s Bf1 = *(const bf16x8s*)(l1wb + n_*16 + hi*8);
    int ptA  = (l >> 4) & 1;
    int nbrA = l & 15;
    size_t pA = p0 + ptA;
    int idA = nidx[pA*KNN + nbrA];
    float4 cp = *(const float4*)(xp + 4*pA);
    float4 nv = *(const float4*)(xp + 4*((size_t)(b<<12)+idA));
    float dx = nv.x-cp.x, dy = nv.y-cp.y, dz = nv.z-cp.z;
    float dist = sqrtf(dx*dx+dy*dy+dz*dz + 1e-12f);
    bf16x8s Ag;
    if (hi == 0){
        Ag[0]=f2bf(cp.x); Ag[1]=f2bf(cp.y); Ag[2]=f2bf(cp.z); Ag[3]=f2bf(nv.x);
        Ag[4]=f2bf(nv.y); Ag[5]=f2bf(nv.z); Ag[6]=f2bf(dx);   Ag[7]=f2bf(dy);
    } else {
        Ag[0]=f2bf(dz); Ag[1]=f2bf(dist);
        Ag[2]=0; Ag[3]=0; Ag[4]=0; Ag[5]=0; Ag[6]=0; Ag[7]=0;
    }
    f32x16 cz = {0.f,0.f,0.f,0.f,0.f,0.f,0.f,0.f,0.f,0.f,0.f,0.f,0.f,0.f,0.f,0.f};
    f32x16 D1 = __builtin_amdgcn_mfma_f32_32x32x16_bf16(Ag, Bf1, cz, 0, 0, 0);

    float sl1 = l1s[n_], bl1 = l1b[n_];
    #pragma unroll
    for (int r=0;r<16;r++){
        int m = (r&3) + 8*(r>>2) + 4*hi;
        xiT[wv_][m*40 + n_] = (unsigned short)f2bf(lrelu(D1[r]*sl1 + bl1));
    }
    bf16x8s A20 = *(const bf16x8s*)&xiT[wv_][n_*40 + hi*8];
    bf16x8s A21 = *(const bf16x8s*)&xiT[wv_][n_*40 + 16 + hi*8];
    bf16x8s B0 = *(const bf16x8s*)(l2wb + n_*32 + hi*8);
    bf16x8s B1 = *(const bf16x8s*)(l2wb + n_*32 + 16 + hi*8);
    f32x16 D = __builtin_amdgcn_mfma_f32_32x32x16_bf16(A20, B0, cz, 0, 0, 0);
    D = __builtin_amdgcn_mfma_f32_32x32x16_bf16(A21, B1, D, 0, 0, 0);

    float sl2 = l2s[n_], bl2 = l2b[n_];
    const int* irow0 = nidx + p0*KNN;
    float outv[2];
    #pragma unroll
    for (int pt=0; pt<2; pt++){
        size_t p = p0 + pt;
        float qc = q2[p*H + n_];
        int4 idlo = *(const int4*)(irow0 + pt*KNN + 4*hi);
        int4 idhi = *(const int4*)(irow0 + pt*KNN + 8 + 4*hi);
        int ids[8] = {idlo.x,idlo.y,idlo.z,idlo.w, idhi.x,idhi.y,idhi.z,idhi.w};
        float W[8], V[8];
        #pragma unroll
        for (int rr=0; rr<8; rr++){
            float xi2 = lrelu(D[pt*8+rr]*sl2 + bl2);
            float2 kv = *(const float2*)(kv2 + 2*(((size_t)b*NP + ids[rr])*H + n_));
            W[rr] = xi2*(kv.x - qc);
            V[rr] = kv.y;
        }
        float mx = W[0];
        #pragma unroll
        for (int rr=1;rr<8;rr++) mx = fmaxf(mx, W[rr]);
        mx = fmaxf(mx, __shfl_xor(mx, 32, 64));
        float den = 0.f, ac = 0.f;
        #pragma unroll
        for (int rr=0;rr<8;rr++){
            float e = __expf(W[rr]-mx);
            den += e; ac = fmaf(e, V[rr], ac);
        }
        den += __shfl_xor(den, 32, 64);
        ac  += __shfl_xor(ac,  32, 64);
        outv[pt] = ac/den;
    }
    if (l < 32){
        bcb[wv_*2 + 0][n_] = (unsigned short)f2bf(outv[0]);
        bcb[wv_*2 + 1][n_] = (unsigned short)f2bf(outv[1]);
    }
    __syncthreads();

    int lr = l & 15, kg = l >> 4;
    if (wv_ < 4){
        bf16x8s Aw = *(const bf16x8s*)(w2bf + (wv_*16 + lr)*32 + kg*8);
        bf16x8s Bp = *(const bf16x8s*)&bcb[lr][kg*8];
        f32x4 zz = {0.f,0.f,0.f,0.f};
        f32x4 Df = __builtin_amdgcn_mfma_f32_16x16x32_bf16(Aw, Bp, zz, 0, 0, 0);
        int ch0 = wv_*16 + kg*4;
        float4 s4 = *(const float4*)(s2 + ch0);
        float4 b4 = *(const float4*)(b2 + ch0);
        xf[lr][ch0+0] = (unsigned short)f2bf(lrelu(Df[0]*s4.x + b4.x));
        xf[lr][ch0+1] = (unsigned short)f2bf(lrelu(Df[1]*s4.y + b4.y));
        xf[lr][ch0+2] = (unsigned short)f2bf(lrelu(Df[2]*s4.z + b4.z));
        xf[lr][ch0+3] = (unsigned short)f2bf(lrelu(Df[3]*s4.w + b4.w));
    }
    __syncthreads();

    int o0 = wv_ * 16;
    const short* wr = wbig + (size_t)(o0 + lr)*128 + kg*8;
    bf16x8s Af0 = *(const bf16x8s*)(wr);
    bf16x8s Af1 = *(const bf16x8s*)(wr + 32);
    bf16x8s Af2 = *(const bf16x8s*)(wr + 64);
    bf16x8s Af3 = *(const bf16x8s*)(wr + 96);
    bf16x8s Bx0 = *(const bf16x8s*)&xf[lr][kg*8];
    bf16x8s Bx1 = *(const bf16x8s*)&xf[lr][32 + kg*8];
    const short* fr = ftp + (pbase + lr)*64 + kg*8;
    bf16x8s Bx2 = *(const bf16x8s*)(fr);
    bf16x8s Bx3 = *(const bf16x8s*)(fr + 32);
    f32x4 Dq = {0.f,0.f,0.f,0.f};
    Dq = __builtin_amdgcn_mfma_f32_16x16x32_bf16(Af0, Bx0, Dq, 0, 0, 0);
    Dq = __builtin_amdgcn_mfma_f32_16x16x32_bf16(Af1, Bx1, Dq, 0, 0, 0);
    Dq = __builtin_amdgcn_mfma_f32_16x16x32_bf16(Af2, Bx2, Dq, 0, 0, 0);
    Dq = __builtin_amdgcn_mfma_f32_16x16x32_bf16(Af3, Bx3, Dq, 0, 0, 0);
    float4 bb4 = *(const float4*)(bb + o0 + kg*4);
    int n0 = (int)(pbase & (NP-1));
    float* ob = out + ((size_t)b*128)*NP + n0 + lr;
    ob[(size_t)(o0 + kg*4 + 0)*NP] = lrelu(Dq[0] + bb4.x);
    ob[(size_t)(o0 + kg*4 + 1)*NP] = lrelu(Dq[1] + bb4.y);
    ob[(size_t)(o0 + kg*4 + 2)*NP] = lrelu(Dq[2] + bb4.z);
    ob[(size_t)(o0 + kg*4 + 3)*NP] = lrelu(Dq[3] + bb4.w);
}

extern "C" void kernel_launch(void* const* d_in, const int* in_sizes, int n_in,
                              void* d_out, int out_size, void* d_ws, size_t ws_size,
                              hipStream_t stream)
{
    (void)in_sizes; (void)n_in; (void)out_size; (void)ws_size;
    const float* x     = (const float*)d_in[0];
    const float* feat  = (const float*)d_in[1];
    const int*   nidx  = (const int*)  d_in[2];
    const float* m1w=(const float*)d_in[3],  *m1s=(const float*)d_in[4],  *m1b=(const float*)d_in[5];
    const float* l1w=(const float*)d_in[6],  *l1s=(const float*)d_in[7],  *l1b=(const float*)d_in[8];
    const float* p1wq=(const float*)d_in[9],  *p1sq=(const float*)d_in[10], *p1bq=(const float*)d_in[11];
    const float* p1wk=(const float*)d_in[12], *p1sk=(const float*)d_in[13], *p1bk=(const float*)d_in[14];
    const float* p1wv=(const float*)d_in[15], *p1sv=(const float*)d_in[16], *p1bv=(const float*)d_in[17];
    const float* p1w2=(const float*)d_in[18], *p1s2=(const float*)d_in[19], *p1b2=(const float*)d_in[20];
    const float* p2wq=(const float*)d_in[21], *p2sq=(const float*)d_in[22], *p2bq=(const float*)d_in[23];
    const float* p2wk=(const float*)d_in[24], *p2sk=(const float*)d_in[25], *p2bk=(const float*)d_in[26];
    const float* p2wv=(const float*)d_in[27], *p2sv=(const float*)d_in[28], *p2bv=(const float*)d_in[29];
    const float* p2w2=(const float*)d_in[30], *p2s2=(const float*)d_in[31], *p2b2=(const float*)d_in[32];
    const float* l2w=(const float*)d_in[33], *l2s=(const float*)d_in[34], *l2b=(const float*)d_in[35];
    const float* m2w=(const float*)d_in[36], *m2s=(const float*)d_in[37], *m2b=(const float*)d_in[38];
    const float* rw =(const float*)d_in[39], *rs =(const float*)d_in[40], *rb =(const float*)d_in[41];

    float* ws = (float*)d_ws;
    float* q1  = ws;                    // PN*32 f32
    float* kv1 = ws + PN*32;            // PN*64 f32
    float* q2  = ws + PN*96;            // PN*32 f32
    float* kv2 = ws + PN*128;           // PN*64 f32
    float* xp  = ws + PN*192;           // PN*4 f32
    short* ftp = (short*)(ws + PN*196); // PN*64 bf16
    short* wbig  = (short*)(ws + PN*228);   // 128*128 bf16
    short* w2bf  = wbig + 16384;            // 64*32 bf16
    float* bb    = (float*)(w2bf + 2048);   // 128 f32
    short* l1wb  = (short*)(bb + 128);      // 32*16 bf16 (lse1^T K-padded)
    short* l2wb  = l1wb + 512;              // 32*32 bf16
    short* p1w2b = l2wb + 1024;             // 32*32 bf16 (p1_w2 * s2)
    short* pqkvb = p1w2b + 1024;            // 3*32*32 bf16 (p2_{q,k,v} * s)

    float* outp = (float*)d_out;

    k_pointwise<<<dim3(PN/64),dim3(256),0,stream>>>(feat, x, m1w,m1s,m1b,
        p1wq,p1sq,p1bq, p1wk,p1sk,p1bk, p1wv,p1sv,p1bv, q1,kv1, xp, ftp,
        m2w,m2s,m2b, rw,rs,rb, p2w2,
        l1w, l2w, p1w2, p1s2, p2wq,p2sq, p2wk,p2sk, p2wv,p2sv,
        wbig, w2bf, bb, l1wb, l2wb, p1w2b, pqkvb);
    k_pool1<<<dim3(PN/16),dim3(512),0,stream>>>(xp,nidx, q1,kv1,
        l1wb, l1s,l1b, p1w2b, p1b2, pqkvb, p2bq,p2bk,p2bv, q2,kv2);
    k_pool2<<<dim3(PN/16),dim3(512),0,stream>>>(xp,nidx, q2,kv2,
        l1wb, l1s,l1b, l2wb, l2s,l2b, w2bf, p2s2, p2b2, ftp, wbig, bb, outp);
}